// Round 10
// baseline (327.414 us; speedup 1.0000x reference)
//
#include <hip/hip_runtime.h>
#include <hip/hip_bf16.h>

#define B_  2
#define T_  1024
#define D_  768
#define H_  12
#define NT  2048        // B*T
#define DQ_ 1024
#define PH_ 4
#define NK_ 256
#define TK_ 32
#define DHK_ 128
#define QKVLD 2304      // merged QKV row stride
#define CVHALF 25165824L // half the values table, elements
#define NKEYS (PH_ * NK_ * 2 * DHK_)

typedef __attribute__((ext_vector_type(8))) short bf16x8;
typedef __attribute__((ext_vector_type(4))) float f32x4;

static __device__ __forceinline__ unsigned short f2bf(float f) {
    union { float f; unsigned u; } c; c.f = f;
    unsigned r = (c.u + 0x7fffu + ((c.u >> 16) & 1u)) >> 16;
    return (unsigned short)r;
}

static __device__ __forceinline__ float bf2f(unsigned short s) {
    union { unsigned u; float f; } c; c.u = ((unsigned)s) << 16;
    return c.f;
}

// ---------------- batched weight prep: 5 transposes + keys convert, one launch ----------------
__global__ void transpose_kernel(const float* __restrict__ wq, const float* __restrict__ wk,
                                 const float* __restrict__ wv, const float* __restrict__ wo,
                                 const float* __restrict__ pwq, const float* __restrict__ keys,
                                 unsigned short* __restrict__ wqkvT,
                                 unsigned short* __restrict__ woT,
                                 unsigned short* __restrict__ pwqT,
                                 unsigned short* __restrict__ keyB) {
    __shared__ float t[32][33];
    int z = blockIdx.z;
    if (z == 5) {   // keys: pure convert, 2 elems/thread
        long i = (((long)blockIdx.y * 24 + blockIdx.x) * 256 + threadIdx.y * 32 + threadIdx.x) * 2;
        if (i + 1 < NKEYS) { keyB[i] = f2bf(keys[i]); keyB[i + 1] = f2bf(keys[i + 1]); }
        return;
    }
    const float* W; unsigned short* Wt; int N;
    if (z == 0)      { W = wq;  Wt = wqkvT;              N = 768; }
    else if (z == 1) { W = wk;  Wt = wqkvT + 589824;     N = 768; }
    else if (z == 2) { W = wv;  Wt = wqkvT + 2 * 589824; N = 768; }
    else if (z == 3) { W = wo;  Wt = woT;                N = 768; }
    else             { W = pwq; Wt = pwqT;               N = 1024; }
    int k0 = blockIdx.x * 32, n0 = blockIdx.y * 32;
    if (n0 >= N) return;
    int tx = threadIdx.x, ty = threadIdx.y;
#pragma unroll
    for (int i = 0; i < 4; ++i)
        t[ty + 8 * i][tx] = W[(long)(k0 + ty + 8 * i) * N + n0 + tx];
    __syncthreads();
#pragma unroll
    for (int i = 0; i < 4; ++i)
        Wt[(long)(n0 + ty + 8 * i) * 768 + k0 + tx] = f2bf(t[tx][ty + 8 * i]);
}

// ---------------- LayerNorm: x f32 [rows][768] -> bf16 ----------------
__global__ __launch_bounds__(256)
void ln_kernel(const float* __restrict__ x, const float* __restrict__ g,
               const float* __restrict__ b, unsigned short* __restrict__ out) {
    int row = blockIdx.x, tid = threadIdx.x;
    const float* xr = x + (long)row * D_;
    float v0 = xr[tid], v1 = xr[tid + 256], v2 = xr[tid + 512];
    float s = v0 + v1 + v2, ss = v0 * v0 + v1 * v1 + v2 * v2;
#pragma unroll
    for (int o = 1; o < 64; o <<= 1) { s += __shfl_xor(s, o); ss += __shfl_xor(ss, o); }
    __shared__ float ps[4], pss[4];
    int wid = tid >> 6, lane = tid & 63;
    if (lane == 0) { ps[wid] = s; pss[wid] = ss; }
    __syncthreads();
    s = ps[0] + ps[1] + ps[2] + ps[3];
    ss = pss[0] + pss[1] + pss[2] + pss[3];
    float mean = s * (1.f / D_);
    float var = ss * (1.f / D_) - mean * mean;
    float rs = rsqrtf(var + 1e-5f);
    unsigned short* orow = out + (long)row * D_;
    orow[tid]       = f2bf((v0 - mean) * rs * g[tid]       + b[tid]);
    orow[tid + 256] = f2bf((v1 - mean) * rs * g[tid + 256] + b[tid + 256]);
    orow[tid + 512] = f2bf((v2 - mean) * rs * g[tid + 512] + b[tid + 512]);
}

// ---------------- MFMA GEMM: C[M,N] = A[M,K](bf16,lda) @ Bt[N,K](bf16,ldb)^T ----------------
// 64x64 tile, 4 waves, BK=32.
// zmode 1: dots batching over blockIdx.z. zmode 2: merged QKV (bias segment select).
// If cvin != nullptr, blocks with blockIdx.y >= cvy0 grid-stride convert a table slice.
__global__ __launch_bounds__(256)
void gemm_kernel(const unsigned short* __restrict__ A, int lda,
                 const unsigned short* __restrict__ Bt, int ldb,
                 const float* __restrict__ bias,
                 const float* __restrict__ bias2,
                 const float* __restrict__ bias3,
                 const float* __restrict__ res,
                 float* __restrict__ outF,
                 unsigned short* __restrict__ outB,
                 int ldc, int K, int zmode,
                 const float* __restrict__ cvin,
                 unsigned short* __restrict__ cvout,
                 long cvbase, int cvy0) {
    if (cvin && (int)blockIdx.y >= cvy0) {
        long stride = (long)(gridDim.y - cvy0) * gridDim.x * 256 * 8;
        long idx = cvbase +
            ((long)((blockIdx.y - cvy0) * gridDim.x + blockIdx.x) * 256 + threadIdx.x) * 8;
        long end = cvbase + CVHALF;
#pragma unroll 2
        for (; idx < end; idx += stride) {
            f32x4 a = *(const f32x4*)(cvin + idx);
            f32x4 b = *(const f32x4*)(cvin + idx + 4);
            bf16x8 r;
#pragma unroll
            for (int j = 0; j < 4; ++j) { r[j] = (short)f2bf(a[j]); r[4 + j] = (short)f2bf(b[j]); }
            *(bf16x8*)(cvout + idx) = r;
        }
        return;
    }
    if (zmode == 1) {
        int z = blockIdx.z, ph = z >> 1, half = z & 1;
        A    += half * 512 + ph * 128;
        Bt   += ph * 65536 + half * 128;
        outF += ph * 512 + half * 256;
    }
    const int tid = threadIdx.x;
    const int w = tid >> 6, lane = tid & 63;
    const int ls = lane & 15, g = lane >> 4;
    const int m0 = blockIdx.x * 64, n0 = blockIdx.y * 64;

    __shared__ unsigned short As[64][40];
    __shared__ unsigned short Bs[64][40];

    f32x4 acc[4];
#pragma unroll
    for (int c = 0; c < 4; ++c) acc[c] = (f32x4){0.f, 0.f, 0.f, 0.f};

    const int lrow = tid >> 2, lseg = tid & 3;
    const unsigned short* gA = A + (long)(m0 + lrow) * lda + lseg * 8;
    const unsigned short* gB = Bt + (long)(n0 + lrow) * ldb + lseg * 8;

    for (int kt = 0; kt < K; kt += 32) {
        __syncthreads();
        *(int4*)&As[lrow][lseg * 8] = *(const int4*)(gA + kt);
        *(int4*)&Bs[lrow][lseg * 8] = *(const int4*)(gB + kt);
        __syncthreads();
        bf16x8 bfr = *(const bf16x8*)&Bs[w * 16 + ls][g * 8];
#pragma unroll
        for (int c = 0; c < 4; ++c) {
            bf16x8 afr = *(const bf16x8*)&As[c * 16 + ls][g * 8];
            acc[c] = __builtin_amdgcn_mfma_f32_16x16x32_bf16(afr, bfr, acc[c], 0, 0, 0);
        }
    }
#pragma unroll
    for (int c = 0; c < 4; ++c) {
#pragma unroll
        for (int r = 0; r < 4; ++r) {
            int row = m0 + c * 16 + g * 4 + r;
            int col = n0 + w * 16 + ls;
            float v = acc[c][r];
            if (bias) {
                const float* bp = bias; int cc = col;
                if (zmode == 2) {
                    int sel = col >= 1536 ? 2 : (col >= 768 ? 1 : 0);
                    bp = sel == 0 ? bias : (sel == 1 ? bias2 : bias3);
                    cc = col - sel * 768;
                }
                v += bp[cc];
            }
            long off = (long)row * ldc + col;
            if (res)  v += res[off];
            if (outF) outF[off] = v;
            if (outB) outB[off] = f2bf(v);
        }
    }
}

// ---------------- MFMA flash attention: 2-wave blocks (32 q-rows), grid 768 = 3 blk/CU ----------------
__global__ __launch_bounds__(128)
void attn_mfma_kernel(const unsigned short* __restrict__ qkv,
                      unsigned short* __restrict__ outg) {
    int bh = blockIdx.x, bb = bh / H_, hh = bh % H_;
    int q0 = blockIdx.y * 32;
    int tid = threadIdx.x, wv = tid >> 6, lane = tid & 63;
    int ls = lane & 15, g = lane >> 4;

    __shared__ unsigned short Klds[128 * 64];     // 16 KB
    __shared__ unsigned short Vlds[64 * 128];     // 16 KB (transposed V)
    __shared__ unsigned short Plds[2][16 * 128];  // 8 KB, per-wave

    const unsigned short* qrow = qkv + (long)(bb * T_ + q0 + wv * 16 + ls) * QKVLD + hh * 64 + g * 8;
    bf16x8 qf0 = *(const bf16x8*)qrow;
    bf16x8 qf1 = *(const bf16x8*)(qrow + 32);

    f32x4 o_acc[4];
#pragma unroll
    for (int nf = 0; nf < 4; ++nf) o_acc[nf] = (f32x4){0.f, 0.f, 0.f, 0.f};
    float mrun[4] = {-1e30f, -1e30f, -1e30f, -1e30f};
    float lrun[4] = {0.f, 0.f, 0.f, 0.f};

    char* pbase = (char*)&Plds[wv][0];

    for (int kt = 0; kt < T_ / 128; ++kt) {
        int kvb = kt * 128;
        __syncthreads();
        // ---- stage K [128][64] swizzled : 8 x b128 per thread (128 threads) ----
#pragma unroll
        for (int i = 0; i < 8; ++i) {
            int c = tid + i * 128;
            int kv = c >> 3, dc = c & 7;
            bf16x8 kd = *(const bf16x8*)(qkv + (long)(bb * T_ + kvb + kv) * QKVLD + 768 + hh * 64 + dc * 8);
            *(bf16x8*)((char*)Klds + ((kv * 128 + dc * 16) ^ ((kv & 7) << 4))) = kd;
        }
        // ---- stage V transposed [64][128] swizzled : 2 x (4 rows x 8 cols) per thread ----
#pragma unroll
        for (int it = 0; it < 2; ++it) {
            int d0 = (tid & 7) * 8, kvq = (tid >> 3) + it * 16;
            const unsigned short* vb = qkv + (long)(bb * T_ + kvb + kvq * 4) * QKVLD + 1536 + hh * 64 + d0;
            bf16x8 r0 = *(const bf16x8*)(vb);
            bf16x8 r1 = *(const bf16x8*)(vb + QKVLD);
            bf16x8 r2 = *(const bf16x8*)(vb + 2 * QKVLD);
            bf16x8 r3 = *(const bf16x8*)(vb + 3 * QKVLD);
#pragma unroll
            for (int j = 0; j < 8; ++j) {
                unsigned lo = (unsigned)(unsigned short)r0[j] | ((unsigned)(unsigned short)r1[j] << 16);
                unsigned hi = (unsigned)(unsigned short)r2[j] | ((unsigned)(unsigned short)r3[j] << 16);
                int d = d0 + j;
                *(uint2*)((char*)Vlds + ((d * 256 + kvq * 8) ^ ((d & 7) << 4))) = make_uint2(lo, hi);
            }
        }
        __syncthreads();

        // ---- S = Q @ K^T ----
        f32x4 sa[8];
#pragma unroll
        for (int f = 0; f < 8; ++f) sa[f] = (f32x4){0.f, 0.f, 0.f, 0.f};
#pragma unroll
        for (int f = 0; f < 8; ++f) {
            int kv = f * 16 + ls;
            bf16x8 b0 = *(const bf16x8*)((char*)Klds + ((kv * 128 + g * 16) ^ ((kv & 7) << 4)));
            bf16x8 b1 = *(const bf16x8*)((char*)Klds + ((kv * 128 + 64 + g * 16) ^ ((kv & 7) << 4)));
            sa[f] = __builtin_amdgcn_mfma_f32_16x16x32_bf16(qf0, b0, sa[f], 0, 0, 0);
            sa[f] = __builtin_amdgcn_mfma_f32_16x16x32_bf16(qf1, b1, sa[f], 0, 0, 0);
        }

        // ---- online softmax ----
        float pw[8][4];
#pragma unroll
        for (int f = 0; f < 8; ++f)
#pragma unroll
            for (int r = 0; r < 4; ++r) pw[f][r] = sa[f][r] * 0.125f;
        float nm[4], fac[4];
#pragma unroll
        for (int r = 0; r < 4; ++r) {
            float m = pw[0][r];
#pragma unroll
            for (int f = 1; f < 8; ++f) m = fmaxf(m, pw[f][r]);
            m = fmaxf(m, __shfl_xor(m, 1));
            m = fmaxf(m, __shfl_xor(m, 2));
            m = fmaxf(m, __shfl_xor(m, 4));
            m = fmaxf(m, __shfl_xor(m, 8));
            nm[r] = fmaxf(mrun[r], m);
            fac[r] = __expf(mrun[r] - nm[r]);
            mrun[r] = nm[r];
        }
#pragma unroll
        for (int r = 0; r < 4; ++r) {
            float s = 0.f;
#pragma unroll
            for (int f = 0; f < 8; ++f) { float e = __expf(pw[f][r] - nm[r]); pw[f][r] = e; s += e; }
            s += __shfl_xor(s, 1); s += __shfl_xor(s, 2);
            s += __shfl_xor(s, 4); s += __shfl_xor(s, 8);
            lrun[r] = lrun[r] * fac[r] + s;
#pragma unroll
            for (int nf = 0; nf < 4; ++nf) o_acc[nf][r] *= fac[r];
        }

        // ---- P -> LDS (wave-private) ----
#pragma unroll
        for (int f = 0; f < 8; ++f)
#pragma unroll
            for (int r = 0; r < 4; ++r) {
                int qr = g * 4 + r, col = ls + 16 * f;
                *(unsigned short*)(pbase + ((qr * 256 + col * 2) ^ ((qr & 7) << 4))) = f2bf(pw[f][r]);
            }

        // ---- O += P @ V ----
#pragma unroll
        for (int ks = 0; ks < 4; ++ks) {
            bf16x8 pa = *(const bf16x8*)(pbase + ((ls * 256 + ks * 64 + g * 16) ^ ((ls & 7) << 4)));
#pragma unroll
            for (int nf = 0; nf < 4; ++nf) {
                int d = nf * 16 + ls;
                bf16x8 bv = *(const bf16x8*)((char*)Vlds + ((d * 256 + ks * 64 + g * 16) ^ ((d & 7) << 4)));
                o_acc[nf] = __builtin_amdgcn_mfma_f32_16x16x32_bf16(pa, bv, o_acc[nf], 0, 0, 0);
            }
        }
    }

    float inv[4];
#pragma unroll
    for (int r = 0; r < 4; ++r) inv[r] = 1.f / lrun[r];
#pragma unroll
    for (int nf = 0; nf < 4; ++nf)
#pragma unroll
        for (int r = 0; r < 4; ++r) {
            long row = bb * T_ + q0 + wv * 16 + g * 4 + r;
            outg[row * D_ + hh * 64 + nf * 16 + ls] = f2bf(o_acc[nf][r] * inv[r]);
        }
}

// ---------------- BatchNorm over tokens (deterministic two-stage, 256 blocks) ----------------
__global__ __launch_bounds__(256)
void bn_part(const float* __restrict__ qf, float* __restrict__ pS, float* __restrict__ pSS) {
    int c = blockIdx.y * 256 + threadIdx.x;
    int r0 = blockIdx.x * 32;
    float s = 0.f, ss = 0.f;
#pragma unroll 4
    for (int r = 0; r < 32; ++r) {
        float v = qf[(long)(r0 + r) * DQ_ + c];
        s += v; ss += v * v;
    }
    pS[(long)blockIdx.x * DQ_ + c] = s;
    pSS[(long)blockIdx.x * DQ_ + c] = ss;
}

__global__ __launch_bounds__(256)
void bn_fin(const float* __restrict__ pS, const float* __restrict__ pSS,
            float* __restrict__ mu, float* __restrict__ rs) {
    int c = blockIdx.x * 256 + threadIdx.x;
    float s = 0.f, ss = 0.f;
#pragma unroll 8
    for (int i = 0; i < 64; ++i) { s += pS[(long)i * DQ_ + c]; ss += pSS[(long)i * DQ_ + c]; }
    float m = s * (1.f / NT);
    float var = ss * (1.f / NT) - m * m;
    mu[c] = m;
    rs[c] = rsqrtf(var + 1e-5f);
}

__global__ __launch_bounds__(256)
void qn_kernel(const float* __restrict__ qf, const float* __restrict__ mu,
               const float* __restrict__ rs, const float* __restrict__ g,
               const float* __restrict__ b, unsigned short* __restrict__ qn) {
    int i = blockIdx.x * 256 + threadIdx.x;
    int c = i & (DQ_ - 1);
    qn[i] = f2bf((qf[i] - mu[c]) * rs[c] * g[c] + b[c]);
}

// ---------------- fused top-k: 2 waves per task (parallel halves) ----------------
__global__ __launch_bounds__(256)
void topk_kernel(const float* __restrict__ dots, float* __restrict__ fs, int* __restrict__ vi) {
    static const unsigned short tab[128] = {
        0,1,2,3,4,5,6,7,8,9,10,11,12,13,14,15,16,17,18,19,20,21,22,23,24,25,26,27,28,29,30,31,
        32,33,34,35,36,37,38,39,40,41,42,43,44,45,46,47,
        64,65,66,67,68,69,70,71,72,73,
        96,97,98,99,100,101,102,103,
        128,129,130,131,132,133,
        160,161,162,163,164,
        192,193,194,195,
        224,225,226,227,
        256,257,258,
        288,289,290,
        320,321, 352,353, 384,385, 416,417, 448,449, 480,481,
        512,544,576,608,640,672,704,736,768,800,832,864,896,928,960,992,
        0xFFFF,0xFFFF,0xFFFF,0xFFFF,0xFFFF,0xFFFF,0xFFFF,0xFFFF,0xFFFF
    };
    __shared__ float sv[2][64];
    __shared__ int   sidx[2][64];
    int tid = threadIdx.x, wv = tid >> 6, lane = tid & 63;
    int slot = wv >> 1, half = wv & 1;
    long task = (long)blockIdx.x * 2 + slot;
    const float* d = dots + (task >> 2) * 2048 + (task & 3) * 512 + half * 256;

    float v0 = d[lane], v1 = d[lane + 64], v2 = d[lane + 128], v3 = d[lane + 192];
#pragma unroll 1
    for (int t = 0; t < 32; ++t) {
        float bm = v0; int ba = 0;
        if (v1 > bm) { bm = v1; ba = 1; }
        if (v2 > bm) { bm = v2; ba = 2; }
        if (v3 > bm) { bm = v3; ba = 3; }
        float wm = bm;
#pragma unroll
        for (int o = 32; o >= 1; o >>= 1) wm = fmaxf(wm, __shfl_xor(wm, o));
        unsigned long long msk = __ballot(bm == wm);
        int owner = (int)__builtin_ctzll(msk);
        if (lane == owner) {
            sv[slot][half * 32 + t] = wm;
            sidx[slot][half * 32 + t] = ba * 64 + lane;
            if (ba == 0) v0 = -1e30f;
            else if (ba == 1) v1 = -1e30f;
            else if (ba == 2) v2 = -1e30f;
            else v3 = -1e30f;
        }
    }
    __syncthreads();
    if (half) return;

    unsigned short t0 = tab[lane], t1 = tab[lane + 64];
    float c0 = -1e30f, c1 = -1e30f;
    int id0 = 0, id1 = 0;
    {
        int i = t0 >> 5, j = t0 & 31;
        c0 = sv[slot][i] + sv[slot][32 + j];
        id0 = sidx[slot][i] * NK_ + sidx[slot][32 + j];
    }
    if (t1 != 0xFFFF) {
        int i = t1 >> 5, j = t1 & 31;
        c1 = sv[slot][i] + sv[slot][32 + j];
        id1 = sidx[slot][i] * NK_ + sidx[slot][32 + j];
    }

    float* fo = fs + task * 32;
    int*   vo = vi + task * 32;
#pragma unroll 1
    for (int t = 0; t < 32; ++t) {
        float bm = c0; int sel = 0;
        if (c1 > bm) { bm = c1; sel = 1; }
        float wm = bm;
#pragma unroll
        for (int o = 32; o >= 1; o >>= 1) wm = fmaxf(wm, __shfl_xor(wm, o));
        unsigned long long msk = __ballot(bm == wm);
        int owner = (int)__builtin_ctzll(msk);
        if (lane == owner) {
            fo[t] = wm;
            vo[t] = sel ? id1 : id0;
            if (sel) c1 = -1e30f; else c0 = -1e30f;
        }
    }
}

// ---------------- softmax + gather(bf16 table) + residual ----------------
__global__ __launch_bounds__(384)
void pkm_out_bf16(const float* __restrict__ fs, const int* __restrict__ vi,
                  const unsigned short* __restrict__ valsb, const float* __restrict__ x1,
                  float* __restrict__ outp) {
    int n = blockIdx.x, tid = threadIdx.x;
    __shared__ float w[128];
    __shared__ int   rows[128];
    __shared__ float red[3 * 768];
    if (tid < 128) {
        float e = fs[(long)n * 128 + tid];
        rows[tid] = vi[(long)n * 128 + tid];
        float m = e;
#pragma unroll
        for (int o = 16; o >= 1; o >>= 1) m = fmaxf(m, __shfl_xor(m, o));
        float ex = __expf(e - m);
        float s = ex;
#pragma unroll
        for (int o = 16; o >= 1; o >>= 1) s += __shfl_xor(s, o);
        w[tid] = ex / s;
    }
    __syncthreads();
    int slot = tid / 96, chunk = tid % 96;
    float a0=0.f,a1=0.f,a2=0.f,a3=0.f,a4=0.f,a5=0.f,a6=0.f,a7=0.f;
#pragma unroll 4
    for (int e = 0; e < 32; ++e) {
        int er = e * 4 + slot;
        float wgt = w[er];
        long ro = (long)rows[er] * D_;
        bf16x8 v = *(const bf16x8*)(valsb + ro + chunk * 8);
        a0 += wgt * bf2f((unsigned short)v[0]); a1 += wgt * bf2f((unsigned short)v[1]);
        a2 += wgt * bf2f((unsigned short)v[2]); a3 += wgt * bf2f((unsigned short)v[3]);
        a4 += wgt * bf2f((unsigned short)v[4]); a5 += wgt * bf2f((unsigned short)v[5]);
        a6 += wgt * bf2f((unsigned short)v[6]); a7 += wgt * bf2f((unsigned short)v[7]);
    }
    if (slot > 0) {
        float* rp = &red[(slot - 1) * 768 + chunk * 8];
        rp[0]=a0; rp[1]=a1; rp[2]=a2; rp[3]=a3; rp[4]=a4; rp[5]=a5; rp[6]=a6; rp[7]=a7;
    }
    __syncthreads();
    if (slot == 0) {
        long o = (long)n * D_ + chunk * 8;
        const float* r0 = &red[chunk * 8];
        const float* r1 = &red[768 + chunk * 8];
        const float* r2 = &red[1536 + chunk * 8];
        f32x4 xa = *(const f32x4*)(x1 + o);
        f32x4 xb = *(const f32x4*)(x1 + o + 4);
        f32x4 o1 = { a0 + r0[0] + r1[0] + r2[0] + xa[0], a1 + r0[1] + r1[1] + r2[1] + xa[1],
                     a2 + r0[2] + r1[2] + r2[2] + xa[2], a3 + r0[3] + r1[3] + r2[3] + xa[3] };
        f32x4 o2 = { a4 + r0[4] + r1[4] + r2[4] + xb[0], a5 + r0[5] + r1[5] + r2[5] + xb[1],
                     a6 + r0[6] + r1[6] + r2[6] + xb[2], a7 + r0[7] + r1[7] + r2[7] + xb[3] };
        *(f32x4*)(outp + o) = o1;
        *(f32x4*)(outp + o + 4) = o2;
    }
}

// ---------------- fallback: f32-table gather ----------------
__global__ __launch_bounds__(384)
void pkm_out_f32(const float* __restrict__ fs, const int* __restrict__ vi,
                 const float* __restrict__ values, const float* __restrict__ x1,
                 float* __restrict__ outp) {
    int n = blockIdx.x, tid = threadIdx.x;
    __shared__ float w[128];
    __shared__ int   rows[128];
    __shared__ float red[768];
    if (tid < 128) {
        float e = fs[(long)n * 128 + tid];
        rows[tid] = vi[(long)n * 128 + tid];
        float m = e;
#pragma unroll
        for (int o = 16; o >= 1; o >>= 1) m = fmaxf(m, __shfl_xor(m, o));
        float ex = __expf(e - m);
        float s = ex;
#pragma unroll
        for (int o = 16; o >= 1; o >>= 1) s += __shfl_xor(s, o);
        w[tid] = ex / s;
    }
    __syncthreads();
    int slot = tid / 192, chunk = tid % 192;
    float a0 = 0.f, a1 = 0.f, a2 = 0.f, a3 = 0.f;
#pragma unroll 4
    for (int e = 0; e < 64; ++e) {
        int er = e * 2 + slot;
        float wgt = w[er];
        long ro = (long)rows[er] * D_;
        f32x4 v = *(const f32x4*)(values + ro + chunk * 4);
        a0 += wgt * v[0]; a1 += wgt * v[1]; a2 += wgt * v[2]; a3 += wgt * v[3];
    }
    if (slot == 1) {
        f32x4 t = {a0, a1, a2, a3};
        *(f32x4*)&red[chunk * 4] = t;
    }
    __syncthreads();
    if (slot == 0) {
        f32x4 o = *(const f32x4*)&red[chunk * 4];
        f32x4 xr = *(const f32x4*)(x1 + (long)n * D_ + chunk * 4);
        o[0] += a0 + xr[0]; o[1] += a1 + xr[1]; o[2] += a2 + xr[2]; o[3] += a3 + xr[3];
        *(f32x4*)(outp + (long)n * D_ + chunk * 4) = o;
    }
}

extern "C" void kernel_launch(void* const* d_in, const int* in_sizes, int n_in,
                              void* d_out, int out_size, void* d_ws, size_t ws_size,
                              hipStream_t stream) {
    const float* x    = (const float*)d_in[0];
    const float* wq   = (const float*)d_in[1];
    const float* bq   = (const float*)d_in[2];
    const float* wk   = (const float*)d_in[3];
    const float* bk   = (const float*)d_in[4];
    const float* wv   = (const float*)d_in[5];
    const float* bv   = (const float*)d_in[6];
    const float* wo   = (const float*)d_in[7];
    const float* bo   = (const float*)d_in[8];
    const float* ln1g = (const float*)d_in[9];
    const float* ln1b = (const float*)d_in[10];
    const float* ln2g = (const float*)d_in[11];
    const float* ln2b = (const float*)d_in[12];
    const float* pwq  = (const float*)d_in[13];
    const float* bng  = (const float*)d_in[14];
    const float* bnb  = (const float*)d_in[15];
    const float* keys = (const float*)d_in[16];
    const float* vals = (const float*)d_in[17];
    float* out = (float*)d_out;

    char* p = (char*)d_ws;
    auto alloc = [&](size_t bytes) -> char* {
        char* r = p; p += (bytes + 255) & ~(size_t)255; return r;
    };
    unsigned short* wqkvT = (unsigned short*)alloc((size_t)3 * D_ * D_ * 2);
    unsigned short* woT   = (unsigned short*)alloc((size_t)D_ * D_ * 2);
    unsigned short* pwqT  = (unsigned short*)alloc((size_t)D_ * DQ_ * 2);
    unsigned short* keyB  = (unsigned short*)alloc((size_t)NKEYS * 2);
    unsigned short* h1    = (unsigned short*)alloc((size_t)NT * D_ * 2);
    unsigned short* qkvB  = (unsigned short*)alloc((size_t)NT * QKVLD * 2);
    unsigned short* aout  = (unsigned short*)alloc((size_t)NT * D_ * 2);
    float* x1             = (float*)alloc((size_t)NT * D_ * 4);
    unsigned short* h2    = (unsigned short*)alloc((size_t)NT * D_ * 2);
    float* qf             = (float*)alloc((size_t)NT * DQ_ * 4);
    float* pS             = (float*)alloc((size_t)64 * DQ_ * 4);
    float* pSS            = (float*)alloc((size_t)64 * DQ_ * 4);
    float* mu             = (float*)alloc((size_t)DQ_ * 4);
    float* rs             = (float*)alloc((size_t)DQ_ * 4);
    unsigned short* qnB   = (unsigned short*)alloc((size_t)NT * DQ_ * 2);
    float* dots           = (float*)alloc((size_t)NT * 2048 * 4);
    float* fsb            = (float*)alloc((size_t)NT * PH_ * 32 * 4);
    int*   vib            = (int*)alloc((size_t)NT * PH_ * 32 * 4);

    // bf16 values table if workspace allows (~100.7 MB more)
    size_t used = (size_t)(p - (char*)d_ws);
    size_t vbytes = (size_t)NK_ * NK_ * D_ * 2;
    bool useBf = (used + vbytes + 256) <= ws_size;
    unsigned short* valsb = nullptr;
    if (useBf) valsb = (unsigned short*)alloc(vbytes);

    // weight prep (5 transposes + keys convert, one launch)
    transpose_kernel<<<dim3(24, 32, 6), dim3(32, 8), 0, stream>>>(
        wq, wk, wv, wo, pwq, keys, wqkvT, woT, pwqT, keyB);

    // LN1
    ln_kernel<<<NT, 256, 0, stream>>>(x, ln1g, ln1b, h1);
    // merged QKV GEMM -> qkvB; hosts first half of the values-table conversion
    gemm_kernel<<<dim3(32, useBf ? 52 : 36), 256, 0, stream>>>(
        h1, D_, wqkvT, D_, bq, bk, bv, nullptr, nullptr, qkvB, QKVLD, D_, 2,
        useBf ? vals : nullptr, valsb, 0L, 36);
    // attention (MFMA flash, 2-wave blocks, grid 768)
    attn_mfma_kernel<<<dim3(B_ * H_, T_ / 32), 128, 0, stream>>>(qkvB, aout);
    // output projection + residual
    gemm_kernel<<<dim3(32, 12), 256, 0, stream>>>(
        aout, D_, woT, D_, bo, nullptr, nullptr, x, x1, nullptr, D_, D_, 0,
        nullptr, nullptr, 0L, 0);
    // LN2 + PKM query GEMM; hosts second half of the values-table conversion
    ln_kernel<<<NT, 256, 0, stream>>>(x1, ln2g, ln2b, h2);
    gemm_kernel<<<dim3(32, useBf ? 32 : 16), 256, 0, stream>>>(
        h2, D_, pwqT, D_, nullptr, nullptr, nullptr, nullptr, qf, nullptr, DQ_, D_, 0,
        useBf ? vals : nullptr, valsb, CVHALF, 16);
    // BatchNorm (256 partial blocks)
    bn_part<<<dim3(64, 4), 256, 0, stream>>>(qf, pS, pSS);
    bn_fin<<<4, 256, 0, stream>>>(pS, pSS, mu, rs);
    qn_kernel<<<(NT * DQ_) / 256, 256, 0, stream>>>(qf, mu, rs, bng, bnb, qnB);
    // dots: 8 batched GEMMs via blockIdx.z
    gemm_kernel<<<dim3(32, 4, 8), 256, 0, stream>>>(
        qnB, DQ_, keyB, 256, nullptr, nullptr, nullptr, nullptr, dots, nullptr, 2048, DHK_, 1,
        nullptr, nullptr, 0L, 0);
    // fused top-k (2 waves per task)
    topk_kernel<<<(NT * PH_) / 2, 256, 0, stream>>>(dots, fsb, vib);
    // softmax + gather + residual
    if (useBf)
        pkm_out_bf16<<<NT, 384, 0, stream>>>(fsb, vib, valsb, x1, out);
    else
        pkm_out_f32<<<NT, 384, 0, stream>>>(fsb, vib, vals, x1, out);
}

// Round 11
// 269.907 us; speedup vs baseline: 1.2131x; 1.2131x over previous
//
#include <hip/hip_runtime.h>
#include <hip/hip_bf16.h>

#define B_  2
#define T_  1024
#define D_  768
#define H_  12
#define NT  2048        // B*T
#define DQ_ 1024
#define PH_ 4
#define NK_ 256
#define TK_ 32
#define DHK_ 128
#define QKVLD 2304      // merged QKV row stride
#define CVHALF 25165824L // half the values table, elements
#define NKEYS (PH_ * NK_ * 2 * DHK_)

typedef __attribute__((ext_vector_type(8))) short bf16x8;
typedef __attribute__((ext_vector_type(4))) float f32x4;
typedef __attribute__((ext_vector_type(2))) float f32x2;

static __device__ __forceinline__ unsigned short f2bf(float f) {
    union { float f; unsigned u; } c; c.f = f;
    unsigned r = (c.u + 0x7fffu + ((c.u >> 16) & 1u)) >> 16;
    return (unsigned short)r;
}

static __device__ __forceinline__ float bf2f(unsigned short s) {
    union { unsigned u; float f; } c; c.u = ((unsigned)s) << 16;
    return c.f;
}

// ---------------- batched weight prep: 5 transposes + keys convert, one launch ----------------
__global__ void transpose_kernel(const float* __restrict__ wq, const float* __restrict__ wk,
                                 const float* __restrict__ wv, const float* __restrict__ wo,
                                 const float* __restrict__ pwq, const float* __restrict__ keys,
                                 unsigned short* __restrict__ wqkvT,
                                 unsigned short* __restrict__ woT,
                                 unsigned short* __restrict__ pwqT,
                                 unsigned short* __restrict__ keyB) {
    __shared__ float t[32][33];
    int z = blockIdx.z;
    if (z == 5) {   // keys: pure convert, 2 elems/thread
        long i = (((long)blockIdx.y * 24 + blockIdx.x) * 256 + threadIdx.y * 32 + threadIdx.x) * 2;
        if (i + 1 < NKEYS) { keyB[i] = f2bf(keys[i]); keyB[i + 1] = f2bf(keys[i + 1]); }
        return;
    }
    const float* W; unsigned short* Wt; int N;
    if (z == 0)      { W = wq;  Wt = wqkvT;              N = 768; }
    else if (z == 1) { W = wk;  Wt = wqkvT + 589824;     N = 768; }
    else if (z == 2) { W = wv;  Wt = wqkvT + 2 * 589824; N = 768; }
    else if (z == 3) { W = wo;  Wt = woT;                N = 768; }
    else             { W = pwq; Wt = pwqT;               N = 1024; }
    int k0 = blockIdx.x * 32, n0 = blockIdx.y * 32;
    if (n0 >= N) return;
    int tx = threadIdx.x, ty = threadIdx.y;
#pragma unroll
    for (int i = 0; i < 4; ++i)
        t[ty + 8 * i][tx] = W[(long)(k0 + ty + 8 * i) * N + n0 + tx];
    __syncthreads();
#pragma unroll
    for (int i = 0; i < 4; ++i)
        Wt[(long)(n0 + ty + 8 * i) * 768 + k0 + tx] = f2bf(t[tx][ty + 8 * i]);
}

// ---------------- LayerNorm: x f32 [rows][768] -> bf16 ----------------
__global__ __launch_bounds__(256)
void ln_kernel(const float* __restrict__ x, const float* __restrict__ g,
               const float* __restrict__ b, unsigned short* __restrict__ out) {
    int row = blockIdx.x, tid = threadIdx.x;
    const float* xr = x + (long)row * D_;
    float v0 = xr[tid], v1 = xr[tid + 256], v2 = xr[tid + 512];
    float s = v0 + v1 + v2, ss = v0 * v0 + v1 * v1 + v2 * v2;
#pragma unroll
    for (int o = 1; o < 64; o <<= 1) { s += __shfl_xor(s, o); ss += __shfl_xor(ss, o); }
    __shared__ float ps[4], pss[4];
    int wid = tid >> 6, lane = tid & 63;
    if (lane == 0) { ps[wid] = s; pss[wid] = ss; }
    __syncthreads();
    s = ps[0] + ps[1] + ps[2] + ps[3];
    ss = pss[0] + pss[1] + pss[2] + pss[3];
    float mean = s * (1.f / D_);
    float var = ss * (1.f / D_) - mean * mean;
    float rs = rsqrtf(var + 1e-5f);
    unsigned short* orow = out + (long)row * D_;
    orow[tid]       = f2bf((v0 - mean) * rs * g[tid]       + b[tid]);
    orow[tid + 256] = f2bf((v1 - mean) * rs * g[tid + 256] + b[tid + 256]);
    orow[tid + 512] = f2bf((v2 - mean) * rs * g[tid + 512] + b[tid + 512]);
}

// ---------------- MFMA GEMM: C[M,N] = A[M,K](bf16,lda) @ Bt[N,K](bf16,ldb)^T ----------------
// 64x64 tile, 4 waves, BK=32.
// zmode 1: dots batching over blockIdx.z. zmode 2: merged QKV (bias segment select).
// If cvin != nullptr, blocks with blockIdx.y >= cvy0 grid-stride convert a table slice
// (fp8 e4m3 via HW cvt_pk).
__global__ __launch_bounds__(256)
void gemm_kernel(const unsigned short* __restrict__ A, int lda,
                 const unsigned short* __restrict__ Bt, int ldb,
                 const float* __restrict__ bias,
                 const float* __restrict__ bias2,
                 const float* __restrict__ bias3,
                 const float* __restrict__ res,
                 float* __restrict__ outF,
                 unsigned short* __restrict__ outB,
                 int ldc, int K, int zmode,
                 const float* __restrict__ cvin,
                 unsigned char* __restrict__ cvout,
                 long cvbase, int cvy0) {
    if (cvin && (int)blockIdx.y >= cvy0) {
        long stride = (long)(gridDim.y - cvy0) * gridDim.x * 256 * 8;
        long idx = cvbase +
            ((long)((blockIdx.y - cvy0) * gridDim.x + blockIdx.x) * 256 + threadIdx.x) * 8;
        long end = cvbase + CVHALF;
#pragma unroll 2
        for (; idx < end; idx += stride) {
            f32x4 a = *(const f32x4*)(cvin + idx);
            f32x4 b = *(const f32x4*)(cvin + idx + 4);
            int lo = __builtin_amdgcn_cvt_pk_fp8_f32(a[0], a[1], 0, false);
            lo = __builtin_amdgcn_cvt_pk_fp8_f32(a[2], a[3], lo, true);
            int hi = __builtin_amdgcn_cvt_pk_fp8_f32(b[0], b[1], 0, false);
            hi = __builtin_amdgcn_cvt_pk_fp8_f32(b[2], b[3], hi, true);
            *(uint2*)(cvout + idx) = make_uint2((unsigned)lo, (unsigned)hi);
        }
        return;
    }
    if (zmode == 1) {
        int z = blockIdx.z, ph = z >> 1, half = z & 1;
        A    += half * 512 + ph * 128;
        Bt   += ph * 65536 + half * 128;
        outF += ph * 512 + half * 256;
    }
    const int tid = threadIdx.x;
    const int w = tid >> 6, lane = tid & 63;
    const int ls = lane & 15, g = lane >> 4;
    const int m0 = blockIdx.x * 64, n0 = blockIdx.y * 64;

    __shared__ unsigned short As[64][40];
    __shared__ unsigned short Bs[64][40];

    f32x4 acc[4];
#pragma unroll
    for (int c = 0; c < 4; ++c) acc[c] = (f32x4){0.f, 0.f, 0.f, 0.f};

    const int lrow = tid >> 2, lseg = tid & 3;
    const unsigned short* gA = A + (long)(m0 + lrow) * lda + lseg * 8;
    const unsigned short* gB = Bt + (long)(n0 + lrow) * ldb + lseg * 8;

    for (int kt = 0; kt < K; kt += 32) {
        __syncthreads();
        *(int4*)&As[lrow][lseg * 8] = *(const int4*)(gA + kt);
        *(int4*)&Bs[lrow][lseg * 8] = *(const int4*)(gB + kt);
        __syncthreads();
        bf16x8 bfr = *(const bf16x8*)&Bs[w * 16 + ls][g * 8];
#pragma unroll
        for (int c = 0; c < 4; ++c) {
            bf16x8 afr = *(const bf16x8*)&As[c * 16 + ls][g * 8];
            acc[c] = __builtin_amdgcn_mfma_f32_16x16x32_bf16(afr, bfr, acc[c], 0, 0, 0);
        }
    }
#pragma unroll
    for (int c = 0; c < 4; ++c) {
#pragma unroll
        for (int r = 0; r < 4; ++r) {
            int row = m0 + c * 16 + g * 4 + r;
            int col = n0 + w * 16 + ls;
            float v = acc[c][r];
            if (bias) {
                const float* bp = bias; int cc = col;
                if (zmode == 2) {
                    int sel = col >= 1536 ? 2 : (col >= 768 ? 1 : 0);
                    bp = sel == 0 ? bias : (sel == 1 ? bias2 : bias3);
                    cc = col - sel * 768;
                }
                v += bp[cc];
            }
            long off = (long)row * ldc + col;
            if (res)  v += res[off];
            if (outF) outF[off] = v;
            if (outB) outB[off] = f2bf(v);
        }
    }
}

// ---------------- MFMA flash attention (bf16 in/out, f32 online softmax) ----------------
// 4-wave blocks, 64 q-rows (staging amortized over the bigger block).
__global__ __launch_bounds__(256)
void attn_mfma_kernel(const unsigned short* __restrict__ qkv,
                      unsigned short* __restrict__ outg) {
    int bh = blockIdx.x, bb = bh / H_, hh = bh % H_;
    int q0 = blockIdx.y * 64;
    int tid = threadIdx.x, wv = tid >> 6, lane = tid & 63;
    int ls = lane & 15, g = lane >> 4;

    __shared__ unsigned short Klds[128 * 64];
    __shared__ unsigned short Vlds[64 * 128];
    __shared__ unsigned short Plds[4][16 * 128];

    const unsigned short* qrow = qkv + (long)(bb * T_ + q0 + wv * 16 + ls) * QKVLD + hh * 64 + g * 8;
    bf16x8 qf0 = *(const bf16x8*)qrow;
    bf16x8 qf1 = *(const bf16x8*)(qrow + 32);

    f32x4 o_acc[4];
#pragma unroll
    for (int nf = 0; nf < 4; ++nf) o_acc[nf] = (f32x4){0.f, 0.f, 0.f, 0.f};
    float mrun[4] = {-1e30f, -1e30f, -1e30f, -1e30f};
    float lrun[4] = {0.f, 0.f, 0.f, 0.f};

    char* pbase = (char*)&Plds[wv][0];

    for (int kt = 0; kt < T_ / 128; ++kt) {
        int kvb = kt * 128;
        __syncthreads();
#pragma unroll
        for (int i = 0; i < 4; ++i) {
            int c = tid + i * 256;
            int kv = c >> 3, dc = c & 7;
            bf16x8 kd = *(const bf16x8*)(qkv + (long)(bb * T_ + kvb + kv) * QKVLD + 768 + hh * 64 + dc * 8);
            *(bf16x8*)((char*)Klds + ((kv * 128 + dc * 16) ^ ((kv & 7) << 4))) = kd;
        }
        {
            int d0 = (tid & 7) * 8, kvq = tid >> 3;
            const unsigned short* vb = qkv + (long)(bb * T_ + kvb + kvq * 4) * QKVLD + 1536 + hh * 64 + d0;
            bf16x8 r0 = *(const bf16x8*)(vb);
            bf16x8 r1 = *(const bf16x8*)(vb + QKVLD);
            bf16x8 r2 = *(const bf16x8*)(vb + 2 * QKVLD);
            bf16x8 r3 = *(const bf16x8*)(vb + 3 * QKVLD);
#pragma unroll
            for (int j = 0; j < 8; ++j) {
                unsigned lo = (unsigned)(unsigned short)r0[j] | ((unsigned)(unsigned short)r1[j] << 16);
                unsigned hi = (unsigned)(unsigned short)r2[j] | ((unsigned)(unsigned short)r3[j] << 16);
                int d = d0 + j;
                *(uint2*)((char*)Vlds + ((d * 256 + kvq * 8) ^ ((d & 7) << 4))) = make_uint2(lo, hi);
            }
        }
        __syncthreads();

        f32x4 sa[8];
#pragma unroll
        for (int f = 0; f < 8; ++f) sa[f] = (f32x4){0.f, 0.f, 0.f, 0.f};
#pragma unroll
        for (int f = 0; f < 8; ++f) {
            int kv = f * 16 + ls;
            bf16x8 b0 = *(const bf16x8*)((char*)Klds + ((kv * 128 + g * 16) ^ ((kv & 7) << 4)));
            bf16x8 b1 = *(const bf16x8*)((char*)Klds + ((kv * 128 + 64 + g * 16) ^ ((kv & 7) << 4)));
            sa[f] = __builtin_amdgcn_mfma_f32_16x16x32_bf16(qf0, b0, sa[f], 0, 0, 0);
            sa[f] = __builtin_amdgcn_mfma_f32_16x16x32_bf16(qf1, b1, sa[f], 0, 0, 0);
        }

        float pw[8][4];
#pragma unroll
        for (int f = 0; f < 8; ++f)
#pragma unroll
            for (int r = 0; r < 4; ++r) pw[f][r] = sa[f][r] * 0.125f;
        float nm[4], fac[4];
#pragma unroll
        for (int r = 0; r < 4; ++r) {
            float m = pw[0][r];
#pragma unroll
            for (int f = 1; f < 8; ++f) m = fmaxf(m, pw[f][r]);
            m = fmaxf(m, __shfl_xor(m, 1));
            m = fmaxf(m, __shfl_xor(m, 2));
            m = fmaxf(m, __shfl_xor(m, 4));
            m = fmaxf(m, __shfl_xor(m, 8));
            nm[r] = fmaxf(mrun[r], m);
            fac[r] = __expf(mrun[r] - nm[r]);
            mrun[r] = nm[r];
        }
#pragma unroll
        for (int r = 0; r < 4; ++r) {
            float s = 0.f;
#pragma unroll
            for (int f = 0; f < 8; ++f) { float e = __expf(pw[f][r] - nm[r]); pw[f][r] = e; s += e; }
            s += __shfl_xor(s, 1); s += __shfl_xor(s, 2);
            s += __shfl_xor(s, 4); s += __shfl_xor(s, 8);
            lrun[r] = lrun[r] * fac[r] + s;
#pragma unroll
            for (int nf = 0; nf < 4; ++nf) o_acc[nf][r] *= fac[r];
        }

#pragma unroll
        for (int f = 0; f < 8; ++f)
#pragma unroll
            for (int r = 0; r < 4; ++r) {
                int qr = g * 4 + r, col = ls + 16 * f;
                *(unsigned short*)(pbase + ((qr * 256 + col * 2) ^ ((qr & 7) << 4))) = f2bf(pw[f][r]);
            }

#pragma unroll
        for (int ks = 0; ks < 4; ++ks) {
            bf16x8 pa = *(const bf16x8*)(pbase + ((ls * 256 + ks * 64 + g * 16) ^ ((ls & 7) << 4)));
#pragma unroll
            for (int nf = 0; nf < 4; ++nf) {
                int d = nf * 16 + ls;
                bf16x8 bv = *(const bf16x8*)((char*)Vlds + ((d * 256 + ks * 64 + g * 16) ^ ((d & 7) << 4)));
                o_acc[nf] = __builtin_amdgcn_mfma_f32_16x16x32_bf16(pa, bv, o_acc[nf], 0, 0, 0);
            }
        }
    }

    float inv[4];
#pragma unroll
    for (int r = 0; r < 4; ++r) inv[r] = 1.f / lrun[r];
#pragma unroll
    for (int nf = 0; nf < 4; ++nf)
#pragma unroll
        for (int r = 0; r < 4; ++r) {
            long row = bb * T_ + q0 + wv * 16 + g * 4 + r;
            outg[row * D_ + hh * 64 + nf * 16 + ls] = f2bf(o_acc[nf][r] * inv[r]);
        }
}

// ---------------- BatchNorm over tokens (deterministic two-stage, 256 blocks) ----------------
__global__ __launch_bounds__(256)
void bn_part(const float* __restrict__ qf, float* __restrict__ pS, float* __restrict__ pSS) {
    int c = blockIdx.y * 256 + threadIdx.x;
    int r0 = blockIdx.x * 32;
    float s = 0.f, ss = 0.f;
#pragma unroll 4
    for (int r = 0; r < 32; ++r) {
        float v = qf[(long)(r0 + r) * DQ_ + c];
        s += v; ss += v * v;
    }
    pS[(long)blockIdx.x * DQ_ + c] = s;
    pSS[(long)blockIdx.x * DQ_ + c] = ss;
}

__global__ __launch_bounds__(256)
void bn_fin(const float* __restrict__ pS, const float* __restrict__ pSS,
            float* __restrict__ mu, float* __restrict__ rs) {
    int c = blockIdx.x * 256 + threadIdx.x;
    float s = 0.f, ss = 0.f;
#pragma unroll 8
    for (int i = 0; i < 64; ++i) { s += pS[(long)i * DQ_ + c]; ss += pSS[(long)i * DQ_ + c]; }
    float m = s * (1.f / NT);
    float var = ss * (1.f / NT) - m * m;
    mu[c] = m;
    rs[c] = rsqrtf(var + 1e-5f);
}

__global__ __launch_bounds__(256)
void qn_kernel(const float* __restrict__ qf, const float* __restrict__ mu,
               const float* __restrict__ rs, const float* __restrict__ g,
               const float* __restrict__ b, unsigned short* __restrict__ qn) {
    int i = blockIdx.x * 256 + threadIdx.x;
    int c = i & (DQ_ - 1);
    qn[i] = f2bf((qf[i] - mu[c]) * rs[c] * g[c] + b[c]);
}

// ---------------- fused top-k: 2 waves per task (parallel halves) ----------------
__global__ __launch_bounds__(256)
void topk_kernel(const float* __restrict__ dots, float* __restrict__ fs, int* __restrict__ vi) {
    static const unsigned short tab[128] = {
        0,1,2,3,4,5,6,7,8,9,10,11,12,13,14,15,16,17,18,19,20,21,22,23,24,25,26,27,28,29,30,31,
        32,33,34,35,36,37,38,39,40,41,42,43,44,45,46,47,
        64,65,66,67,68,69,70,71,72,73,
        96,97,98,99,100,101,102,103,
        128,129,130,131,132,133,
        160,161,162,163,164,
        192,193,194,195,
        224,225,226,227,
        256,257,258,
        288,289,290,
        320,321, 352,353, 384,385, 416,417, 448,449, 480,481,
        512,544,576,608,640,672,704,736,768,800,832,864,896,928,960,992,
        0xFFFF,0xFFFF,0xFFFF,0xFFFF,0xFFFF,0xFFFF,0xFFFF,0xFFFF,0xFFFF
    };
    __shared__ float sv[2][64];
    __shared__ int   sidx[2][64];
    int tid = threadIdx.x, wv = tid >> 6, lane = tid & 63;
    int slot = wv >> 1, half = wv & 1;
    long task = (long)blockIdx.x * 2 + slot;
    const float* d = dots + (task >> 2) * 2048 + (task & 3) * 512 + half * 256;

    float v0 = d[lane], v1 = d[lane + 64], v2 = d[lane + 128], v3 = d[lane + 192];
#pragma unroll 1
    for (int t = 0; t < 32; ++t) {
        float bm = v0; int ba = 0;
        if (v1 > bm) { bm = v1; ba = 1; }
        if (v2 > bm) { bm = v2; ba = 2; }
        if (v3 > bm) { bm = v3; ba = 3; }
        float wm = bm;
#pragma unroll
        for (int o = 32; o >= 1; o >>= 1) wm = fmaxf(wm, __shfl_xor(wm, o));
        unsigned long long msk = __ballot(bm == wm);
        int owner = (int)__builtin_ctzll(msk);
        if (lane == owner) {
            sv[slot][half * 32 + t] = wm;
            sidx[slot][half * 32 + t] = ba * 64 + lane;
            if (ba == 0) v0 = -1e30f;
            else if (ba == 1) v1 = -1e30f;
            else if (ba == 2) v2 = -1e30f;
            else v3 = -1e30f;
        }
    }
    __syncthreads();
    if (half) return;

    unsigned short t0 = tab[lane], t1 = tab[lane + 64];
    float c0 = -1e30f, c1 = -1e30f;
    int id0 = 0, id1 = 0;
    {
        int i = t0 >> 5, j = t0 & 31;
        c0 = sv[slot][i] + sv[slot][32 + j];
        id0 = sidx[slot][i] * NK_ + sidx[slot][32 + j];
    }
    if (t1 != 0xFFFF) {
        int i = t1 >> 5, j = t1 & 31;
        c1 = sv[slot][i] + sv[slot][32 + j];
        id1 = sidx[slot][i] * NK_ + sidx[slot][32 + j];
    }

    float* fo = fs + task * 32;
    int*   vo = vi + task * 32;
#pragma unroll 1
    for (int t = 0; t < 32; ++t) {
        float bm = c0; int sel = 0;
        if (c1 > bm) { bm = c1; sel = 1; }
        float wm = bm;
#pragma unroll
        for (int o = 32; o >= 1; o >>= 1) wm = fmaxf(wm, __shfl_xor(wm, o));
        unsigned long long msk = __ballot(bm == wm);
        int owner = (int)__builtin_ctzll(msk);
        if (lane == owner) {
            fo[t] = wm;
            vo[t] = sel ? id1 : id0;
            if (sel) c1 = -1e30f; else c0 = -1e30f;
        }
    }
}

// ---------------- softmax + gather(fp8 e4m3 table) + residual ----------------
// 384 threads = 4 row-slots x 96 chunks of 8 fp8 (8B/lane); HW cvt_pk decode.
__global__ __launch_bounds__(384)
void pkm_out_fp8(const float* __restrict__ fs, const int* __restrict__ vi,
                 const unsigned char* __restrict__ vals8, const float* __restrict__ x1,
                 float* __restrict__ outp) {
    int n = blockIdx.x, tid = threadIdx.x;
    __shared__ float w[128];
    __shared__ int   rows[128];
    __shared__ float red[3 * 768];
    if (tid < 128) {
        float e = fs[(long)n * 128 + tid];
        rows[tid] = vi[(long)n * 128 + tid];
        float m = e;
#pragma unroll
        for (int o = 16; o >= 1; o >>= 1) m = fmaxf(m, __shfl_xor(m, o));
        float ex = __expf(e - m);
        float s = ex;
#pragma unroll
        for (int o = 16; o >= 1; o >>= 1) s += __shfl_xor(s, o);
        w[tid] = ex / s;
    }
    __syncthreads();
    int slot = tid / 96, chunk = tid % 96;
    float a0=0.f,a1=0.f,a2=0.f,a3=0.f,a4=0.f,a5=0.f,a6=0.f,a7=0.f;
#pragma unroll 4
    for (int e = 0; e < 32; ++e) {
        int er = e * 4 + slot;
        float wgt = w[er];
        long ro = (long)rows[er] * D_;
        uint2 v = *(const uint2*)(vals8 + ro + chunk * 8);
        f32x2 f0 = __builtin_amdgcn_cvt_pk_f32_fp8((int)v.x, false);
        f32x2 f1 = __builtin_amdgcn_cvt_pk_f32_fp8((int)v.x, true);
        f32x2 f2 = __builtin_amdgcn_cvt_pk_f32_fp8((int)v.y, false);
        f32x2 f3 = __builtin_amdgcn_cvt_pk_f32_fp8((int)v.y, true);
        a0 += wgt * f0[0]; a1 += wgt * f0[1]; a2 += wgt * f1[0]; a3 += wgt * f1[1];
        a4 += wgt * f2[0]; a5 += wgt * f2[1]; a6 += wgt * f3[0]; a7 += wgt * f3[1];
    }
    if (slot > 0) {
        float* rp = &red[(slot - 1) * 768 + chunk * 8];
        rp[0]=a0; rp[1]=a1; rp[2]=a2; rp[3]=a3; rp[4]=a4; rp[5]=a5; rp[6]=a6; rp[7]=a7;
    }
    __syncthreads();
    if (slot == 0) {
        long o = (long)n * D_ + chunk * 8;
        const float* r0 = &red[chunk * 8];
        const float* r1 = &red[768 + chunk * 8];
        const float* r2 = &red[1536 + chunk * 8];
        f32x4 xa = *(const f32x4*)(x1 + o);
        f32x4 xb = *(const f32x4*)(x1 + o + 4);
        f32x4 o1 = { a0 + r0[0] + r1[0] + r2[0] + xa[0], a1 + r0[1] + r1[1] + r2[1] + xa[1],
                     a2 + r0[2] + r1[2] + r2[2] + xa[2], a3 + r0[3] + r1[3] + r2[3] + xa[3] };
        f32x4 o2 = { a4 + r0[4] + r1[4] + r2[4] + xb[0], a5 + r0[5] + r1[5] + r2[5] + xb[1],
                     a6 + r0[6] + r1[6] + r2[6] + xb[2], a7 + r0[7] + r1[7] + r2[7] + xb[3] };
        *(f32x4*)(outp + o) = o1;
        *(f32x4*)(outp + o + 4) = o2;
    }
}

// ---------------- fallback: f32-table gather ----------------
__global__ __launch_bounds__(384)
void pkm_out_f32(const float* __restrict__ fs, const int* __restrict__ vi,
                 const float* __restrict__ values, const float* __restrict__ x1,
                 float* __restrict__ outp) {
    int n = blockIdx.x, tid = threadIdx.x;
    __shared__ float w[128];
    __shared__ int   rows[128];
    __shared__ float red[768];
    if (tid < 128) {
        float e = fs[(long)n * 128 + tid];
        rows[tid] = vi[(long)n * 128 + tid];
        float m = e;
#pragma unroll
        for (int o = 16; o >= 1; o >>= 1) m = fmaxf(m, __shfl_xor(m, o));
        float ex = __expf(e - m);
        float s = ex;
#pragma unroll
        for (int o = 16; o >= 1; o >>= 1) s += __shfl_xor(s, o);
        w[tid] = ex / s;
    }
    __syncthreads();
    int slot = tid / 192, chunk = tid % 192;
    float a0 = 0.f, a1 = 0.f, a2 = 0.f, a3 = 0.f;
#pragma unroll 4
    for (int e = 0; e < 64; ++e) {
        int er = e * 2 + slot;
        float wgt = w[er];
        long ro = (long)rows[er] * D_;
        f32x4 v = *(const f32x4*)(values + ro + chunk * 4);
        a0 += wgt * v[0]; a1 += wgt * v[1]; a2 += wgt * v[2]; a3 += wgt * v[3];
    }
    if (slot == 1) {
        f32x4 t = {a0, a1, a2, a3};
        *(f32x4*)&red[chunk * 4] = t;
    }
    __syncthreads();
    if (slot == 0) {
        f32x4 o = *(const f32x4*)&red[chunk * 4];
        f32x4 xr = *(const f32x4*)(x1 + (long)n * D_ + chunk * 4);
        o[0] += a0 + xr[0]; o[1] += a1 + xr[1]; o[2] += a2 + xr[2]; o[3] += a3 + xr[3];
        *(f32x4*)(outp + (long)n * D_ + chunk * 4) = o;
    }
}

extern "C" void kernel_launch(void* const* d_in, const int* in_sizes, int n_in,
                              void* d_out, int out_size, void* d_ws, size_t ws_size,
                              hipStream_t stream) {
    const float* x    = (const float*)d_in[0];
    const float* wq   = (const float*)d_in[1];
    const float* bq   = (const float*)d_in[2];
    const float* wk   = (const float*)d_in[3];
    const float* bk   = (const float*)d_in[4];
    const float* wv   = (const float*)d_in[5];
    const float* bv   = (const float*)d_in[6];
    const float* wo   = (const float*)d_in[7];
    const float* bo   = (const float*)d_in[8];
    const float* ln1g = (const float*)d_in[9];
    const float* ln1b = (const float*)d_in[10];
    const float* ln2g = (const float*)d_in[11];
    const float* ln2b = (const float*)d_in[12];
    const float* pwq  = (const float*)d_in[13];
    const float* bng  = (const float*)d_in[14];
    const float* bnb  = (const float*)d_in[15];
    const float* keys = (const float*)d_in[16];
    const float* vals = (const float*)d_in[17];
    float* out = (float*)d_out;

    char* p = (char*)d_ws;
    auto alloc = [&](size_t bytes) -> char* {
        char* r = p; p += (bytes + 255) & ~(size_t)255; return r;
    };
    unsigned short* wqkvT = (unsigned short*)alloc((size_t)3 * D_ * D_ * 2);
    unsigned short* woT   = (unsigned short*)alloc((size_t)D_ * D_ * 2);
    unsigned short* pwqT  = (unsigned short*)alloc((size_t)D_ * DQ_ * 2);
    unsigned short* keyB  = (unsigned short*)alloc((size_t)NKEYS * 2);
    unsigned short* h1    = (unsigned short*)alloc((size_t)NT * D_ * 2);
    unsigned short* qkvB  = (unsigned short*)alloc((size_t)NT * QKVLD * 2);
    unsigned short* aout  = (unsigned short*)alloc((size_t)NT * D_ * 2);
    float* x1             = (float*)alloc((size_t)NT * D_ * 4);
    unsigned short* h2    = (unsigned short*)alloc((size_t)NT * D_ * 2);
    float* qf             = (float*)alloc((size_t)NT * DQ_ * 4);
    float* pS             = (float*)alloc((size_t)64 * DQ_ * 4);
    float* pSS            = (float*)alloc((size_t)64 * DQ_ * 4);
    float* mu             = (float*)alloc((size_t)DQ_ * 4);
    float* rs             = (float*)alloc((size_t)DQ_ * 4);
    unsigned short* qnB   = (unsigned short*)alloc((size_t)NT * DQ_ * 2);
    float* dots           = (float*)alloc((size_t)NT * 2048 * 4);
    float* fsb            = (float*)alloc((size_t)NT * PH_ * 32 * 4);
    int*   vib            = (int*)alloc((size_t)NT * PH_ * 32 * 4);

    // fp8 values table if workspace allows (~50.4 MB more)
    size_t used = (size_t)(p - (char*)d_ws);
    size_t vbytes = (size_t)NK_ * NK_ * D_;
    bool useTab = (used + vbytes + 256) <= ws_size;
    unsigned char* vals8 = nullptr;
    if (useTab) vals8 = (unsigned char*)alloc(vbytes);

    // weight prep (5 transposes + keys convert, one launch)
    transpose_kernel<<<dim3(24, 32, 6), dim3(32, 8), 0, stream>>>(
        wq, wk, wv, wo, pwq, keys, wqkvT, woT, pwqT, keyB);

    // LN1
    ln_kernel<<<NT, 256, 0, stream>>>(x, ln1g, ln1b, h1);
    // merged QKV GEMM -> qkvB; hosts first half of the values-table conversion
    gemm_kernel<<<dim3(32, useTab ? 52 : 36), 256, 0, stream>>>(
        h1, D_, wqkvT, D_, bq, bk, bv, nullptr, nullptr, qkvB, QKVLD, D_, 2,
        useTab ? vals : nullptr, vals8, 0L, 36);
    // attention (MFMA flash, 4-wave blocks)
    attn_mfma_kernel<<<dim3(B_ * H_, T_ / 64), 256, 0, stream>>>(qkvB, aout);
    // output projection + residual
    gemm_kernel<<<dim3(32, 12), 256, 0, stream>>>(
        aout, D_, woT, D_, bo, nullptr, nullptr, x, x1, nullptr, D_, D_, 0,
        nullptr, nullptr, 0L, 0);
    // LN2 + PKM query GEMM; hosts second half of the values-table conversion
    ln_kernel<<<NT, 256, 0, stream>>>(x1, ln2g, ln2b, h2);
    gemm_kernel<<<dim3(32, useTab ? 32 : 16), 256, 0, stream>>>(
        h2, D_, pwqT, D_, nullptr, nullptr, nullptr, nullptr, qf, nullptr, DQ_, D_, 0,
        useTab ? vals : nullptr, vals8, CVHALF, 16);
    // BatchNorm (256 partial blocks)
    bn_part<<<dim3(64, 4), 256, 0, stream>>>(qf, pS, pSS);
    bn_fin<<<4, 256, 0, stream>>>(pS, pSS, mu, rs);
    qn_kernel<<<(NT * DQ_) / 256, 256, 0, stream>>>(qf, mu, rs, bng, bnb, qnB);
    // dots: 8 batched GEMMs via blockIdx.z
    gemm_kernel<<<dim3(32, 4, 8), 256, 0, stream>>>(
        qnB, DQ_, keyB, 256, nullptr, nullptr, nullptr, nullptr, dots, nullptr, 2048, DHK_, 1,
        nullptr, nullptr, 0L, 0);
    // fused top-k (2 waves per task)
    topk_kernel<<<(NT * PH_) / 2, 256, 0, stream>>>(dots, fsb, vib);
    // softmax + gather + residual
    if (useTab)
        pkm_out_fp8<<<NT, 384, 0, stream>>>(fsb, vib, vals8, x1, out);
    else
        pkm_out_f32<<<NT, 384, 0, stream>>>(fsb, vib, vals, x1, out);
}

// Round 12
// 269.475 us; speedup vs baseline: 1.2150x; 1.0016x over previous
//
#include <hip/hip_runtime.h>
#include <hip/hip_bf16.h>

#define B_  2
#define T_  1024
#define D_  768
#define H_  12
#define NT  2048        // B*T
#define DQ_ 1024
#define PH_ 4
#define NK_ 256
#define TK_ 32
#define DHK_ 128
#define QKVLD 2304      // merged QKV row stride
#define CVHALF 25165824L // half the values table, elements
#define NKEYS (PH_ * NK_ * 2 * DHK_)

typedef __attribute__((ext_vector_type(8))) short bf16x8;
typedef __attribute__((ext_vector_type(4))) float f32x4;
typedef __attribute__((ext_vector_type(2))) float f32x2;

static __device__ __forceinline__ unsigned short f2bf(float f) {
    union { float f; unsigned u; } c; c.f = f;
    unsigned r = (c.u + 0x7fffu + ((c.u >> 16) & 1u)) >> 16;
    return (unsigned short)r;
}

static __device__ __forceinline__ float bf2f(unsigned short s) {
    union { unsigned u; float f; } c; c.u = ((unsigned)s) << 16;
    return c.f;
}

// ---------------- batched weight prep: 5 transposes + keys convert, one launch ----------------
__global__ void transpose_kernel(const float* __restrict__ wq, const float* __restrict__ wk,
                                 const float* __restrict__ wv, const float* __restrict__ wo,
                                 const float* __restrict__ pwq, const float* __restrict__ keys,
                                 unsigned short* __restrict__ wqkvT,
                                 unsigned short* __restrict__ woT,
                                 unsigned short* __restrict__ pwqT,
                                 unsigned short* __restrict__ keyB) {
    __shared__ float t[32][33];
    int z = blockIdx.z;
    if (z == 5) {   // keys: pure convert, 2 elems/thread
        long i = (((long)blockIdx.y * 24 + blockIdx.x) * 256 + threadIdx.y * 32 + threadIdx.x) * 2;
        if (i + 1 < NKEYS) { keyB[i] = f2bf(keys[i]); keyB[i + 1] = f2bf(keys[i + 1]); }
        return;
    }
    const float* W; unsigned short* Wt; int N;
    if (z == 0)      { W = wq;  Wt = wqkvT;              N = 768; }
    else if (z == 1) { W = wk;  Wt = wqkvT + 589824;     N = 768; }
    else if (z == 2) { W = wv;  Wt = wqkvT + 2 * 589824; N = 768; }
    else if (z == 3) { W = wo;  Wt = woT;                N = 768; }
    else             { W = pwq; Wt = pwqT;               N = 1024; }
    int k0 = blockIdx.x * 32, n0 = blockIdx.y * 32;
    if (n0 >= N) return;
    int tx = threadIdx.x, ty = threadIdx.y;
#pragma unroll
    for (int i = 0; i < 4; ++i)
        t[ty + 8 * i][tx] = W[(long)(k0 + ty + 8 * i) * N + n0 + tx];
    __syncthreads();
#pragma unroll
    for (int i = 0; i < 4; ++i)
        Wt[(long)(n0 + ty + 8 * i) * 768 + k0 + tx] = f2bf(t[tx][ty + 8 * i]);
}

// ---------------- LayerNorm: x f32 [rows][768] -> bf16 ----------------
__global__ __launch_bounds__(256)
void ln_kernel(const float* __restrict__ x, const float* __restrict__ g,
               const float* __restrict__ b, unsigned short* __restrict__ out) {
    int row = blockIdx.x, tid = threadIdx.x;
    const float* xr = x + (long)row * D_;
    float v0 = xr[tid], v1 = xr[tid + 256], v2 = xr[tid + 512];
    float s = v0 + v1 + v2, ss = v0 * v0 + v1 * v1 + v2 * v2;
#pragma unroll
    for (int o = 1; o < 64; o <<= 1) { s += __shfl_xor(s, o); ss += __shfl_xor(ss, o); }
    __shared__ float ps[4], pss[4];
    int wid = tid >> 6, lane = tid & 63;
    if (lane == 0) { ps[wid] = s; pss[wid] = ss; }
    __syncthreads();
    s = ps[0] + ps[1] + ps[2] + ps[3];
    ss = pss[0] + pss[1] + pss[2] + pss[3];
    float mean = s * (1.f / D_);
    float var = ss * (1.f / D_) - mean * mean;
    float rs = rsqrtf(var + 1e-5f);
    unsigned short* orow = out + (long)row * D_;
    orow[tid]       = f2bf((v0 - mean) * rs * g[tid]       + b[tid]);
    orow[tid + 256] = f2bf((v1 - mean) * rs * g[tid + 256] + b[tid + 256]);
    orow[tid + 512] = f2bf((v2 - mean) * rs * g[tid + 512] + b[tid + 512]);
}

// ---------------- MFMA GEMM: C[M,N] = A[M,K](bf16,lda) @ Bt[N,K](bf16,ldb)^T ----------------
// 64x64 tile, 4 waves, BK=32.
// zmode 1: dots batching over blockIdx.z. zmode 2: merged QKV (bias segment select).
// If cvin != nullptr, blocks with blockIdx.y >= cvy0 grid-stride convert a table slice
// (fp8 e4m3 via HW cvt_pk).
__global__ __launch_bounds__(256)
void gemm_kernel(const unsigned short* __restrict__ A, int lda,
                 const unsigned short* __restrict__ Bt, int ldb,
                 const float* __restrict__ bias,
                 const float* __restrict__ bias2,
                 const float* __restrict__ bias3,
                 const float* __restrict__ res,
                 float* __restrict__ outF,
                 unsigned short* __restrict__ outB,
                 int ldc, int K, int zmode,
                 const float* __restrict__ cvin,
                 unsigned char* __restrict__ cvout,
                 long cvbase, int cvy0) {
    if (cvin && (int)blockIdx.y >= cvy0) {
        long stride = (long)(gridDim.y - cvy0) * gridDim.x * 256 * 8;
        long idx = cvbase +
            ((long)((blockIdx.y - cvy0) * gridDim.x + blockIdx.x) * 256 + threadIdx.x) * 8;
        long end = cvbase + CVHALF;
#pragma unroll 2
        for (; idx < end; idx += stride) {
            f32x4 a = *(const f32x4*)(cvin + idx);
            f32x4 b = *(const f32x4*)(cvin + idx + 4);
            int lo = __builtin_amdgcn_cvt_pk_fp8_f32(a[0], a[1], 0, false);
            lo = __builtin_amdgcn_cvt_pk_fp8_f32(a[2], a[3], lo, true);
            int hi = __builtin_amdgcn_cvt_pk_fp8_f32(b[0], b[1], 0, false);
            hi = __builtin_amdgcn_cvt_pk_fp8_f32(b[2], b[3], hi, true);
            *(uint2*)(cvout + idx) = make_uint2((unsigned)lo, (unsigned)hi);
        }
        return;
    }
    if (zmode == 1) {
        int z = blockIdx.z, ph = z >> 1, half = z & 1;
        A    += half * 512 + ph * 128;
        Bt   += ph * 65536 + half * 128;
        outF += ph * 512 + half * 256;
    }
    const int tid = threadIdx.x;
    const int w = tid >> 6, lane = tid & 63;
    const int ls = lane & 15, g = lane >> 4;
    const int m0 = blockIdx.x * 64, n0 = blockIdx.y * 64;

    __shared__ unsigned short As[64][40];
    __shared__ unsigned short Bs[64][40];

    f32x4 acc[4];
#pragma unroll
    for (int c = 0; c < 4; ++c) acc[c] = (f32x4){0.f, 0.f, 0.f, 0.f};

    const int lrow = tid >> 2, lseg = tid & 3;
    const unsigned short* gA = A + (long)(m0 + lrow) * lda + lseg * 8;
    const unsigned short* gB = Bt + (long)(n0 + lrow) * ldb + lseg * 8;

    for (int kt = 0; kt < K; kt += 32) {
        __syncthreads();
        *(int4*)&As[lrow][lseg * 8] = *(const int4*)(gA + kt);
        *(int4*)&Bs[lrow][lseg * 8] = *(const int4*)(gB + kt);
        __syncthreads();
        bf16x8 bfr = *(const bf16x8*)&Bs[w * 16 + ls][g * 8];
#pragma unroll
        for (int c = 0; c < 4; ++c) {
            bf16x8 afr = *(const bf16x8*)&As[c * 16 + ls][g * 8];
            acc[c] = __builtin_amdgcn_mfma_f32_16x16x32_bf16(afr, bfr, acc[c], 0, 0, 0);
        }
    }
#pragma unroll
    for (int c = 0; c < 4; ++c) {
#pragma unroll
        for (int r = 0; r < 4; ++r) {
            int row = m0 + c * 16 + g * 4 + r;
            int col = n0 + w * 16 + ls;
            float v = acc[c][r];
            if (bias) {
                const float* bp = bias; int cc = col;
                if (zmode == 2) {
                    int sel = col >= 1536 ? 2 : (col >= 768 ? 1 : 0);
                    bp = sel == 0 ? bias : (sel == 1 ? bias2 : bias3);
                    cc = col - sel * 768;
                }
                v += bp[cc];
            }
            long off = (long)row * ldc + col;
            if (res)  v += res[off];
            if (outF) outF[off] = v;
            if (outB) outB[off] = f2bf(v);
        }
    }
}

// ---------------- MFMA flash attention (bf16 in/out, f32 online softmax) ----------------
// 4-wave blocks, 64 q-rows. T14 async-stage (prefetch next K/V tile into regs under
// compute), T13 defer-max (THR=8), T5 setprio around MFMA clusters.
__global__ __launch_bounds__(256)
void attn_mfma_kernel(const unsigned short* __restrict__ qkv,
                      unsigned short* __restrict__ outg) {
    int bh = blockIdx.x, bb = bh / H_, hh = bh % H_;
    int q0 = blockIdx.y * 64;
    int tid = threadIdx.x, wv = tid >> 6, lane = tid & 63;
    int ls = lane & 15, g = lane >> 4;

    __shared__ unsigned short Klds[128 * 64];
    __shared__ unsigned short Vlds[64 * 128];
    __shared__ unsigned short Plds[4][16 * 128];

    const unsigned short* qrow = qkv + (long)(bb * T_ + q0 + wv * 16 + ls) * QKVLD + hh * 64 + g * 8;
    bf16x8 qf0 = *(const bf16x8*)qrow;
    bf16x8 qf1 = *(const bf16x8*)(qrow + 32);

    f32x4 o_acc[4];
#pragma unroll
    for (int nf = 0; nf < 4; ++nf) o_acc[nf] = (f32x4){0.f, 0.f, 0.f, 0.f};
    float mrun[4] = {-1e30f, -1e30f, -1e30f, -1e30f};
    float lrun[4] = {0.f, 0.f, 0.f, 0.f};

    char* pbase = (char*)&Plds[wv][0];
    const int d0 = (tid & 7) * 8, kvq = tid >> 3;   // V-load geometry

    // prefetch registers for the next K/V tile
    bf16x8 kreg[4], vreg[4];
    auto loadKV = [&](int kvb) {
#pragma unroll
        for (int i = 0; i < 4; ++i) {
            int c = tid + i * 256;
            kreg[i] = *(const bf16x8*)(qkv + (long)(bb * T_ + kvb + (c >> 3)) * QKVLD + 768 + hh * 64 + (c & 7) * 8);
        }
        const unsigned short* vb = qkv + (long)(bb * T_ + kvb + kvq * 4) * QKVLD + 1536 + hh * 64 + d0;
#pragma unroll
        for (int i = 0; i < 4; ++i) vreg[i] = *(const bf16x8*)(vb + i * QKVLD);
    };

    loadKV(0);
    for (int kt = 0; kt < T_ / 128; ++kt) {
        __syncthreads();                  // previous tile fully consumed
        // ---- write prefetched K -> LDS (swizzled) ----
#pragma unroll
        for (int i = 0; i < 4; ++i) {
            int c = tid + i * 256;
            int kv = c >> 3, dc = c & 7;
            *(bf16x8*)((char*)Klds + ((kv * 128 + dc * 16) ^ ((kv & 7) << 4))) = kreg[i];
        }
        // ---- write prefetched V transposed -> LDS (swizzled) ----
#pragma unroll
        for (int j = 0; j < 8; ++j) {
            unsigned lo = (unsigned)(unsigned short)vreg[0][j] | ((unsigned)(unsigned short)vreg[1][j] << 16);
            unsigned hi = (unsigned)(unsigned short)vreg[2][j] | ((unsigned)(unsigned short)vreg[3][j] << 16);
            int d = d0 + j;
            *(uint2*)((char*)Vlds + ((d * 256 + kvq * 8) ^ ((d & 7) << 4))) = make_uint2(lo, hi);
        }
        __syncthreads();
        // ---- issue next tile's loads; they complete under this tile's compute ----
        if (kt + 1 < T_ / 128) loadKV((kt + 1) * 128);

        // ---- S = Q @ K^T ----
        f32x4 sa[8];
#pragma unroll
        for (int f = 0; f < 8; ++f) sa[f] = (f32x4){0.f, 0.f, 0.f, 0.f};
        __builtin_amdgcn_s_setprio(1);
#pragma unroll
        for (int f = 0; f < 8; ++f) {
            int kv = f * 16 + ls;
            bf16x8 b0 = *(const bf16x8*)((char*)Klds + ((kv * 128 + g * 16) ^ ((kv & 7) << 4)));
            bf16x8 b1 = *(const bf16x8*)((char*)Klds + ((kv * 128 + 64 + g * 16) ^ ((kv & 7) << 4)));
            sa[f] = __builtin_amdgcn_mfma_f32_16x16x32_bf16(qf0, b0, sa[f], 0, 0, 0);
            sa[f] = __builtin_amdgcn_mfma_f32_16x16x32_bf16(qf1, b1, sa[f], 0, 0, 0);
        }
        __builtin_amdgcn_s_setprio(0);

        // ---- online softmax with defer-max (THR=8) ----
        float pw[8][4];
#pragma unroll
        for (int f = 0; f < 8; ++f)
#pragma unroll
            for (int r = 0; r < 4; ++r) pw[f][r] = sa[f][r] * 0.125f;
#pragma unroll
        for (int r = 0; r < 4; ++r) {
            float m = pw[0][r];
#pragma unroll
            for (int f = 1; f < 8; ++f) m = fmaxf(m, pw[f][r]);
            m = fmaxf(m, __shfl_xor(m, 1));
            m = fmaxf(m, __shfl_xor(m, 2));
            m = fmaxf(m, __shfl_xor(m, 4));
            m = fmaxf(m, __shfl_xor(m, 8));
            if (m > mrun[r] + 8.f) {          // rescale only on big max growth
                float fac = __expf(mrun[r] - m);
                lrun[r] *= fac;
#pragma unroll
                for (int nf = 0; nf < 4; ++nf) o_acc[nf][r] *= fac;
                mrun[r] = m;
            }
            float s = 0.f;
#pragma unroll
            for (int f = 0; f < 8; ++f) { float e = __expf(pw[f][r] - mrun[r]); pw[f][r] = e; s += e; }
            s += __shfl_xor(s, 1); s += __shfl_xor(s, 2);
            s += __shfl_xor(s, 4); s += __shfl_xor(s, 8);
            lrun[r] += s;
        }

        // ---- P -> LDS (wave-private) ----
#pragma unroll
        for (int f = 0; f < 8; ++f)
#pragma unroll
            for (int r = 0; r < 4; ++r) {
                int qr = g * 4 + r, col = ls + 16 * f;
                *(unsigned short*)(pbase + ((qr * 256 + col * 2) ^ ((qr & 7) << 4))) = f2bf(pw[f][r]);
            }

        // ---- O += P @ V ----
        __builtin_amdgcn_s_setprio(1);
#pragma unroll
        for (int ks = 0; ks < 4; ++ks) {
            bf16x8 pa = *(const bf16x8*)(pbase + ((ls * 256 + ks * 64 + g * 16) ^ ((ls & 7) << 4)));
#pragma unroll
            for (int nf = 0; nf < 4; ++nf) {
                int d = nf * 16 + ls;
                bf16x8 bv = *(const bf16x8*)((char*)Vlds + ((d * 256 + ks * 64 + g * 16) ^ ((d & 7) << 4)));
                o_acc[nf] = __builtin_amdgcn_mfma_f32_16x16x32_bf16(pa, bv, o_acc[nf], 0, 0, 0);
            }
        }
        __builtin_amdgcn_s_setprio(0);
    }

    float inv[4];
#pragma unroll
    for (int r = 0; r < 4; ++r) inv[r] = 1.f / lrun[r];
#pragma unroll
    for (int nf = 0; nf < 4; ++nf)
#pragma unroll
        for (int r = 0; r < 4; ++r) {
            long row = bb * T_ + q0 + wv * 16 + g * 4 + r;
            outg[row * D_ + hh * 64 + nf * 16 + ls] = f2bf(o_acc[nf][r] * inv[r]);
        }
}

// ---------------- BatchNorm over tokens (deterministic two-stage, 256 blocks) ----------------
__global__ __launch_bounds__(256)
void bn_part(const float* __restrict__ qf, float* __restrict__ pS, float* __restrict__ pSS) {
    int c = blockIdx.y * 256 + threadIdx.x;
    int r0 = blockIdx.x * 32;
    float s = 0.f, ss = 0.f;
#pragma unroll 4
    for (int r = 0; r < 32; ++r) {
        float v = qf[(long)(r0 + r) * DQ_ + c];
        s += v; ss += v * v;
    }
    pS[(long)blockIdx.x * DQ_ + c] = s;
    pSS[(long)blockIdx.x * DQ_ + c] = ss;
}

__global__ __launch_bounds__(256)
void bn_fin(const float* __restrict__ pS, const float* __restrict__ pSS,
            float* __restrict__ mu, float* __restrict__ rs) {
    int c = blockIdx.x * 256 + threadIdx.x;
    float s = 0.f, ss = 0.f;
#pragma unroll 8
    for (int i = 0; i < 64; ++i) { s += pS[(long)i * DQ_ + c]; ss += pSS[(long)i * DQ_ + c]; }
    float m = s * (1.f / NT);
    float var = ss * (1.f / NT) - m * m;
    mu[c] = m;
    rs[c] = rsqrtf(var + 1e-5f);
}

__global__ __launch_bounds__(256)
void qn_kernel(const float* __restrict__ qf, const float* __restrict__ mu,
               const float* __restrict__ rs, const float* __restrict__ g,
               const float* __restrict__ b, unsigned short* __restrict__ qn) {
    int i = blockIdx.x * 256 + threadIdx.x;
    int c = i & (DQ_ - 1);
    qn[i] = f2bf((qf[i] - mu[c]) * rs[c] * g[c] + b[c]);
}

// ---------------- fused top-k: 2 waves per task (parallel halves) ----------------
__global__ __launch_bounds__(256)
void topk_kernel(const float* __restrict__ dots, float* __restrict__ fs, int* __restrict__ vi) {
    static const unsigned short tab[128] = {
        0,1,2,3,4,5,6,7,8,9,10,11,12,13,14,15,16,17,18,19,20,21,22,23,24,25,26,27,28,29,30,31,
        32,33,34,35,36,37,38,39,40,41,42,43,44,45,46,47,
        64,65,66,67,68,69,70,71,72,73,
        96,97,98,99,100,101,102,103,
        128,129,130,131,132,133,
        160,161,162,163,164,
        192,193,194,195,
        224,225,226,227,
        256,257,258,
        288,289,290,
        320,321, 352,353, 384,385, 416,417, 448,449, 480,481,
        512,544,576,608,640,672,704,736,768,800,832,864,896,928,960,992,
        0xFFFF,0xFFFF,0xFFFF,0xFFFF,0xFFFF,0xFFFF,0xFFFF,0xFFFF,0xFFFF
    };
    __shared__ float sv[2][64];
    __shared__ int   sidx[2][64];
    int tid = threadIdx.x, wv = tid >> 6, lane = tid & 63;
    int slot = wv >> 1, half = wv & 1;
    long task = (long)blockIdx.x * 2 + slot;
    const float* d = dots + (task >> 2) * 2048 + (task & 3) * 512 + half * 256;

    float v0 = d[lane], v1 = d[lane + 64], v2 = d[lane + 128], v3 = d[lane + 192];
#pragma unroll 1
    for (int t = 0; t < 32; ++t) {
        float bm = v0; int ba = 0;
        if (v1 > bm) { bm = v1; ba = 1; }
        if (v2 > bm) { bm = v2; ba = 2; }
        if (v3 > bm) { bm = v3; ba = 3; }
        float wm = bm;
#pragma unroll
        for (int o = 32; o >= 1; o >>= 1) wm = fmaxf(wm, __shfl_xor(wm, o));
        unsigned long long msk = __ballot(bm == wm);
        int owner = (int)__builtin_ctzll(msk);
        if (lane == owner) {
            sv[slot][half * 32 + t] = wm;
            sidx[slot][half * 32 + t] = ba * 64 + lane;
            if (ba == 0) v0 = -1e30f;
            else if (ba == 1) v1 = -1e30f;
            else if (ba == 2) v2 = -1e30f;
            else v3 = -1e30f;
        }
    }
    __syncthreads();
    if (half) return;

    unsigned short t0 = tab[lane], t1 = tab[lane + 64];
    float c0 = -1e30f, c1 = -1e30f;
    int id0 = 0, id1 = 0;
    {
        int i = t0 >> 5, j = t0 & 31;
        c0 = sv[slot][i] + sv[slot][32 + j];
        id0 = sidx[slot][i] * NK_ + sidx[slot][32 + j];
    }
    if (t1 != 0xFFFF) {
        int i = t1 >> 5, j = t1 & 31;
        c1 = sv[slot][i] + sv[slot][32 + j];
        id1 = sidx[slot][i] * NK_ + sidx[slot][32 + j];
    }

    float* fo = fs + task * 32;
    int*   vo = vi + task * 32;
#pragma unroll 1
    for (int t = 0; t < 32; ++t) {
        float bm = c0; int sel = 0;
        if (c1 > bm) { bm = c1; sel = 1; }
        float wm = bm;
#pragma unroll
        for (int o = 32; o >= 1; o >>= 1) wm = fmaxf(wm, __shfl_xor(wm, o));
        unsigned long long msk = __ballot(bm == wm);
        int owner = (int)__builtin_ctzll(msk);
        if (lane == owner) {
            fo[t] = wm;
            vo[t] = sel ? id1 : id0;
            if (sel) c1 = -1e30f; else c0 = -1e30f;
        }
    }
}

// ---------------- softmax + gather(fp8 e4m3 table) + residual ----------------
__global__ __launch_bounds__(384)
void pkm_out_fp8(const float* __restrict__ fs, const int* __restrict__ vi,
                 const unsigned char* __restrict__ vals8, const float* __restrict__ x1,
                 float* __restrict__ outp) {
    int n = blockIdx.x, tid = threadIdx.x;
    __shared__ float w[128];
    __shared__ int   rows[128];
    __shared__ float red[3 * 768];
    if (tid < 128) {
        float e = fs[(long)n * 128 + tid];
        rows[tid] = vi[(long)n * 128 + tid];
        float m = e;
#pragma unroll
        for (int o = 16; o >= 1; o >>= 1) m = fmaxf(m, __shfl_xor(m, o));
        float ex = __expf(e - m);
        float s = ex;
#pragma unroll
        for (int o = 16; o >= 1; o >>= 1) s += __shfl_xor(s, o);
        w[tid] = ex / s;
    }
    __syncthreads();
    int slot = tid / 96, chunk = tid % 96;
    float a0=0.f,a1=0.f,a2=0.f,a3=0.f,a4=0.f,a5=0.f,a6=0.f,a7=0.f;
#pragma unroll 4
    for (int e = 0; e < 32; ++e) {
        int er = e * 4 + slot;
        float wgt = w[er];
        long ro = (long)rows[er] * D_;
        uint2 v = *(const uint2*)(vals8 + ro + chunk * 8);
        f32x2 f0 = __builtin_amdgcn_cvt_pk_f32_fp8((int)v.x, false);
        f32x2 f1 = __builtin_amdgcn_cvt_pk_f32_fp8((int)v.x, true);
        f32x2 f2 = __builtin_amdgcn_cvt_pk_f32_fp8((int)v.y, false);
        f32x2 f3 = __builtin_amdgcn_cvt_pk_f32_fp8((int)v.y, true);
        a0 += wgt * f0[0]; a1 += wgt * f0[1]; a2 += wgt * f1[0]; a3 += wgt * f1[1];
        a4 += wgt * f2[0]; a5 += wgt * f2[1]; a6 += wgt * f3[0]; a7 += wgt * f3[1];
    }
    if (slot > 0) {
        float* rp = &red[(slot - 1) * 768 + chunk * 8];
        rp[0]=a0; rp[1]=a1; rp[2]=a2; rp[3]=a3; rp[4]=a4; rp[5]=a5; rp[6]=a6; rp[7]=a7;
    }
    __syncthreads();
    if (slot == 0) {
        long o = (long)n * D_ + chunk * 8;
        const float* r0 = &red[chunk * 8];
        const float* r1 = &red[768 + chunk * 8];
        const float* r2 = &red[1536 + chunk * 8];
        f32x4 xa = *(const f32x4*)(x1 + o);
        f32x4 xb = *(const f32x4*)(x1 + o + 4);
        f32x4 o1 = { a0 + r0[0] + r1[0] + r2[0] + xa[0], a1 + r0[1] + r1[1] + r2[1] + xa[1],
                     a2 + r0[2] + r1[2] + r2[2] + xa[2], a3 + r0[3] + r1[3] + r2[3] + xa[3] };
        f32x4 o2 = { a4 + r0[4] + r1[4] + r2[4] + xb[0], a5 + r0[5] + r1[5] + r2[5] + xb[1],
                     a6 + r0[6] + r1[6] + r2[6] + xb[2], a7 + r0[7] + r1[7] + r2[7] + xb[3] };
        *(f32x4*)(outp + o) = o1;
        *(f32x4*)(outp + o + 4) = o2;
    }
}

// ---------------- fallback: f32-table gather ----------------
__global__ __launch_bounds__(384)
void pkm_out_f32(const float* __restrict__ fs, const int* __restrict__ vi,
                 const float* __restrict__ values, const float* __restrict__ x1,
                 float* __restrict__ outp) {
    int n = blockIdx.x, tid = threadIdx.x;
    __shared__ float w[128];
    __shared__ int   rows[128];
    __shared__ float red[768];
    if (tid < 128) {
        float e = fs[(long)n * 128 + tid];
        rows[tid] = vi[(long)n * 128 + tid];
        float m = e;
#pragma unroll
        for (int o = 16; o >= 1; o >>= 1) m = fmaxf(m, __shfl_xor(m, o));
        float ex = __expf(e - m);
        float s = ex;
#pragma unroll
        for (int o = 16; o >= 1; o >>= 1) s += __shfl_xor(s, o);
        w[tid] = ex / s;
    }
    __syncthreads();
    int slot = tid / 192, chunk = tid % 192;
    float a0 = 0.f, a1 = 0.f, a2 = 0.f, a3 = 0.f;
#pragma unroll 4
    for (int e = 0; e < 64; ++e) {
        int er = e * 2 + slot;
        float wgt = w[er];
        long ro = (long)rows[er] * D_;
        f32x4 v = *(const f32x4*)(values + ro + chunk * 4);
        a0 += wgt * v[0]; a1 += wgt * v[1]; a2 += wgt * v[2]; a3 += wgt * v[3];
    }
    if (slot == 1) {
        f32x4 t = {a0, a1, a2, a3};
        *(f32x4*)&red[chunk * 4] = t;
    }
    __syncthreads();
    if (slot == 0) {
        f32x4 o = *(const f32x4*)&red[chunk * 4];
        f32x4 xr = *(const f32x4*)(x1 + (long)n * D_ + chunk * 4);
        o[0] += a0 + xr[0]; o[1] += a1 + xr[1]; o[2] += a2 + xr[2]; o[3] += a3 + xr[3];
        *(f32x4*)(outp + (long)n * D_ + chunk * 4) = o;
    }
}

extern "C" void kernel_launch(void* const* d_in, const int* in_sizes, int n_in,
                              void* d_out, int out_size, void* d_ws, size_t ws_size,
                              hipStream_t stream) {
    const float* x    = (const float*)d_in[0];
    const float* wq   = (const float*)d_in[1];
    const float* bq   = (const float*)d_in[2];
    const float* wk   = (const float*)d_in[3];
    const float* bk   = (const float*)d_in[4];
    const float* wv   = (const float*)d_in[5];
    const float* bv   = (const float*)d_in[6];
    const float* wo   = (const float*)d_in[7];
    const float* bo   = (const float*)d_in[8];
    const float* ln1g = (const float*)d_in[9];
    const float* ln1b = (const float*)d_in[10];
    const float* ln2g = (const float*)d_in[11];
    const float* ln2b = (const float*)d_in[12];
    const float* pwq  = (const float*)d_in[13];
    const float* bng  = (const float*)d_in[14];
    const float* bnb  = (const float*)d_in[15];
    const float* keys = (const float*)d_in[16];
    const float* vals = (const float*)d_in[17];
    float* out = (float*)d_out;

    char* p = (char*)d_ws;
    auto alloc = [&](size_t bytes) -> char* {
        char* r = p; p += (bytes + 255) & ~(size_t)255; return r;
    };
    unsigned short* wqkvT = (unsigned short*)alloc((size_t)3 * D_ * D_ * 2);
    unsigned short* woT   = (unsigned short*)alloc((size_t)D_ * D_ * 2);
    unsigned short* pwqT  = (unsigned short*)alloc((size_t)D_ * DQ_ * 2);
    unsigned short* keyB  = (unsigned short*)alloc((size_t)NKEYS * 2);
    unsigned short* h1    = (unsigned short*)alloc((size_t)NT * D_ * 2);
    unsigned short* qkvB  = (unsigned short*)alloc((size_t)NT * QKVLD * 2);
    unsigned short* aout  = (unsigned short*)alloc((size_t)NT * D_ * 2);
    float* x1             = (float*)alloc((size_t)NT * D_ * 4);
    unsigned short* h2    = (unsigned short*)alloc((size_t)NT * D_ * 2);
    float* qf             = (float*)alloc((size_t)NT * DQ_ * 4);
    float* pS             = (float*)alloc((size_t)64 * DQ_ * 4);
    float* pSS            = (float*)alloc((size_t)64 * DQ_ * 4);
    float* mu             = (float*)alloc((size_t)DQ_ * 4);
    float* rs             = (float*)alloc((size_t)DQ_ * 4);
    unsigned short* qnB   = (unsigned short*)alloc((size_t)NT * DQ_ * 2);
    float* dots           = (float*)alloc((size_t)NT * 2048 * 4);
    float* fsb            = (float*)alloc((size_t)NT * PH_ * 32 * 4);
    int*   vib            = (int*)alloc((size_t)NT * PH_ * 32 * 4);

    // fp8 values table if workspace allows (~50.4 MB more)
    size_t used = (size_t)(p - (char*)d_ws);
    size_t vbytes = (size_t)NK_ * NK_ * D_;
    bool useTab = (used + vbytes + 256) <= ws_size;
    unsigned char* vals8 = nullptr;
    if (useTab) vals8 = (unsigned char*)alloc(vbytes);

    // weight prep (5 transposes + keys convert, one launch)
    transpose_kernel<<<dim3(24, 32, 6), dim3(32, 8), 0, stream>>>(
        wq, wk, wv, wo, pwq, keys, wqkvT, woT, pwqT, keyB);

    // LN1
    ln_kernel<<<NT, 256, 0, stream>>>(x, ln1g, ln1b, h1);
    // merged QKV GEMM -> qkvB; hosts first half of the values-table conversion
    gemm_kernel<<<dim3(32, useTab ? 52 : 36), 256, 0, stream>>>(
        h1, D_, wqkvT, D_, bq, bk, bv, nullptr, nullptr, qkvB, QKVLD, D_, 2,
        useTab ? vals : nullptr, vals8, 0L, 36);
    // attention (MFMA flash, async-stage + defer-max + setprio)
    attn_mfma_kernel<<<dim3(B_ * H_, T_ / 64), 256, 0, stream>>>(qkvB, aout);
    // output projection + residual
    gemm_kernel<<<dim3(32, 12), 256, 0, stream>>>(
        aout, D_, woT, D_, bo, nullptr, nullptr, x, x1, nullptr, D_, D_, 0,
        nullptr, nullptr, 0L, 0);
    // LN2 + PKM query GEMM; hosts second half of the values-table conversion
    ln_kernel<<<NT, 256, 0, stream>>>(x1, ln2g, ln2b, h2);
    gemm_kernel<<<dim3(32, useTab ? 32 : 16), 256, 0, stream>>>(
        h2, D_, pwqT, D_, nullptr, nullptr, nullptr, nullptr, qf, nullptr, DQ_, D_, 0,
        useTab ? vals : nullptr, vals8, CVHALF, 16);
    // BatchNorm (256 partial blocks)
    bn_part<<<dim3(64, 4), 256, 0, stream>>>(qf, pS, pSS);
    bn_fin<<<4, 256, 0, stream>>>(pS, pSS, mu, rs);
    qn_kernel<<<(NT * DQ_) / 256, 256, 0, stream>>>(qf, mu, rs, bng, bnb, qnB);
    // dots: 8 batched GEMMs via blockIdx.z
    gemm_kernel<<<dim3(32, 4, 8), 256, 0, stream>>>(
        qnB, DQ_, keyB, 256, nullptr, nullptr, nullptr, nullptr, dots, nullptr, 2048, DHK_, 1,
        nullptr, nullptr, 0L, 0);
    // fused top-k (2 waves per task)
    topk_kernel<<<(NT * PH_) / 2, 256, 0, stream>>>(dots, fsb, vib);
    // softmax + gather + residual
    if (useTab)
        pkm_out_fp8<<<NT, 384, 0, stream>>>(fsb, vib, vals8, x1, out);
    else
        pkm_out_f32<<<NT, 384, 0, stream>>>(fsb, vib, vals, x1, out);
}

// Round 13
// 264.138 us; speedup vs baseline: 1.2396x; 1.0202x over previous
//
#include <hip/hip_runtime.h>
#include <hip/hip_bf16.h>

#define B_  2
#define T_  1024
#define D_  768
#define H_  12
#define NT  2048        // B*T
#define DQ_ 1024
#define PH_ 4
#define NK_ 256
#define TK_ 32
#define DHK_ 128
#define QKVLD 2304      // merged QKV row stride
#define CVHALF 25165824L // half the values table, elements
#define NKEYS (PH_ * NK_ * 2 * DHK_)
#define PREPBLKS 3584   // 4*576 + 768 + 512

typedef __attribute__((ext_vector_type(8))) short bf16x8;
typedef __attribute__((ext_vector_type(4))) float f32x4;
typedef __attribute__((ext_vector_type(2))) float f32x2;

static __device__ __forceinline__ unsigned short f2bf(float f) {
    union { float f; unsigned u; } c; c.f = f;
    unsigned r = (c.u + 0x7fffu + ((c.u >> 16) & 1u)) >> 16;
    return (unsigned short)r;
}

static __device__ __forceinline__ float bf2f(unsigned short s) {
    union { unsigned u; float f; } c; c.u = ((unsigned)s) << 16;
    return c.f;
}

// ---------------- LayerNorm (rows < nrows) + hosted weight prep (rows >= nrows) ----------------
// prep blocks: 5 transposes (f32->bf16, [K][N] -> [N][K]) + keys convert.
__global__ __launch_bounds__(256)
void ln_kernel(const float* __restrict__ x, const float* __restrict__ g,
               const float* __restrict__ b, unsigned short* __restrict__ out,
               int nrows,
               const float* __restrict__ wq, const float* __restrict__ wk,
               const float* __restrict__ wv, const float* __restrict__ wo,
               const float* __restrict__ pwq, const float* __restrict__ keys,
               unsigned short* __restrict__ wqkvT, unsigned short* __restrict__ woT,
               unsigned short* __restrict__ pwqT, unsigned short* __restrict__ keyB) {
    int tid = threadIdx.x;
    if ((int)blockIdx.x >= nrows) {
        int tb = blockIdx.x - nrows;
        if (tb >= 3072) {                         // keys convert: 512 blocks x 512 elems
            long i = ((long)(tb - 3072) * 256 + tid) * 2;
            if (i + 1 < NKEYS + 1) { keyB[i] = f2bf(keys[i]); keyB[i + 1] = f2bf(keys[i + 1]); }
            return;
        }
        __shared__ float t[32][33];
        const float* W; unsigned short* Wt; int N, kx, ny;
        if (tb < 2304) {
            int z = tb / 576, rem = tb % 576;
            kx = rem % 24; ny = rem / 24; N = 768;
            if (z == 0)      { W = wq; Wt = wqkvT; }
            else if (z == 1) { W = wk; Wt = wqkvT + 589824; }
            else if (z == 2) { W = wv; Wt = wqkvT + 2 * 589824; }
            else             { W = wo; Wt = woT; }
        } else {
            int rem = tb - 2304;
            kx = rem % 24; ny = rem / 24; N = 1024;
            W = pwq; Wt = pwqT;
        }
        int k0 = kx * 32, n0 = ny * 32;
        int tx = tid & 31, ty = tid >> 5;
#pragma unroll
        for (int i = 0; i < 4; ++i)
            t[ty + 8 * i][tx] = W[(long)(k0 + ty + 8 * i) * N + n0 + tx];
        __syncthreads();
#pragma unroll
        for (int i = 0; i < 4; ++i)
            Wt[(long)(n0 + ty + 8 * i) * 768 + k0 + tx] = f2bf(t[tx][ty + 8 * i]);
        return;
    }

    int row = blockIdx.x;
    const float* xr = x + (long)row * D_;
    float v0 = xr[tid], v1 = xr[tid + 256], v2 = xr[tid + 512];
    float s = v0 + v1 + v2, ss = v0 * v0 + v1 * v1 + v2 * v2;
#pragma unroll
    for (int o = 1; o < 64; o <<= 1) { s += __shfl_xor(s, o); ss += __shfl_xor(ss, o); }
    __shared__ float ps[4], pss[4];
    int wid = tid >> 6, lane = tid & 63;
    if (lane == 0) { ps[wid] = s; pss[wid] = ss; }
    __syncthreads();
    s = ps[0] + ps[1] + ps[2] + ps[3];
    ss = pss[0] + pss[1] + pss[2] + pss[3];
    float mean = s * (1.f / D_);
    float var = ss * (1.f / D_) - mean * mean;
    float rs = rsqrtf(var + 1e-5f);
    unsigned short* orow = out + (long)row * D_;
    orow[tid]       = f2bf((v0 - mean) * rs * g[tid]       + b[tid]);
    orow[tid + 256] = f2bf((v1 - mean) * rs * g[tid + 256] + b[tid + 256]);
    orow[tid + 512] = f2bf((v2 - mean) * rs * g[tid + 512] + b[tid + 512]);
}

// ---------------- MFMA GEMM: C[M,N] = A[M,K](bf16,lda) @ Bt[N,K](bf16,ldb)^T ----------------
// 64x64 tile, 4 waves, BK=32.
// zmode 1: dots batching over blockIdx.z (bf16 out). zmode 2: merged QKV (bias segment select).
// If cvin != nullptr, blocks with blockIdx.y >= cvy0 grid-stride convert a table slice (fp8).
__global__ __launch_bounds__(256)
void gemm_kernel(const unsigned short* __restrict__ A, int lda,
                 const unsigned short* __restrict__ Bt, int ldb,
                 const float* __restrict__ bias,
                 const float* __restrict__ bias2,
                 const float* __restrict__ bias3,
                 const float* __restrict__ res,
                 float* __restrict__ outF,
                 unsigned short* __restrict__ outB,
                 int ldc, int K, int zmode,
                 const float* __restrict__ cvin,
                 unsigned char* __restrict__ cvout,
                 long cvbase, int cvy0) {
    if (cvin && (int)blockIdx.y >= cvy0) {
        long stride = (long)(gridDim.y - cvy0) * gridDim.x * 256 * 8;
        long idx = cvbase +
            ((long)((blockIdx.y - cvy0) * gridDim.x + blockIdx.x) * 256 + threadIdx.x) * 8;
        long end = cvbase + CVHALF;
#pragma unroll 2
        for (; idx < end; idx += stride) {
            f32x4 a = *(const f32x4*)(cvin + idx);
            f32x4 b = *(const f32x4*)(cvin + idx + 4);
            int lo = __builtin_amdgcn_cvt_pk_fp8_f32(a[0], a[1], 0, false);
            lo = __builtin_amdgcn_cvt_pk_fp8_f32(a[2], a[3], lo, true);
            int hi = __builtin_amdgcn_cvt_pk_fp8_f32(b[0], b[1], 0, false);
            hi = __builtin_amdgcn_cvt_pk_fp8_f32(b[2], b[3], hi, true);
            *(uint2*)(cvout + idx) = make_uint2((unsigned)lo, (unsigned)hi);
        }
        return;
    }
    if (zmode == 1) {
        int z = blockIdx.z, ph = z >> 1, half = z & 1;
        A    += half * 512 + ph * 128;
        Bt   += ph * 65536 + half * 128;
        if (outF) outF += ph * 512 + half * 256;
        if (outB) outB += ph * 512 + half * 256;
    }
    const int tid = threadIdx.x;
    const int w = tid >> 6, lane = tid & 63;
    const int ls = lane & 15, g = lane >> 4;
    const int m0 = blockIdx.x * 64, n0 = blockIdx.y * 64;

    __shared__ unsigned short As[64][40];
    __shared__ unsigned short Bs[64][40];

    f32x4 acc[4];
#pragma unroll
    for (int c = 0; c < 4; ++c) acc[c] = (f32x4){0.f, 0.f, 0.f, 0.f};

    const int lrow = tid >> 2, lseg = tid & 3;
    const unsigned short* gA = A + (long)(m0 + lrow) * lda + lseg * 8;
    const unsigned short* gB = Bt + (long)(n0 + lrow) * ldb + lseg * 8;

    for (int kt = 0; kt < K; kt += 32) {
        __syncthreads();
        *(int4*)&As[lrow][lseg * 8] = *(const int4*)(gA + kt);
        *(int4*)&Bs[lrow][lseg * 8] = *(const int4*)(gB + kt);
        __syncthreads();
        bf16x8 bfr = *(const bf16x8*)&Bs[w * 16 + ls][g * 8];
#pragma unroll
        for (int c = 0; c < 4; ++c) {
            bf16x8 afr = *(const bf16x8*)&As[c * 16 + ls][g * 8];
            acc[c] = __builtin_amdgcn_mfma_f32_16x16x32_bf16(afr, bfr, acc[c], 0, 0, 0);
        }
    }
#pragma unroll
    for (int c = 0; c < 4; ++c) {
#pragma unroll
        for (int r = 0; r < 4; ++r) {
            int row = m0 + c * 16 + g * 4 + r;
            int col = n0 + w * 16 + ls;
            float v = acc[c][r];
            if (bias) {
                const float* bp = bias; int cc = col;
                if (zmode == 2) {
                    int sel = col >= 1536 ? 2 : (col >= 768 ? 1 : 0);
                    bp = sel == 0 ? bias : (sel == 1 ? bias2 : bias3);
                    cc = col - sel * 768;
                }
                v += bp[cc];
            }
            long off = (long)row * ldc + col;
            if (res)  v += res[off];
            if (outF) outF[off] = v;
            if (outB) outB[off] = f2bf(v);
        }
    }
}

// ---------------- MFMA flash attention (bf16 in/out, f32 online softmax) ----------------
// 4-wave blocks, 64 q-rows; reg-prefetch next K/V tile, defer-max, setprio.
__global__ __launch_bounds__(256)
void attn_mfma_kernel(const unsigned short* __restrict__ qkv,
                      unsigned short* __restrict__ outg) {
    int bh = blockIdx.x, bb = bh / H_, hh = bh % H_;
    int q0 = blockIdx.y * 64;
    int tid = threadIdx.x, wv = tid >> 6, lane = tid & 63;
    int ls = lane & 15, g = lane >> 4;

    __shared__ unsigned short Klds[128 * 64];
    __shared__ unsigned short Vlds[64 * 128];
    __shared__ unsigned short Plds[4][16 * 128];

    const unsigned short* qrow = qkv + (long)(bb * T_ + q0 + wv * 16 + ls) * QKVLD + hh * 64 + g * 8;
    bf16x8 qf0 = *(const bf16x8*)qrow;
    bf16x8 qf1 = *(const bf16x8*)(qrow + 32);

    f32x4 o_acc[4];
#pragma unroll
    for (int nf = 0; nf < 4; ++nf) o_acc[nf] = (f32x4){0.f, 0.f, 0.f, 0.f};
    float mrun[4] = {-1e30f, -1e30f, -1e30f, -1e30f};
    float lrun[4] = {0.f, 0.f, 0.f, 0.f};

    char* pbase = (char*)&Plds[wv][0];
    const int d0 = (tid & 7) * 8, kvq = tid >> 3;

    bf16x8 kreg[4], vreg[4];
    auto loadKV = [&](int kvb) {
#pragma unroll
        for (int i = 0; i < 4; ++i) {
            int c = tid + i * 256;
            kreg[i] = *(const bf16x8*)(qkv + (long)(bb * T_ + kvb + (c >> 3)) * QKVLD + 768 + hh * 64 + (c & 7) * 8);
        }
        const unsigned short* vb = qkv + (long)(bb * T_ + kvb + kvq * 4) * QKVLD + 1536 + hh * 64 + d0;
#pragma unroll
        for (int i = 0; i < 4; ++i) vreg[i] = *(const bf16x8*)(vb + i * QKVLD);
    };

    loadKV(0);
    for (int kt = 0; kt < T_ / 128; ++kt) {
        __syncthreads();
#pragma unroll
        for (int i = 0; i < 4; ++i) {
            int c = tid + i * 256;
            int kv = c >> 3, dc = c & 7;
            *(bf16x8*)((char*)Klds + ((kv * 128 + dc * 16) ^ ((kv & 7) << 4))) = kreg[i];
        }
#pragma unroll
        for (int j = 0; j < 8; ++j) {
            unsigned lo = (unsigned)(unsigned short)vreg[0][j] | ((unsigned)(unsigned short)vreg[1][j] << 16);
            unsigned hi = (unsigned)(unsigned short)vreg[2][j] | ((unsigned)(unsigned short)vreg[3][j] << 16);
            int d = d0 + j;
            *(uint2*)((char*)Vlds + ((d * 256 + kvq * 8) ^ ((d & 7) << 4))) = make_uint2(lo, hi);
        }
        __syncthreads();
        if (kt + 1 < T_ / 128) loadKV((kt + 1) * 128);

        f32x4 sa[8];
#pragma unroll
        for (int f = 0; f < 8; ++f) sa[f] = (f32x4){0.f, 0.f, 0.f, 0.f};
        __builtin_amdgcn_s_setprio(1);
#pragma unroll
        for (int f = 0; f < 8; ++f) {
            int kv = f * 16 + ls;
            bf16x8 b0 = *(const bf16x8*)((char*)Klds + ((kv * 128 + g * 16) ^ ((kv & 7) << 4)));
            bf16x8 b1 = *(const bf16x8*)((char*)Klds + ((kv * 128 + 64 + g * 16) ^ ((kv & 7) << 4)));
            sa[f] = __builtin_amdgcn_mfma_f32_16x16x32_bf16(qf0, b0, sa[f], 0, 0, 0);
            sa[f] = __builtin_amdgcn_mfma_f32_16x16x32_bf16(qf1, b1, sa[f], 0, 0, 0);
        }
        __builtin_amdgcn_s_setprio(0);

        float pw[8][4];
#pragma unroll
        for (int f = 0; f < 8; ++f)
#pragma unroll
            for (int r = 0; r < 4; ++r) pw[f][r] = sa[f][r] * 0.125f;
#pragma unroll
        for (int r = 0; r < 4; ++r) {
            float m = pw[0][r];
#pragma unroll
            for (int f = 1; f < 8; ++f) m = fmaxf(m, pw[f][r]);
            m = fmaxf(m, __shfl_xor(m, 1));
            m = fmaxf(m, __shfl_xor(m, 2));
            m = fmaxf(m, __shfl_xor(m, 4));
            m = fmaxf(m, __shfl_xor(m, 8));
            if (m > mrun[r] + 8.f) {
                float fac = __expf(mrun[r] - m);
                lrun[r] *= fac;
#pragma unroll
                for (int nf = 0; nf < 4; ++nf) o_acc[nf][r] *= fac;
                mrun[r] = m;
            }
            float s = 0.f;
#pragma unroll
            for (int f = 0; f < 8; ++f) { float e = __expf(pw[f][r] - mrun[r]); pw[f][r] = e; s += e; }
            s += __shfl_xor(s, 1); s += __shfl_xor(s, 2);
            s += __shfl_xor(s, 4); s += __shfl_xor(s, 8);
            lrun[r] += s;
        }

#pragma unroll
        for (int f = 0; f < 8; ++f)
#pragma unroll
            for (int r = 0; r < 4; ++r) {
                int qr = g * 4 + r, col = ls + 16 * f;
                *(unsigned short*)(pbase + ((qr * 256 + col * 2) ^ ((qr & 7) << 4))) = f2bf(pw[f][r]);
            }

        __builtin_amdgcn_s_setprio(1);
#pragma unroll
        for (int ks = 0; ks < 4; ++ks) {
            bf16x8 pa = *(const bf16x8*)(pbase + ((ls * 256 + ks * 64 + g * 16) ^ ((ls & 7) << 4)));
#pragma unroll
            for (int nf = 0; nf < 4; ++nf) {
                int d = nf * 16 + ls;
                bf16x8 bv = *(const bf16x8*)((char*)Vlds + ((d * 256 + ks * 64 + g * 16) ^ ((d & 7) << 4)));
                o_acc[nf] = __builtin_amdgcn_mfma_f32_16x16x32_bf16(pa, bv, o_acc[nf], 0, 0, 0);
            }
        }
        __builtin_amdgcn_s_setprio(0);
    }

    float inv[4];
#pragma unroll
    for (int r = 0; r < 4; ++r) inv[r] = 1.f / lrun[r];
#pragma unroll
    for (int nf = 0; nf < 4; ++nf)
#pragma unroll
        for (int r = 0; r < 4; ++r) {
            long row = bb * T_ + q0 + wv * 16 + g * 4 + r;
            outg[row * D_ + hh * 64 + nf * 16 + ls] = f2bf(o_acc[nf][r] * inv[r]);
        }
}

// ---------------- BatchNorm partials (64x4 blocks) ----------------
__global__ __launch_bounds__(256)
void bn_part(const float* __restrict__ qf, float* __restrict__ pS, float* __restrict__ pSS) {
    int c = blockIdx.y * 256 + threadIdx.x;
    int r0 = blockIdx.x * 32;
    float s = 0.f, ss = 0.f;
#pragma unroll 4
    for (int r = 0; r < 32; ++r) {
        float v = qf[(long)(r0 + r) * DQ_ + c];
        s += v; ss += v * v;
    }
    pS[(long)blockIdx.x * DQ_ + c] = s;
    pSS[(long)blockIdx.x * DQ_ + c] = ss;
}

// ---------------- fused BN finalize + normalize (deterministic redundant reduce) ----------------
__global__ __launch_bounds__(256)
void qnf_kernel(const float* __restrict__ qf, const float* __restrict__ pS,
                const float* __restrict__ pSS, const float* __restrict__ g,
                const float* __restrict__ b, unsigned short* __restrict__ qn) {
    int c = blockIdx.y * 256 + threadIdx.x;
    float s = 0.f, ss = 0.f;
#pragma unroll 8
    for (int i = 0; i < 64; ++i) { s += pS[(long)i * DQ_ + c]; ss += pSS[(long)i * DQ_ + c]; }
    float m = s * (1.f / NT);
    float rs = rsqrtf(ss * (1.f / NT) - m * m + 1e-5f);
    float gg = g[c] * rs;
    float bb = b[c] - m * gg;
    int r0 = blockIdx.x * 32;
#pragma unroll 4
    for (int r = 0; r < 32; ++r) {
        long o = (long)(r0 + r) * DQ_ + c;
        qn[o] = f2bf(qf[o] * gg + bb);
    }
}

// ---------------- fused top-k (bf16 dots): 2 waves per task (parallel halves) ----------------
__global__ __launch_bounds__(256)
void topk_kernel(const unsigned short* __restrict__ dots, float* __restrict__ fs, int* __restrict__ vi) {
    static const unsigned short tab[128] = {
        0,1,2,3,4,5,6,7,8,9,10,11,12,13,14,15,16,17,18,19,20,21,22,23,24,25,26,27,28,29,30,31,
        32,33,34,35,36,37,38,39,40,41,42,43,44,45,46,47,
        64,65,66,67,68,69,70,71,72,73,
        96,97,98,99,100,101,102,103,
        128,129,130,131,132,133,
        160,161,162,163,164,
        192,193,194,195,
        224,225,226,227,
        256,257,258,
        288,289,290,
        320,321, 352,353, 384,385, 416,417, 448,449, 480,481,
        512,544,576,608,640,672,704,736,768,800,832,864,896,928,960,992,
        0xFFFF,0xFFFF,0xFFFF,0xFFFF,0xFFFF,0xFFFF,0xFFFF,0xFFFF,0xFFFF
    };
    __shared__ float sv[2][64];
    __shared__ int   sidx[2][64];
    int tid = threadIdx.x, wv = tid >> 6, lane = tid & 63;
    int slot = wv >> 1, half = wv & 1;
    long task = (long)blockIdx.x * 2 + slot;
    const unsigned short* d = dots + (task >> 2) * 2048 + (task & 3) * 512 + half * 256;

    float v0 = bf2f(d[lane]), v1 = bf2f(d[lane + 64]);
    float v2 = bf2f(d[lane + 128]), v3 = bf2f(d[lane + 192]);
#pragma unroll 1
    for (int t = 0; t < 32; ++t) {
        float bm = v0; int ba = 0;
        if (v1 > bm) { bm = v1; ba = 1; }
        if (v2 > bm) { bm = v2; ba = 2; }
        if (v3 > bm) { bm = v3; ba = 3; }
        float wm = bm;
#pragma unroll
        for (int o = 32; o >= 1; o >>= 1) wm = fmaxf(wm, __shfl_xor(wm, o));
        unsigned long long msk = __ballot(bm == wm);
        int owner = (int)__builtin_ctzll(msk);
        if (lane == owner) {
            sv[slot][half * 32 + t] = wm;
            sidx[slot][half * 32 + t] = ba * 64 + lane;
            if (ba == 0) v0 = -1e30f;
            else if (ba == 1) v1 = -1e30f;
            else if (ba == 2) v2 = -1e30f;
            else v3 = -1e30f;
        }
    }
    __syncthreads();
    if (half) return;

    unsigned short t0 = tab[lane], t1 = tab[lane + 64];
    float c0 = -1e30f, c1 = -1e30f;
    int id0 = 0, id1 = 0;
    {
        int i = t0 >> 5, j = t0 & 31;
        c0 = sv[slot][i] + sv[slot][32 + j];
        id0 = sidx[slot][i] * NK_ + sidx[slot][32 + j];
    }
    if (t1 != 0xFFFF) {
        int i = t1 >> 5, j = t1 & 31;
        c1 = sv[slot][i] + sv[slot][32 + j];
        id1 = sidx[slot][i] * NK_ + sidx[slot][32 + j];
    }

    float* fo = fs + task * 32;
    int*   vo = vi + task * 32;
#pragma unroll 1
    for (int t = 0; t < 32; ++t) {
        float bm = c0; int sel = 0;
        if (c1 > bm) { bm = c1; sel = 1; }
        float wm = bm;
#pragma unroll
        for (int o = 32; o >= 1; o >>= 1) wm = fmaxf(wm, __shfl_xor(wm, o));
        unsigned long long msk = __ballot(bm == wm);
        int owner = (int)__builtin_ctzll(msk);
        if (lane == owner) {
            fo[t] = wm;
            vo[t] = sel ? id1 : id0;
            if (sel) c1 = -1e30f; else c0 = -1e30f;
        }
    }
}

// ---------------- softmax + gather(fp8 e4m3 table) + residual ----------------
__global__ __launch_bounds__(384)
void pkm_out_fp8(const float* __restrict__ fs, const int* __restrict__ vi,
                 const unsigned char* __restrict__ vals8, const float* __restrict__ x1,
                 float* __restrict__ outp) {
    int n = blockIdx.x, tid = threadIdx.x;
    __shared__ float w[128];
    __shared__ int   rows[128];
    __shared__ float red[3 * 768];
    if (tid < 128) {
        float e = fs[(long)n * 128 + tid];
        rows[tid] = vi[(long)n * 128 + tid];
        float m = e;
#pragma unroll
        for (int o = 16; o >= 1; o >>= 1) m = fmaxf(m, __shfl_xor(m, o));
        float ex = __expf(e - m);
        float s = ex;
#pragma unroll
        for (int o = 16; o >= 1; o >>= 1) s += __shfl_xor(s, o);
        w[tid] = ex / s;
    }
    __syncthreads();
    int slot = tid / 96, chunk = tid % 96;
    float a0=0.f,a1=0.f,a2=0.f,a3=0.f,a4=0.f,a5=0.f,a6=0.f,a7=0.f;
#pragma unroll 4
    for (int e = 0; e < 32; ++e) {
        int er = e * 4 + slot;
        float wgt = w[er];
        long ro = (long)rows[er] * D_;
        uint2 v = *(const uint2*)(vals8 + ro + chunk * 8);
        f32x2 f0 = __builtin_amdgcn_cvt_pk_f32_fp8((int)v.x, false);
        f32x2 f1 = __builtin_amdgcn_cvt_pk_f32_fp8((int)v.x, true);
        f32x2 f2 = __builtin_amdgcn_cvt_pk_f32_fp8((int)v.y, false);
        f32x2 f3 = __builtin_amdgcn_cvt_pk_f32_fp8((int)v.y, true);
        a0 += wgt * f0[0]; a1 += wgt * f0[1]; a2 += wgt * f1[0]; a3 += wgt * f1[1];
        a4 += wgt * f2[0]; a5 += wgt * f2[1]; a6 += wgt * f3[0]; a7 += wgt * f3[1];
    }
    if (slot > 0) {
        float* rp = &red[(slot - 1) * 768 + chunk * 8];
        rp[0]=a0; rp[1]=a1; rp[2]=a2; rp[3]=a3; rp[4]=a4; rp[5]=a5; rp[6]=a6; rp[7]=a7;
    }
    __syncthreads();
    if (slot == 0) {
        long o = (long)n * D_ + chunk * 8;
        const float* r0 = &red[chunk * 8];
        const float* r1 = &red[768 + chunk * 8];
        const float* r2 = &red[1536 + chunk * 8];
        f32x4 xa = *(const f32x4*)(x1 + o);
        f32x4 xb = *(const f32x4*)(x1 + o + 4);
        f32x4 o1 = { a0 + r0[0] + r1[0] + r2[0] + xa[0], a1 + r0[1] + r1[1] + r2[1] + xa[1],
                     a2 + r0[2] + r1[2] + r2[2] + xa[2], a3 + r0[3] + r1[3] + r2[3] + xa[3] };
        f32x4 o2 = { a4 + r0[4] + r1[4] + r2[4] + xb[0], a5 + r0[5] + r1[5] + r2[5] + xb[1],
                     a6 + r0[6] + r1[6] + r2[6] + xb[2], a7 + r0[7] + r1[7] + r2[7] + xb[3] };
        *(f32x4*)(outp + o) = o1;
        *(f32x4*)(outp + o + 4) = o2;
    }
}

// ---------------- fallback: f32-table gather ----------------
__global__ __launch_bounds__(384)
void pkm_out_f32(const float* __restrict__ fs, const int* __restrict__ vi,
                 const float* __restrict__ values, const float* __restrict__ x1,
                 float* __restrict__ outp) {
    int n = blockIdx.x, tid = threadIdx.x;
    __shared__ float w[128];
    __shared__ int   rows[128];
    __shared__ float red[768];
    if (tid < 128) {
        float e = fs[(long)n * 128 + tid];
        rows[tid] = vi[(long)n * 128 + tid];
        float m = e;
#pragma unroll
        for (int o = 16; o >= 1; o >>= 1) m = fmaxf(m, __shfl_xor(m, o));
        float ex = __expf(e - m);
        float s = ex;
#pragma unroll
        for (int o = 16; o >= 1; o >>= 1) s += __shfl_xor(s, o);
        w[tid] = ex / s;
    }
    __syncthreads();
    int slot = tid / 192, chunk = tid % 192;
    float a0 = 0.f, a1 = 0.f, a2 = 0.f, a3 = 0.f;
#pragma unroll 4
    for (int e = 0; e < 64; ++e) {
        int er = e * 2 + slot;
        float wgt = w[er];
        long ro = (long)rows[er] * D_;
        f32x4 v = *(const f32x4*)(values + ro + chunk * 4);
        a0 += wgt * v[0]; a1 += wgt * v[1]; a2 += wgt * v[2]; a3 += wgt * v[3];
    }
    if (slot == 1) {
        f32x4 t = {a0, a1, a2, a3};
        *(f32x4*)&red[chunk * 4] = t;
    }
    __syncthreads();
    if (slot == 0) {
        f32x4 o = *(const f32x4*)&red[chunk * 4];
        f32x4 xr = *(const f32x4*)(x1 + (long)n * D_ + chunk * 4);
        o[0] += a0 + xr[0]; o[1] += a1 + xr[1]; o[2] += a2 + xr[2]; o[3] += a3 + xr[3];
        *(f32x4*)(outp + (long)n * D_ + chunk * 4) = o;
    }
}

extern "C" void kernel_launch(void* const* d_in, const int* in_sizes, int n_in,
                              void* d_out, int out_size, void* d_ws, size_t ws_size,
                              hipStream_t stream) {
    const float* x    = (const float*)d_in[0];
    const float* wq   = (const float*)d_in[1];
    const float* bq   = (const float*)d_in[2];
    const float* wk   = (const float*)d_in[3];
    const float* bk   = (const float*)d_in[4];
    const float* wv   = (const float*)d_in[5];
    const float* bv   = (const float*)d_in[6];
    const float* wo   = (const float*)d_in[7];
    const float* bo   = (const float*)d_in[8];
    const float* ln1g = (const float*)d_in[9];
    const float* ln1b = (const float*)d_in[10];
    const float* ln2g = (const float*)d_in[11];
    const float* ln2b = (const float*)d_in[12];
    const float* pwq  = (const float*)d_in[13];
    const float* bng  = (const float*)d_in[14];
    const float* bnb  = (const float*)d_in[15];
    const float* keys = (const float*)d_in[16];
    const float* vals = (const float*)d_in[17];
    float* out = (float*)d_out;

    char* p = (char*)d_ws;
    auto alloc = [&](size_t bytes) -> char* {
        char* r = p; p += (bytes + 255) & ~(size_t)255; return r;
    };
    unsigned short* wqkvT = (unsigned short*)alloc((size_t)3 * D_ * D_ * 2);
    unsigned short* woT   = (unsigned short*)alloc((size_t)D_ * D_ * 2);
    unsigned short* pwqT  = (unsigned short*)alloc((size_t)D_ * DQ_ * 2);
    unsigned short* keyB  = (unsigned short*)alloc((size_t)NKEYS * 2);
    unsigned short* h1    = (unsigned short*)alloc((size_t)NT * D_ * 2);
    unsigned short* qkvB  = (unsigned short*)alloc((size_t)NT * QKVLD * 2);
    unsigned short* aout  = (unsigned short*)alloc((size_t)NT * D_ * 2);
    float* x1             = (float*)alloc((size_t)NT * D_ * 4);
    unsigned short* h2    = (unsigned short*)alloc((size_t)NT * D_ * 2);
    float* qf             = (float*)alloc((size_t)NT * DQ_ * 4);
    float* pS             = (float*)alloc((size_t)64 * DQ_ * 4);
    float* pSS            = (float*)alloc((size_t)64 * DQ_ * 4);
    unsigned short* qnB   = (unsigned short*)alloc((size_t)NT * DQ_ * 2);
    unsigned short* dots  = (unsigned short*)alloc((size_t)NT * 2048 * 2);
    float* fsb            = (float*)alloc((size_t)NT * PH_ * 32 * 4);
    int*   vib            = (int*)alloc((size_t)NT * PH_ * 32 * 4);

    // fp8 values table if workspace allows (~50.4 MB more)
    size_t used = (size_t)(p - (char*)d_ws);
    size_t vbytes = (size_t)NK_ * NK_ * D_;
    bool useTab = (used + vbytes + 256) <= ws_size;
    unsigned char* vals8 = nullptr;
    if (useTab) vals8 = (unsigned char*)alloc(vbytes);

    // LN1 + hosted weight prep (transposes + keys convert)
    ln_kernel<<<NT + PREPBLKS, 256, 0, stream>>>(
        x, ln1g, ln1b, h1, NT, wq, wk, wv, wo, pwq, keys, wqkvT, woT, pwqT, keyB);
    // merged QKV GEMM -> qkvB; hosts first half of the values-table conversion
    gemm_kernel<<<dim3(32, useTab ? 52 : 36), 256, 0, stream>>>(
        h1, D_, wqkvT, D_, bq, bk, bv, nullptr, nullptr, qkvB, QKVLD, D_, 2,
        useTab ? vals : nullptr, vals8, 0L, 36);
    // attention
    attn_mfma_kernel<<<dim3(B_ * H_, T_ / 64), 256, 0, stream>>>(qkvB, aout);
    // output projection + residual
    gemm_kernel<<<dim3(32, 12), 256, 0, stream>>>(
        aout, D_, woT, D_, bo, nullptr, nullptr, x, x1, nullptr, D_, D_, 0,
        nullptr, nullptr, 0L, 0);
    // LN2 (no prep)
    ln_kernel<<<NT, 256, 0, stream>>>(
        x1, ln2g, ln2b, h2, NT, nullptr, nullptr, nullptr, nullptr, nullptr, nullptr,
        nullptr, nullptr, nullptr, nullptr);
    // PKM query GEMM; hosts second half of the values-table conversion
    gemm_kernel<<<dim3(32, useTab ? 32 : 16), 256, 0, stream>>>(
        h2, D_, pwqT, D_, nullptr, nullptr, nullptr, nullptr, qf, nullptr, DQ_, D_, 0,
        useTab ? vals : nullptr, vals8, CVHALF, 16);
    // BatchNorm partials + fused finalize/normalize
    bn_part<<<dim3(64, 4), 256, 0, stream>>>(qf, pS, pSS);
    qnf_kernel<<<dim3(64, 4), 256, 0, stream>>>(qf, pS, pSS, bng, bnb, qnB);
    // dots: 8 batched GEMMs via blockIdx.z -> bf16
    gemm_kernel<<<dim3(32, 4, 8), 256, 0, stream>>>(
        qnB, DQ_, keyB, 256, nullptr, nullptr, nullptr, nullptr, nullptr, dots, 2048, DHK_, 1,
        nullptr, nullptr, 0L, 0);
    // fused top-k (bf16 dots)
    topk_kernel<<<(NT * PH_) / 2, 256, 0, stream>>>(dots, fsb, vib);
    // softmax + gather + residual
    if (useTab)
        pkm_out_fp8<<<NT, 384, 0, stream>>>(fsb, vib, vals8, x1, out);
    else
        pkm_out_f32<<<NT, 384, 0, stream>>>(fsb, vib, vals, x1, out);
}

// Round 14
// 259.187 us; speedup vs baseline: 1.2632x; 1.0191x over previous
//
#include <hip/hip_runtime.h>
#include <hip/hip_bf16.h>

#define B_  2
#define T_  1024
#define D_  768
#define H_  12
#define NT  2048        // B*T
#define DQ_ 1024
#define PH_ 4
#define NK_ 256
#define TK_ 32
#define DHK_ 128
#define QKVLD 2304      // merged QKV row stride
#define CVHALF 25165824L // half the values table, elements
#define NKEYS (PH_ * NK_ * 2 * DHK_)
#define PREPBLKS 3584   // 4*576 + 768 + 512

typedef __attribute__((ext_vector_type(8))) short bf16x8;
typedef __attribute__((ext_vector_type(4))) float f32x4;
typedef __attribute__((ext_vector_type(2))) float f32x2;

static __device__ __forceinline__ unsigned short f2bf(float f) {
    union { float f; unsigned u; } c; c.f = f;
    unsigned r = (c.u + 0x7fffu + ((c.u >> 16) & 1u)) >> 16;
    return (unsigned short)r;
}

static __device__ __forceinline__ float bf2f(unsigned short s) {
    union { unsigned u; float f; } c; c.u = ((unsigned)s) << 16;
    return c.f;
}

// ---------------- LayerNorm (rows < nrows) + hosted weight prep (rows >= nrows) ----------------
__global__ __launch_bounds__(256)
void ln_kernel(const float* __restrict__ x, const float* __restrict__ g,
               const float* __restrict__ b, unsigned short* __restrict__ out,
               int nrows,
               const float* __restrict__ wq, const float* __restrict__ wk,
               const float* __restrict__ wv, const float* __restrict__ wo,
               const float* __restrict__ pwq, const float* __restrict__ keys,
               unsigned short* __restrict__ wqkvT, unsigned short* __restrict__ woT,
               unsigned short* __restrict__ pwqT, unsigned short* __restrict__ keyB) {
    int tid = threadIdx.x;
    if ((int)blockIdx.x >= nrows) {
        int tb = blockIdx.x - nrows;
        if (tb >= 3072) {                         // keys convert: 512 blocks x 512 elems
            long i = ((long)(tb - 3072) * 256 + tid) * 2;
            if (i + 1 < NKEYS + 1) { keyB[i] = f2bf(keys[i]); keyB[i + 1] = f2bf(keys[i + 1]); }
            return;
        }
        __shared__ float t[32][33];
        const float* W; unsigned short* Wt; int N, kx, ny;
        if (tb < 2304) {
            int z = tb / 576, rem = tb % 576;
            kx = rem % 24; ny = rem / 24; N = 768;
            if (z == 0)      { W = wq; Wt = wqkvT; }
            else if (z == 1) { W = wk; Wt = wqkvT + 589824; }
            else if (z == 2) { W = wv; Wt = wqkvT + 2 * 589824; }
            else             { W = wo; Wt = woT; }
        } else {
            int rem = tb - 2304;
            kx = rem % 24; ny = rem / 24; N = 1024;
            W = pwq; Wt = pwqT;
        }
        int k0 = kx * 32, n0 = ny * 32;
        int tx = tid & 31, ty = tid >> 5;
#pragma unroll
        for (int i = 0; i < 4; ++i)
            t[ty + 8 * i][tx] = W[(long)(k0 + ty + 8 * i) * N + n0 + tx];
        __syncthreads();
#pragma unroll
        for (int i = 0; i < 4; ++i)
            Wt[(long)(n0 + ty + 8 * i) * 768 + k0 + tx] = f2bf(t[tx][ty + 8 * i]);
        return;
    }

    int row = blockIdx.x;
    const float* xr = x + (long)row * D_;
    float v0 = xr[tid], v1 = xr[tid + 256], v2 = xr[tid + 512];
    float s = v0 + v1 + v2, ss = v0 * v0 + v1 * v1 + v2 * v2;
#pragma unroll
    for (int o = 1; o < 64; o <<= 1) { s += __shfl_xor(s, o); ss += __shfl_xor(ss, o); }
    __shared__ float ps[4], pss[4];
    int wid = tid >> 6, lane = tid & 63;
    if (lane == 0) { ps[wid] = s; pss[wid] = ss; }
    __syncthreads();
    s = ps[0] + ps[1] + ps[2] + ps[3];
    ss = pss[0] + pss[1] + pss[2] + pss[3];
    float mean = s * (1.f / D_);
    float var = ss * (1.f / D_) - mean * mean;
    float rs = rsqrtf(var + 1e-5f);
    unsigned short* orow = out + (long)row * D_;
    orow[tid]       = f2bf((v0 - mean) * rs * g[tid]       + b[tid]);
    orow[tid + 256] = f2bf((v1 - mean) * rs * g[tid + 256] + b[tid + 256]);
    orow[tid + 512] = f2bf((v2 - mean) * rs * g[tid + 512] + b[tid + 512]);
}

// ---------------- MFMA GEMM (64x64 tile, 4 waves, BK=32) ----------------
__global__ __launch_bounds__(256)
void gemm_kernel(const unsigned short* __restrict__ A, int lda,
                 const unsigned short* __restrict__ Bt, int ldb,
                 const float* __restrict__ bias,
                 const float* __restrict__ bias2,
                 const float* __restrict__ bias3,
                 const float* __restrict__ res,
                 float* __restrict__ outF,
                 unsigned short* __restrict__ outB,
                 int ldc, int K, int zmode,
                 const float* __restrict__ cvin,
                 unsigned char* __restrict__ cvout,
                 long cvbase, int cvy0) {
    if (cvin && (int)blockIdx.y >= cvy0) {
        long stride = (long)(gridDim.y - cvy0) * gridDim.x * 256 * 8;
        long idx = cvbase +
            ((long)((blockIdx.y - cvy0) * gridDim.x + blockIdx.x) * 256 + threadIdx.x) * 8;
        long end = cvbase + CVHALF;
#pragma unroll 2
        for (; idx < end; idx += stride) {
            f32x4 a = *(const f32x4*)(cvin + idx);
            f32x4 b = *(const f32x4*)(cvin + idx + 4);
            int lo = __builtin_amdgcn_cvt_pk_fp8_f32(a[0], a[1], 0, false);
            lo = __builtin_amdgcn_cvt_pk_fp8_f32(a[2], a[3], lo, true);
            int hi = __builtin_amdgcn_cvt_pk_fp8_f32(b[0], b[1], 0, false);
            hi = __builtin_amdgcn_cvt_pk_fp8_f32(b[2], b[3], hi, true);
            *(uint2*)(cvout + idx) = make_uint2((unsigned)lo, (unsigned)hi);
        }
        return;
    }
    if (zmode == 1) {
        int z = blockIdx.z, ph = z >> 1, half = z & 1;
        A    += half * 512 + ph * 128;
        Bt   += ph * 65536 + half * 128;
        if (outF) outF += ph * 512 + half * 256;
        if (outB) outB += ph * 512 + half * 256;
    }
    const int tid = threadIdx.x;
    const int w = tid >> 6, lane = tid & 63;
    const int ls = lane & 15, g = lane >> 4;
    const int m0 = blockIdx.x * 64, n0 = blockIdx.y * 64;

    __shared__ unsigned short As[64][40];
    __shared__ unsigned short Bs[64][40];

    f32x4 acc[4];
#pragma unroll
    for (int c = 0; c < 4; ++c) acc[c] = (f32x4){0.f, 0.f, 0.f, 0.f};

    const int lrow = tid >> 2, lseg = tid & 3;
    const unsigned short* gA = A + (long)(m0 + lrow) * lda + lseg * 8;
    const unsigned short* gB = Bt + (long)(n0 + lrow) * ldb + lseg * 8;

    for (int kt = 0; kt < K; kt += 32) {
        __syncthreads();
        *(int4*)&As[lrow][lseg * 8] = *(const int4*)(gA + kt);
        *(int4*)&Bs[lrow][lseg * 8] = *(const int4*)(gB + kt);
        __syncthreads();
        bf16x8 bfr = *(const bf16x8*)&Bs[w * 16 + ls][g * 8];
#pragma unroll
        for (int c = 0; c < 4; ++c) {
            bf16x8 afr = *(const bf16x8*)&As[c * 16 + ls][g * 8];
            acc[c] = __builtin_amdgcn_mfma_f32_16x16x32_bf16(afr, bfr, acc[c], 0, 0, 0);
        }
    }
#pragma unroll
    for (int c = 0; c < 4; ++c) {
#pragma unroll
        for (int r = 0; r < 4; ++r) {
            int row = m0 + c * 16 + g * 4 + r;
            int col = n0 + w * 16 + ls;
            float v = acc[c][r];
            if (bias) {
                const float* bp = bias; int cc = col;
                if (zmode == 2) {
                    int sel = col >= 1536 ? 2 : (col >= 768 ? 1 : 0);
                    bp = sel == 0 ? bias : (sel == 1 ? bias2 : bias3);
                    cc = col - sel * 768;
                }
                v += bp[cc];
            }
            long off = (long)row * ldc + col;
            if (res)  v += res[off];
            if (outF) outF[off] = v;
            if (outB) outB[off] = f2bf(v);
        }
    }
}

// ---------------- MFMA flash attention: 8-wave blocks, 128 q-rows ----------------
// Halves K/V re-reads (each staged tile serves 128 q rows); grid 192 = <=1 block/CU (no tail).
// Waves 0-3 stage K, waves 4-7 stage V (register prefetch of next tile under compute).
__global__ __launch_bounds__(512)
void attn_mfma_kernel(const unsigned short* __restrict__ qkv,
                      unsigned short* __restrict__ outg) {
    int bh = blockIdx.x, bb = bh / H_, hh = bh % H_;
    int q0 = blockIdx.y * 128;
    int tid = threadIdx.x, wv = tid >> 6, lane = tid & 63;
    int ls = lane & 15, g = lane >> 4;

    __shared__ unsigned short Klds[128 * 64];     // 16 KB
    __shared__ unsigned short Vlds[64 * 128];     // 16 KB (transposed V)
    __shared__ unsigned short Plds[8][16 * 128];  // 32 KB, per-wave

    const unsigned short* qrow = qkv + (long)(bb * T_ + q0 + wv * 16 + ls) * QKVLD + hh * 64 + g * 8;
    bf16x8 qf0 = *(const bf16x8*)qrow;
    bf16x8 qf1 = *(const bf16x8*)(qrow + 32);

    f32x4 o_acc[4];
#pragma unroll
    for (int nf = 0; nf < 4; ++nf) o_acc[nf] = (f32x4){0.f, 0.f, 0.f, 0.f};
    float mrun[4] = {-1e30f, -1e30f, -1e30f, -1e30f};
    float lrun[4] = {0.f, 0.f, 0.f, 0.f};

    char* pbase = (char*)&Plds[wv][0];
    const bool doK = tid < 256;
    const int t2 = tid & 255;
    const int d0 = (t2 & 7) * 8, kvq = t2 >> 3;

    bf16x8 streg[4];
    auto loadKV = [&](int kvb) {
        if (doK) {
#pragma unroll
            for (int i = 0; i < 4; ++i) {
                int c = t2 + i * 256;
                streg[i] = *(const bf16x8*)(qkv + (long)(bb * T_ + kvb + (c >> 3)) * QKVLD + 768 + hh * 64 + (c & 7) * 8);
            }
        } else {
            const unsigned short* vb = qkv + (long)(bb * T_ + kvb + kvq * 4) * QKVLD + 1536 + hh * 64 + d0;
#pragma unroll
            for (int i = 0; i < 4; ++i) streg[i] = *(const bf16x8*)(vb + i * QKVLD);
        }
    };

    loadKV(0);
    for (int kt = 0; kt < T_ / 128; ++kt) {
        __syncthreads();                  // previous tile fully consumed
        if (doK) {
#pragma unroll
            for (int i = 0; i < 4; ++i) {
                int c = t2 + i * 256;
                int kv = c >> 3, dc = c & 7;
                *(bf16x8*)((char*)Klds + ((kv * 128 + dc * 16) ^ ((kv & 7) << 4))) = streg[i];
            }
        } else {
#pragma unroll
            for (int j = 0; j < 8; ++j) {
                unsigned lo = (unsigned)(unsigned short)streg[0][j] | ((unsigned)(unsigned short)streg[1][j] << 16);
                unsigned hi = (unsigned)(unsigned short)streg[2][j] | ((unsigned)(unsigned short)streg[3][j] << 16);
                int d = d0 + j;
                *(uint2*)((char*)Vlds + ((d * 256 + kvq * 8) ^ ((d & 7) << 4))) = make_uint2(lo, hi);
            }
        }
        __syncthreads();
        if (kt + 1 < T_ / 128) loadKV((kt + 1) * 128);

        // ---- S = Q @ K^T ----
        f32x4 sa[8];
#pragma unroll
        for (int f = 0; f < 8; ++f) sa[f] = (f32x4){0.f, 0.f, 0.f, 0.f};
        __builtin_amdgcn_s_setprio(1);
#pragma unroll
        for (int f = 0; f < 8; ++f) {
            int kv = f * 16 + ls;
            bf16x8 b0 = *(const bf16x8*)((char*)Klds + ((kv * 128 + g * 16) ^ ((kv & 7) << 4)));
            bf16x8 b1 = *(const bf16x8*)((char*)Klds + ((kv * 128 + 64 + g * 16) ^ ((kv & 7) << 4)));
            sa[f] = __builtin_amdgcn_mfma_f32_16x16x32_bf16(qf0, b0, sa[f], 0, 0, 0);
            sa[f] = __builtin_amdgcn_mfma_f32_16x16x32_bf16(qf1, b1, sa[f], 0, 0, 0);
        }
        __builtin_amdgcn_s_setprio(0);

        // ---- online softmax with defer-max (THR=8) ----
        float pw[8][4];
#pragma unroll
        for (int f = 0; f < 8; ++f)
#pragma unroll
            for (int r = 0; r < 4; ++r) pw[f][r] = sa[f][r] * 0.125f;
#pragma unroll
        for (int r = 0; r < 4; ++r) {
            float m = pw[0][r];
#pragma unroll
            for (int f = 1; f < 8; ++f) m = fmaxf(m, pw[f][r]);
            m = fmaxf(m, __shfl_xor(m, 1));
            m = fmaxf(m, __shfl_xor(m, 2));
            m = fmaxf(m, __shfl_xor(m, 4));
            m = fmaxf(m, __shfl_xor(m, 8));
            if (m > mrun[r] + 8.f) {
                float fac = __expf(mrun[r] - m);
                lrun[r] *= fac;
#pragma unroll
                for (int nf = 0; nf < 4; ++nf) o_acc[nf][r] *= fac;
                mrun[r] = m;
            }
            float s = 0.f;
#pragma unroll
            for (int f = 0; f < 8; ++f) { float e = __expf(pw[f][r] - mrun[r]); pw[f][r] = e; s += e; }
            s += __shfl_xor(s, 1); s += __shfl_xor(s, 2);
            s += __shfl_xor(s, 4); s += __shfl_xor(s, 8);
            lrun[r] += s;
        }

        // ---- P -> LDS (wave-private) ----
#pragma unroll
        for (int f = 0; f < 8; ++f)
#pragma unroll
            for (int r = 0; r < 4; ++r) {
                int qr = g * 4 + r, col = ls + 16 * f;
                *(unsigned short*)(pbase + ((qr * 256 + col * 2) ^ ((qr & 7) << 4))) = f2bf(pw[f][r]);
            }

        // ---- O += P @ V ----
        __builtin_amdgcn_s_setprio(1);
#pragma unroll
        for (int ks = 0; ks < 4; ++ks) {
            bf16x8 pa = *(const bf16x8*)(pbase + ((ls * 256 + ks * 64 + g * 16) ^ ((ls & 7) << 4)));
#pragma unroll
            for (int nf = 0; nf < 4; ++nf) {
                int d = nf * 16 + ls;
                bf16x8 bv = *(const bf16x8*)((char*)Vlds + ((d * 256 + ks * 64 + g * 16) ^ ((d & 7) << 4)));
                o_acc[nf] = __builtin_amdgcn_mfma_f32_16x16x32_bf16(pa, bv, o_acc[nf], 0, 0, 0);
            }
        }
        __builtin_amdgcn_s_setprio(0);
    }

    float inv[4];
#pragma unroll
    for (int r = 0; r < 4; ++r) inv[r] = 1.f / lrun[r];
#pragma unroll
    for (int nf = 0; nf < 4; ++nf)
#pragma unroll
        for (int r = 0; r < 4; ++r) {
            long row = bb * T_ + q0 + wv * 16 + g * 4 + r;
            outg[row * D_ + hh * 64 + nf * 16 + ls] = f2bf(o_acc[nf][r] * inv[r]);
        }
}

// ---------------- BatchNorm partials (bf16 qf input) ----------------
__global__ __launch_bounds__(256)
void bn_part(const unsigned short* __restrict__ qf, float* __restrict__ pS, float* __restrict__ pSS) {
    int c = blockIdx.y * 256 + threadIdx.x;
    int r0 = blockIdx.x * 32;
    float s = 0.f, ss = 0.f;
#pragma unroll 4
    for (int r = 0; r < 32; ++r) {
        float v = bf2f(qf[(long)(r0 + r) * DQ_ + c]);
        s += v; ss += v * v;
    }
    pS[(long)blockIdx.x * DQ_ + c] = s;
    pSS[(long)blockIdx.x * DQ_ + c] = ss;
}

// ---------------- fused BN finalize + normalize (bf16 in/out) ----------------
__global__ __launch_bounds__(256)
void qnf_kernel(const unsigned short* __restrict__ qf, const float* __restrict__ pS,
                const float* __restrict__ pSS, const float* __restrict__ g,
                const float* __restrict__ b, unsigned short* __restrict__ qn) {
    int c = blockIdx.y * 256 + threadIdx.x;
    float s = 0.f, ss = 0.f;
#pragma unroll 8
    for (int i = 0; i < 64; ++i) { s += pS[(long)i * DQ_ + c]; ss += pSS[(long)i * DQ_ + c]; }
    float m = s * (1.f / NT);
    float rs = rsqrtf(ss * (1.f / NT) - m * m + 1e-5f);
    float gg = g[c] * rs;
    float bb = b[c] - m * gg;
    int r0 = blockIdx.x * 32;
#pragma unroll 4
    for (int r = 0; r < 32; ++r) {
        long o = (long)(r0 + r) * DQ_ + c;
        qn[o] = f2bf(bf2f(qf[o]) * gg + bb);
    }
}

// ---------------- fused top-k (bf16 dots): 2 waves per task ----------------
__global__ __launch_bounds__(256)
void topk_kernel(const unsigned short* __restrict__ dots, float* __restrict__ fs, int* __restrict__ vi) {
    static const unsigned short tab[128] = {
        0,1,2,3,4,5,6,7,8,9,10,11,12,13,14,15,16,17,18,19,20,21,22,23,24,25,26,27,28,29,30,31,
        32,33,34,35,36,37,38,39,40,41,42,43,44,45,46,47,
        64,65,66,67,68,69,70,71,72,73,
        96,97,98,99,100,101,102,103,
        128,129,130,131,132,133,
        160,161,162,163,164,
        192,193,194,195,
        224,225,226,227,
        256,257,258,
        288,289,290,
        320,321, 352,353, 384,385, 416,417, 448,449, 480,481,
        512,544,576,608,640,672,704,736,768,800,832,864,896,928,960,992,
        0xFFFF,0xFFFF,0xFFFF,0xFFFF,0xFFFF,0xFFFF,0xFFFF,0xFFFF,0xFFFF
    };
    __shared__ float sv[2][64];
    __shared__ int   sidx[2][64];
    int tid = threadIdx.x, wv = tid >> 6, lane = tid & 63;
    int slot = wv >> 1, half = wv & 1;
    long task = (long)blockIdx.x * 2 + slot;
    const unsigned short* d = dots + (task >> 2) * 2048 + (task & 3) * 512 + half * 256;

    float v0 = bf2f(d[lane]), v1 = bf2f(d[lane + 64]);
    float v2 = bf2f(d[lane + 128]), v3 = bf2f(d[lane + 192]);
#pragma unroll 1
    for (int t = 0; t < 32; ++t) {
        float bm = v0; int ba = 0;
        if (v1 > bm) { bm = v1; ba = 1; }
        if (v2 > bm) { bm = v2; ba = 2; }
        if (v3 > bm) { bm = v3; ba = 3; }
        float wm = bm;
#pragma unroll
        for (int o = 32; o >= 1; o >>= 1) wm = fmaxf(wm, __shfl_xor(wm, o));
        unsigned long long msk = __ballot(bm == wm);
        int owner = (int)__builtin_ctzll(msk);
        if (lane == owner) {
            sv[slot][half * 32 + t] = wm;
            sidx[slot][half * 32 + t] = ba * 64 + lane;
            if (ba == 0) v0 = -1e30f;
            else if (ba == 1) v1 = -1e30f;
            else if (ba == 2) v2 = -1e30f;
            else v3 = -1e30f;
        }
    }
    __syncthreads();
    if (half) return;

    unsigned short t0 = tab[lane], t1 = tab[lane + 64];
    float c0 = -1e30f, c1 = -1e30f;
    int id0 = 0, id1 = 0;
    {
        int i = t0 >> 5, j = t0 & 31;
        c0 = sv[slot][i] + sv[slot][32 + j];
        id0 = sidx[slot][i] * NK_ + sidx[slot][32 + j];
    }
    if (t1 != 0xFFFF) {
        int i = t1 >> 5, j = t1 & 31;
        c1 = sv[slot][i] + sv[slot][32 + j];
        id1 = sidx[slot][i] * NK_ + sidx[slot][32 + j];
    }

    float* fo = fs + task * 32;
    int*   vo = vi + task * 32;
#pragma unroll 1
    for (int t = 0; t < 32; ++t) {
        float bm = c0; int sel = 0;
        if (c1 > bm) { bm = c1; sel = 1; }
        float wm = bm;
#pragma unroll
        for (int o = 32; o >= 1; o >>= 1) wm = fmaxf(wm, __shfl_xor(wm, o));
        unsigned long long msk = __ballot(bm == wm);
        int owner = (int)__builtin_ctzll(msk);
        if (lane == owner) {
            fo[t] = wm;
            vo[t] = sel ? id1 : id0;
            if (sel) c1 = -1e30f; else c0 = -1e30f;
        }
    }
}

// ---------------- softmax + gather(fp8 e4m3 table) + residual ----------------
__global__ __launch_bounds__(384)
void pkm_out_fp8(const float* __restrict__ fs, const int* __restrict__ vi,
                 const unsigned char* __restrict__ vals8, const float* __restrict__ x1,
                 float* __restrict__ outp) {
    int n = blockIdx.x, tid = threadIdx.x;
    __shared__ float w[128];
    __shared__ int   rows[128];
    __shared__ float red[3 * 768];
    if (tid < 128) {
        float e = fs[(long)n * 128 + tid];
        rows[tid] = vi[(long)n * 128 + tid];
        float m = e;
#pragma unroll
        for (int o = 16; o >= 1; o >>= 1) m = fmaxf(m, __shfl_xor(m, o));
        float ex = __expf(e - m);
        float s = ex;
#pragma unroll
        for (int o = 16; o >= 1; o >>= 1) s += __shfl_xor(s, o);
        w[tid] = ex / s;
    }
    __syncthreads();
    int slot = tid / 96, chunk = tid % 96;
    float a0=0.f,a1=0.f,a2=0.f,a3=0.f,a4=0.f,a5=0.f,a6=0.f,a7=0.f;
#pragma unroll 4
    for (int e = 0; e < 32; ++e) {
        int er = e * 4 + slot;
        float wgt = w[er];
        long ro = (long)rows[er] * D_;
        uint2 v = *(const uint2*)(vals8 + ro + chunk * 8);
        f32x2 f0 = __builtin_amdgcn_cvt_pk_f32_fp8((int)v.x, false);
        f32x2 f1 = __builtin_amdgcn_cvt_pk_f32_fp8((int)v.x, true);
        f32x2 f2 = __builtin_amdgcn_cvt_pk_f32_fp8((int)v.y, false);
        f32x2 f3 = __builtin_amdgcn_cvt_pk_f32_fp8((int)v.y, true);
        a0 += wgt * f0[0]; a1 += wgt * f0[1]; a2 += wgt * f1[0]; a3 += wgt * f1[1];
        a4 += wgt * f2[0]; a5 += wgt * f2[1]; a6 += wgt * f3[0]; a7 += wgt * f3[1];
    }
    if (slot > 0) {
        float* rp = &red[(slot - 1) * 768 + chunk * 8];
        rp[0]=a0; rp[1]=a1; rp[2]=a2; rp[3]=a3; rp[4]=a4; rp[5]=a5; rp[6]=a6; rp[7]=a7;
    }
    __syncthreads();
    if (slot == 0) {
        long o = (long)n * D_ + chunk * 8;
        const float* r0 = &red[chunk * 8];
        const float* r1 = &red[768 + chunk * 8];
        const float* r2 = &red[1536 + chunk * 8];
        f32x4 xa = *(const f32x4*)(x1 + o);
        f32x4 xb = *(const f32x4*)(x1 + o + 4);
        f32x4 o1 = { a0 + r0[0] + r1[0] + r2[0] + xa[0], a1 + r0[1] + r1[1] + r2[1] + xa[1],
                     a2 + r0[2] + r1[2] + r2[2] + xa[2], a3 + r0[3] + r1[3] + r2[3] + xa[3] };
        f32x4 o2 = { a4 + r0[4] + r1[4] + r2[4] + xb[0], a5 + r0[5] + r1[5] + r2[5] + xb[1],
                     a6 + r0[6] + r1[6] + r2[6] + xb[2], a7 + r0[7] + r1[7] + r2[7] + xb[3] };
        *(f32x4*)(outp + o) = o1;
        *(f32x4*)(outp + o + 4) = o2;
    }
}

// ---------------- fallback: f32-table gather ----------------
__global__ __launch_bounds__(384)
void pkm_out_f32(const float* __restrict__ fs, const int* __restrict__ vi,
                 const float* __restrict__ values, const float* __restrict__ x1,
                 float* __restrict__ outp) {
    int n = blockIdx.x, tid = threadIdx.x;
    __shared__ float w[128];
    __shared__ int   rows[128];
    __shared__ float red[768];
    if (tid < 128) {
        float e = fs[(long)n * 128 + tid];
        rows[tid] = vi[(long)n * 128 + tid];
        float m = e;
#pragma unroll
        for (int o = 16; o >= 1; o >>= 1) m = fmaxf(m, __shfl_xor(m, o));
        float ex = __expf(e - m);
        float s = ex;
#pragma unroll
        for (int o = 16; o >= 1; o >>= 1) s += __shfl_xor(s, o);
        w[tid] = ex / s;
    }
    __syncthreads();
    int slot = tid / 192, chunk = tid % 192;
    float a0 = 0.f, a1 = 0.f, a2 = 0.f, a3 = 0.f;
#pragma unroll 4
    for (int e = 0; e < 64; ++e) {
        int er = e * 2 + slot;
        float wgt = w[er];
        long ro = (long)rows[er] * D_;
        f32x4 v = *(const f32x4*)(values + ro + chunk * 4);
        a0 += wgt * v[0]; a1 += wgt * v[1]; a2 += wgt * v[2]; a3 += wgt * v[3];
    }
    if (slot == 1) {
        f32x4 t = {a0, a1, a2, a3};
        *(f32x4*)&red[chunk * 4] = t;
    }
    __syncthreads();
    if (slot == 0) {
        f32x4 o = *(const f32x4*)&red[chunk * 4];
        f32x4 xr = *(const f32x4*)(x1 + (long)n * D_ + chunk * 4);
        o[0] += a0 + xr[0]; o[1] += a1 + xr[1]; o[2] += a2 + xr[2]; o[3] += a3 + xr[3];
        *(f32x4*)(outp + (long)n * D_ + chunk * 4) = o;
    }
}

extern "C" void kernel_launch(void* const* d_in, const int* in_sizes, int n_in,
                              void* d_out, int out_size, void* d_ws, size_t ws_size,
                              hipStream_t stream) {
    const float* x    = (const float*)d_in[0];
    const float* wq   = (const float*)d_in[1];
    const float* bq   = (const float*)d_in[2];
    const float* wk   = (const float*)d_in[3];
    const float* bk   = (const float*)d_in[4];
    const float* wv   = (const float*)d_in[5];
    const float* bv   = (const float*)d_in[6];
    const float* wo   = (const float*)d_in[7];
    const float* bo   = (const float*)d_in[8];
    const float* ln1g = (const float*)d_in[9];
    const float* ln1b = (const float*)d_in[10];
    const float* ln2g = (const float*)d_in[11];
    const float* ln2b = (const float*)d_in[12];
    const float* pwq  = (const float*)d_in[13];
    const float* bng  = (const float*)d_in[14];
    const float* bnb  = (const float*)d_in[15];
    const float* keys = (const float*)d_in[16];
    const float* vals = (const float*)d_in[17];
    float* out = (float*)d_out;

    char* p = (char*)d_ws;
    auto alloc = [&](size_t bytes) -> char* {
        char* r = p; p += (bytes + 255) & ~(size_t)255; return r;
    };
    unsigned short* wqkvT = (unsigned short*)alloc((size_t)3 * D_ * D_ * 2);
    unsigned short* woT   = (unsigned short*)alloc((size_t)D_ * D_ * 2);
    unsigned short* pwqT  = (unsigned short*)alloc((size_t)D_ * DQ_ * 2);
    unsigned short* keyB  = (unsigned short*)alloc((size_t)NKEYS * 2);
    unsigned short* h1    = (unsigned short*)alloc((size_t)NT * D_ * 2);
    unsigned short* qkvB  = (unsigned short*)alloc((size_t)NT * QKVLD * 2);
    unsigned short* aout  = (unsigned short*)alloc((size_t)NT * D_ * 2);
    float* x1             = (float*)alloc((size_t)NT * D_ * 4);
    unsigned short* h2    = (unsigned short*)alloc((size_t)NT * D_ * 2);
    unsigned short* qfB   = (unsigned short*)alloc((size_t)NT * DQ_ * 2);
    float* pS             = (float*)alloc((size_t)64 * DQ_ * 4);
    float* pSS            = (float*)alloc((size_t)64 * DQ_ * 4);
    unsigned short* qnB   = (unsigned short*)alloc((size_t)NT * DQ_ * 2);
    unsigned short* dots  = (unsigned short*)alloc((size_t)NT * 2048 * 2);
    float* fsb            = (float*)alloc((size_t)NT * PH_ * 32 * 4);
    int*   vib            = (int*)alloc((size_t)NT * PH_ * 32 * 4);

    // fp8 values table if workspace allows (~50.4 MB more)
    size_t used = (size_t)(p - (char*)d_ws);
    size_t vbytes = (size_t)NK_ * NK_ * D_;
    bool useTab = (used + vbytes + 256) <= ws_size;
    unsigned char* vals8 = nullptr;
    if (useTab) vals8 = (unsigned char*)alloc(vbytes);

    // LN1 + hosted weight prep (transposes + keys convert)
    ln_kernel<<<NT + PREPBLKS, 256, 0, stream>>>(
        x, ln1g, ln1b, h1, NT, wq, wk, wv, wo, pwq, keys, wqkvT, woT, pwqT, keyB);
    // merged QKV GEMM -> qkvB; hosts first half of the values-table conversion
    gemm_kernel<<<dim3(32, useTab ? 52 : 36), 256, 0, stream>>>(
        h1, D_, wqkvT, D_, bq, bk, bv, nullptr, nullptr, qkvB, QKVLD, D_, 2,
        useTab ? vals : nullptr, vals8, 0L, 36);
    // attention (8-wave blocks, 128 q-rows, grid 192)
    attn_mfma_kernel<<<dim3(B_ * H_, T_ / 128), 512, 0, stream>>>(qkvB, aout);
    // output projection + residual
    gemm_kernel<<<dim3(32, 12), 256, 0, stream>>>(
        aout, D_, woT, D_, bo, nullptr, nullptr, x, x1, nullptr, D_, D_, 0,
        nullptr, nullptr, 0L, 0);
    // LN2
    ln_kernel<<<NT, 256, 0, stream>>>(
        x1, ln2g, ln2b, h2, NT, nullptr, nullptr, nullptr, nullptr, nullptr, nullptr,
        nullptr, nullptr, nullptr, nullptr);
    // PKM query GEMM (bf16 qf); hosts second half of the values-table conversion
    gemm_kernel<<<dim3(32, useTab ? 32 : 16), 256, 0, stream>>>(
        h2, D_, pwqT, D_, nullptr, nullptr, nullptr, nullptr, nullptr, qfB, DQ_, D_, 0,
        useTab ? vals : nullptr, vals8, CVHALF, 16);
    // BatchNorm partials + fused finalize/normalize
    bn_part<<<dim3(64, 4), 256, 0, stream>>>(qfB, pS, pSS);
    qnf_kernel<<<dim3(64, 4), 256, 0, stream>>>(qfB, pS, pSS, bng, bnb, qnB);
    // dots: 8 batched GEMMs via blockIdx.z -> bf16
    gemm_kernel<<<dim3(32, 4, 8), 256, 0, stream>>>(
        qnB, DQ_, keyB, 256, nullptr, nullptr, nullptr, nullptr, nullptr, dots, 2048, DHK_, 1,
        nullptr, nullptr, 0L, 0);
    // fused top-k (bf16 dots)
    topk_kernel<<<(NT * PH_) / 2, 256, 0, stream>>>(dots, fsb, vib);
    // softmax + gather + residual
    if (useTab)
        pkm_out_fp8<<<NT, 384, 0, stream>>>(fsb, vib, vals8, x1, out);
    else
        pkm_out_f32<<<NT, 384, 0, stream>>>(fsb, vib, vals, x1, out);
}

// Round 15
// 243.884 us; speedup vs baseline: 1.3425x; 1.0627x over previous
//
#include <hip/hip_runtime.h>
#include <hip/hip_bf16.h>

#define B_  2
#define T_  1024
#define D_  768
#define H_  12
#define NT  2048        // B*T
#define DQ_ 1024
#define PH_ 4
#define NK_ 256
#define TK_ 32
#define DHK_ 128
#define QKVLD 2304      // merged QKV row stride
#define CVHALF 25165824L // half the values table, elements
#define NKEYS (PH_ * NK_ * 2 * DHK_)
#define PREPBLKS 3584   // 4*576 + 768 + 512

typedef __attribute__((ext_vector_type(8))) short bf16x8;
typedef __attribute__((ext_vector_type(4))) float f32x4;
typedef __attribute__((ext_vector_type(2))) float f32x2;

static __device__ __forceinline__ unsigned short f2bf(float f) {
    union { float f; unsigned u; } c; c.f = f;
    unsigned r = (c.u + 0x7fffu + ((c.u >> 16) & 1u)) >> 16;
    return (unsigned short)r;
}

static __device__ __forceinline__ float bf2f(unsigned short s) {
    union { unsigned u; float f; } c; c.u = ((unsigned)s) << 16;
    return c.f;
}

__device__ __constant__ unsigned short ctab[128] = {
    0,1,2,3,4,5,6,7,8,9,10,11,12,13,14,15,16,17,18,19,20,21,22,23,24,25,26,27,28,29,30,31,
    32,33,34,35,36,37,38,39,40,41,42,43,44,45,46,47,
    64,65,66,67,68,69,70,71,72,73,
    96,97,98,99,100,101,102,103,
    128,129,130,131,132,133,
    160,161,162,163,164,
    192,193,194,195,
    224,225,226,227,
    256,257,258,
    288,289,290,
    320,321, 352,353, 384,385, 416,417, 448,449, 480,481,
    512,544,576,608,640,672,704,736,768,800,832,864,896,928,960,992,
    0xFFFF,0xFFFF,0xFFFF,0xFFFF,0xFFFF,0xFFFF,0xFFFF,0xFFFF,0xFFFF
};

// ---------------- LayerNorm (rows < nrows) + hosted weight prep (rows >= nrows) ----------------
__global__ __launch_bounds__(256)
void ln_kernel(const float* __restrict__ x, const float* __restrict__ g,
               const float* __restrict__ b, unsigned short* __restrict__ out,
               int nrows,
               const float* __restrict__ wq, const float* __restrict__ wk,
               const float* __restrict__ wv, const float* __restrict__ wo,
               const float* __restrict__ pwq, const float* __restrict__ keys,
               unsigned short* __restrict__ wqkvT, unsigned short* __restrict__ woT,
               unsigned short* __restrict__ pwqT, unsigned short* __restrict__ keyB) {
    int tid = threadIdx.x;
    if ((int)blockIdx.x >= nrows) {
        int tb = blockIdx.x - nrows;
        if (tb >= 3072) {                         // keys convert: 512 blocks x 512 elems
            long i = ((long)(tb - 3072) * 256 + tid) * 2;
            if (i + 1 < NKEYS + 1) { keyB[i] = f2bf(keys[i]); keyB[i + 1] = f2bf(keys[i + 1]); }
            return;
        }
        __shared__ float t[32][33];
        const float* W; unsigned short* Wt; int N, kx, ny;
        if (tb < 2304) {
            int z = tb / 576, rem = tb % 576;
            kx = rem % 24; ny = rem / 24; N = 768;
            if (z == 0)      { W = wq; Wt = wqkvT; }
            else if (z == 1) { W = wk; Wt = wqkvT + 589824; }
            else if (z == 2) { W = wv; Wt = wqkvT + 2 * 589824; }
            else             { W = wo; Wt = woT; }
        } else {
            int rem = tb - 2304;
            kx = rem % 24; ny = rem / 24; N = 1024;
            W = pwq; Wt = pwqT;
        }
        int k0 = kx * 32, n0 = ny * 32;
        int tx = tid & 31, ty = tid >> 5;
#pragma unroll
        for (int i = 0; i < 4; ++i)
            t[ty + 8 * i][tx] = W[(long)(k0 + ty + 8 * i) * N + n0 + tx];
        __syncthreads();
#pragma unroll
        for (int i = 0; i < 4; ++i)
            Wt[(long)(n0 + ty + 8 * i) * 768 + k0 + tx] = f2bf(t[tx][ty + 8 * i]);
        return;
    }

    int row = blockIdx.x;
    const float* xr = x + (long)row * D_;
    float v0 = xr[tid], v1 = xr[tid + 256], v2 = xr[tid + 512];
    float s = v0 + v1 + v2, ss = v0 * v0 + v1 * v1 + v2 * v2;
#pragma unroll
    for (int o = 1; o < 64; o <<= 1) { s += __shfl_xor(s, o); ss += __shfl_xor(ss, o); }
    __shared__ float ps[4], pss[4];
    int wid = tid >> 6, lane = tid & 63;
    if (lane == 0) { ps[wid] = s; pss[wid] = ss; }
    __syncthreads();
    s = ps[0] + ps[1] + ps[2] + ps[3];
    ss = pss[0] + pss[1] + pss[2] + pss[3];
    float mean = s * (1.f / D_);
    float var = ss * (1.f / D_) - mean * mean;
    float rs = rsqrtf(var + 1e-5f);
    unsigned short* orow = out + (long)row * D_;
    orow[tid]       = f2bf((v0 - mean) * rs * g[tid]       + b[tid]);
    orow[tid + 256] = f2bf((v1 - mean) * rs * g[tid + 256] + b[tid + 256]);
    orow[tid + 512] = f2bf((v2 - mean) * rs * g[tid + 512] + b[tid + 512]);
}

// ---------------- MFMA GEMM (64x64 tile, 4 waves, BK=32) ----------------
__global__ __launch_bounds__(256)
void gemm_kernel(const unsigned short* __restrict__ A, int lda,
                 const unsigned short* __restrict__ Bt, int ldb,
                 const float* __restrict__ bias,
                 const float* __restrict__ bias2,
                 const float* __restrict__ bias3,
                 const float* __restrict__ res,
                 float* __restrict__ outF,
                 unsigned short* __restrict__ outB,
                 int ldc, int K, int zmode,
                 const float* __restrict__ cvin,
                 unsigned char* __restrict__ cvout,
                 long cvbase, int cvy0) {
    if (cvin && (int)blockIdx.y >= cvy0) {
        long stride = (long)(gridDim.y - cvy0) * gridDim.x * 256 * 8;
        long idx = cvbase +
            ((long)((blockIdx.y - cvy0) * gridDim.x + blockIdx.x) * 256 + threadIdx.x) * 8;
        long end = cvbase + CVHALF;
#pragma unroll 2
        for (; idx < end; idx += stride) {
            f32x4 a = *(const f32x4*)(cvin + idx);
            f32x4 b = *(const f32x4*)(cvin + idx + 4);
            int lo = __builtin_amdgcn_cvt_pk_fp8_f32(a[0], a[1], 0, false);
            lo = __builtin_amdgcn_cvt_pk_fp8_f32(a[2], a[3], lo, true);
            int hi = __builtin_amdgcn_cvt_pk_fp8_f32(b[0], b[1], 0, false);
            hi = __builtin_amdgcn_cvt_pk_fp8_f32(b[2], b[3], hi, true);
            *(uint2*)(cvout + idx) = make_uint2((unsigned)lo, (unsigned)hi);
        }
        return;
    }
    const int tid = threadIdx.x;
    const int w = tid >> 6, lane = tid & 63;
    const int ls = lane & 15, g = lane >> 4;
    const int m0 = blockIdx.x * 64, n0 = blockIdx.y * 64;

    __shared__ unsigned short As[64][40];
    __shared__ unsigned short Bs[64][40];

    f32x4 acc[4];
#pragma unroll
    for (int c = 0; c < 4; ++c) acc[c] = (f32x4){0.f, 0.f, 0.f, 0.f};

    const int lrow = tid >> 2, lseg = tid & 3;
    const unsigned short* gA = A + (long)(m0 + lrow) * lda + lseg * 8;
    const unsigned short* gB = Bt + (long)(n0 + lrow) * ldb + lseg * 8;

    for (int kt = 0; kt < K; kt += 32) {
        __syncthreads();
        *(int4*)&As[lrow][lseg * 8] = *(const int4*)(gA + kt);
        *(int4*)&Bs[lrow][lseg * 8] = *(const int4*)(gB + kt);
        __syncthreads();
        bf16x8 bfr = *(const bf16x8*)&Bs[w * 16 + ls][g * 8];
#pragma unroll
        for (int c = 0; c < 4; ++c) {
            bf16x8 afr = *(const bf16x8*)&As[c * 16 + ls][g * 8];
            acc[c] = __builtin_amdgcn_mfma_f32_16x16x32_bf16(afr, bfr, acc[c], 0, 0, 0);
        }
    }
#pragma unroll
    for (int c = 0; c < 4; ++c) {
#pragma unroll
        for (int r = 0; r < 4; ++r) {
            int row = m0 + c * 16 + g * 4 + r;
            int col = n0 + w * 16 + ls;
            float v = acc[c][r];
            if (bias) {
                const float* bp = bias; int cc = col;
                if (zmode == 2) {
                    int sel = col >= 1536 ? 2 : (col >= 768 ? 1 : 0);
                    bp = sel == 0 ? bias : (sel == 1 ? bias2 : bias3);
                    cc = col - sel * 768;
                }
                v += bp[cc];
            }
            long off = (long)row * ldc + col;
            if (res)  v += res[off];
            if (outF) outF[off] = v;
            if (outB) outB[off] = f2bf(v);
        }
    }
}

// ---------------- dots GEMM: K=128 single-stage (one barrier pair, 64 MFMA/block) ----------------
// grid (32, 4, 8): z -> (ph, half). Output bf16 [2048][2048].
__global__ __launch_bounds__(256)
void dots_kernel(const unsigned short* __restrict__ A,    // qnB [2048][1024]
                 const unsigned short* __restrict__ Bt,   // keyB [PH][256][2][128]
                 unsigned short* __restrict__ outB) {
    int z = blockIdx.z, ph = z >> 1, half = z & 1;
    A    += half * 512 + ph * 128;
    Bt   += ph * 65536 + half * 128;
    outB += ph * 512 + half * 256;
    const int tid = threadIdx.x;
    const int w = tid >> 6, lane = tid & 63;
    const int ls = lane & 15, g = lane >> 4;
    const int m0 = blockIdx.x * 64, n0 = blockIdx.y * 64;

    __shared__ unsigned short As[64][136];
    __shared__ unsigned short Bs[64][136];

    const int row = tid >> 2, cs = (tid & 3) * 32;
    const unsigned short* gA = A + (long)(m0 + row) * DQ_ + cs;
    const unsigned short* gB = Bt + (long)(n0 + row) * 256 + cs;
#pragma unroll
    for (int j = 0; j < 4; ++j) {
        *(int4*)&As[row][cs + 8 * j] = *(const int4*)(gA + 8 * j);
        *(int4*)&Bs[row][cs + 8 * j] = *(const int4*)(gB + 8 * j);
    }
    __syncthreads();

    f32x4 acc[4];
#pragma unroll
    for (int c = 0; c < 4; ++c) acc[c] = (f32x4){0.f, 0.f, 0.f, 0.f};
#pragma unroll
    for (int kk = 0; kk < 4; ++kk) {
        bf16x8 bfr = *(const bf16x8*)&Bs[w * 16 + ls][g * 8 + 32 * kk];
#pragma unroll
        for (int c = 0; c < 4; ++c) {
            bf16x8 afr = *(const bf16x8*)&As[c * 16 + ls][g * 8 + 32 * kk];
            acc[c] = __builtin_amdgcn_mfma_f32_16x16x32_bf16(afr, bfr, acc[c], 0, 0, 0);
        }
    }
#pragma unroll
    for (int c = 0; c < 4; ++c)
#pragma unroll
        for (int r = 0; r < 4; ++r)
            outB[(long)(m0 + c * 16 + g * 4 + r) * 2048 + n0 + w * 16 + ls] = f2bf(acc[c][r]);
}

// ---------------- MFMA flash attention: 8-wave blocks, 128 q-rows ----------------
__global__ __launch_bounds__(512)
void attn_mfma_kernel(const unsigned short* __restrict__ qkv,
                      unsigned short* __restrict__ outg) {
    int bh = blockIdx.x, bb = bh / H_, hh = bh % H_;
    int q0 = blockIdx.y * 128;
    int tid = threadIdx.x, wv = tid >> 6, lane = tid & 63;
    int ls = lane & 15, g = lane >> 4;

    __shared__ unsigned short Klds[128 * 64];
    __shared__ unsigned short Vlds[64 * 128];
    __shared__ unsigned short Plds[8][16 * 128];

    const unsigned short* qrow = qkv + (long)(bb * T_ + q0 + wv * 16 + ls) * QKVLD + hh * 64 + g * 8;
    bf16x8 qf0 = *(const bf16x8*)qrow;
    bf16x8 qf1 = *(const bf16x8*)(qrow + 32);

    f32x4 o_acc[4];
#pragma unroll
    for (int nf = 0; nf < 4; ++nf) o_acc[nf] = (f32x4){0.f, 0.f, 0.f, 0.f};
    float mrun[4] = {-1e30f, -1e30f, -1e30f, -1e30f};
    float lrun[4] = {0.f, 0.f, 0.f, 0.f};

    char* pbase = (char*)&Plds[wv][0];
    const bool doK = tid < 256;
    const int t2 = tid & 255;
    const int d0 = (t2 & 7) * 8, kvq = t2 >> 3;

    bf16x8 streg[4];
    auto loadKV = [&](int kvb) {
        if (doK) {
#pragma unroll
            for (int i = 0; i < 4; ++i) {
                int c = t2 + i * 256;
                streg[i] = *(const bf16x8*)(qkv + (long)(bb * T_ + kvb + (c >> 3)) * QKVLD + 768 + hh * 64 + (c & 7) * 8);
            }
        } else {
            const unsigned short* vb = qkv + (long)(bb * T_ + kvb + kvq * 4) * QKVLD + 1536 + hh * 64 + d0;
#pragma unroll
            for (int i = 0; i < 4; ++i) streg[i] = *(const bf16x8*)(vb + i * QKVLD);
        }
    };

    loadKV(0);
    for (int kt = 0; kt < T_ / 128; ++kt) {
        __syncthreads();
        if (doK) {
#pragma unroll
            for (int i = 0; i < 4; ++i) {
                int c = t2 + i * 256;
                int kv = c >> 3, dc = c & 7;
                *(bf16x8*)((char*)Klds + ((kv * 128 + dc * 16) ^ ((kv & 7) << 4))) = streg[i];
            }
        } else {
#pragma unroll
            for (int j = 0; j < 8; ++j) {
                unsigned lo = (unsigned)(unsigned short)streg[0][j] | ((unsigned)(unsigned short)streg[1][j] << 16);
                unsigned hi = (unsigned)(unsigned short)streg[2][j] | ((unsigned)(unsigned short)streg[3][j] << 16);
                int d = d0 + j;
                *(uint2*)((char*)Vlds + ((d * 256 + kvq * 8) ^ ((d & 7) << 4))) = make_uint2(lo, hi);
            }
        }
        __syncthreads();
        if (kt + 1 < T_ / 128) loadKV((kt + 1) * 128);

        f32x4 sa[8];
#pragma unroll
        for (int f = 0; f < 8; ++f) sa[f] = (f32x4){0.f, 0.f, 0.f, 0.f};
        __builtin_amdgcn_s_setprio(1);
#pragma unroll
        for (int f = 0; f < 8; ++f) {
            int kv = f * 16 + ls;
            bf16x8 b0 = *(const bf16x8*)((char*)Klds + ((kv * 128 + g * 16) ^ ((kv & 7) << 4)));
            bf16x8 b1 = *(const bf16x8*)((char*)Klds + ((kv * 128 + 64 + g * 16) ^ ((kv & 7) << 4)));
            sa[f] = __builtin_amdgcn_mfma_f32_16x16x32_bf16(qf0, b0, sa[f], 0, 0, 0);
            sa[f] = __builtin_amdgcn_mfma_f32_16x16x32_bf16(qf1, b1, sa[f], 0, 0, 0);
        }
        __builtin_amdgcn_s_setprio(0);

        float pw[8][4];
#pragma unroll
        for (int f = 0; f < 8; ++f)
#pragma unroll
            for (int r = 0; r < 4; ++r) pw[f][r] = sa[f][r] * 0.125f;
#pragma unroll
        for (int r = 0; r < 4; ++r) {
            float m = pw[0][r];
#pragma unroll
            for (int f = 1; f < 8; ++f) m = fmaxf(m, pw[f][r]);
            m = fmaxf(m, __shfl_xor(m, 1));
            m = fmaxf(m, __shfl_xor(m, 2));
            m = fmaxf(m, __shfl_xor(m, 4));
            m = fmaxf(m, __shfl_xor(m, 8));
            if (m > mrun[r] + 8.f) {
                float fac = __expf(mrun[r] - m);
                lrun[r] *= fac;
#pragma unroll
                for (int nf = 0; nf < 4; ++nf) o_acc[nf][r] *= fac;
                mrun[r] = m;
            }
            float s = 0.f;
#pragma unroll
            for (int f = 0; f < 8; ++f) { float e = __expf(pw[f][r] - mrun[r]); pw[f][r] = e; s += e; }
            s += __shfl_xor(s, 1); s += __shfl_xor(s, 2);
            s += __shfl_xor(s, 4); s += __shfl_xor(s, 8);
            lrun[r] += s;
        }

#pragma unroll
        for (int f = 0; f < 8; ++f)
#pragma unroll
            for (int r = 0; r < 4; ++r) {
                int qr = g * 4 + r, col = ls + 16 * f;
                *(unsigned short*)(pbase + ((qr * 256 + col * 2) ^ ((qr & 7) << 4))) = f2bf(pw[f][r]);
            }

        __builtin_amdgcn_s_setprio(1);
#pragma unroll
        for (int ks = 0; ks < 4; ++ks) {
            bf16x8 pa = *(const bf16x8*)(pbase + ((ls * 256 + ks * 64 + g * 16) ^ ((ls & 7) << 4)));
#pragma unroll
            for (int nf = 0; nf < 4; ++nf) {
                int d = nf * 16 + ls;
                bf16x8 bv = *(const bf16x8*)((char*)Vlds + ((d * 256 + ks * 64 + g * 16) ^ ((d & 7) << 4)));
                o_acc[nf] = __builtin_amdgcn_mfma_f32_16x16x32_bf16(pa, bv, o_acc[nf], 0, 0, 0);
            }
        }
        __builtin_amdgcn_s_setprio(0);
    }

    float inv[4];
#pragma unroll
    for (int r = 0; r < 4; ++r) inv[r] = 1.f / lrun[r];
#pragma unroll
    for (int nf = 0; nf < 4; ++nf)
#pragma unroll
        for (int r = 0; r < 4; ++r) {
            long row = bb * T_ + q0 + wv * 16 + g * 4 + r;
            outg[row * D_ + hh * 64 + nf * 16 + ls] = f2bf(o_acc[nf][r] * inv[r]);
        }
}

// ---------------- BatchNorm partials (bf16 qf input) ----------------
__global__ __launch_bounds__(256)
void bn_part(const unsigned short* __restrict__ qf, float* __restrict__ pS, float* __restrict__ pSS) {
    int c = blockIdx.y * 256 + threadIdx.x;
    int r0 = blockIdx.x * 32;
    float s = 0.f, ss = 0.f;
#pragma unroll 4
    for (int r = 0; r < 32; ++r) {
        float v = bf2f(qf[(long)(r0 + r) * DQ_ + c]);
        s += v; ss += v * v;
    }
    pS[(long)blockIdx.x * DQ_ + c] = s;
    pSS[(long)blockIdx.x * DQ_ + c] = ss;
}

// ---------------- fused BN finalize + normalize (bf16 in/out) ----------------
__global__ __launch_bounds__(256)
void qnf_kernel(const unsigned short* __restrict__ qf, const float* __restrict__ pS,
                const float* __restrict__ pSS, const float* __restrict__ g,
                const float* __restrict__ b, unsigned short* __restrict__ qn) {
    int c = blockIdx.y * 256 + threadIdx.x;
    float s = 0.f, ss = 0.f;
#pragma unroll 8
    for (int i = 0; i < 64; ++i) { s += pS[(long)i * DQ_ + c]; ss += pSS[(long)i * DQ_ + c]; }
    float m = s * (1.f / NT);
    float rs = rsqrtf(ss * (1.f / NT) - m * m + 1e-5f);
    float gg = g[c] * rs;
    float bb = b[c] - m * gg;
    int r0 = blockIdx.x * 32;
#pragma unroll 4
    for (int r = 0; r < 32; ++r) {
        long o = (long)(r0 + r) * DQ_ + c;
        qn[o] = f2bf(bf2f(qf[o]) * gg + bb);
    }
}

// ---------------- FUSED tail: top-k (8 waves) + softmax + fp8 gather + residual ----------------
// One block per token (512 threads). Waves (slot=ph, half): stage-1 extraction; even waves
// combine the 119-candidate frontier into LDS; then softmax + gather (384 active lanes).
__global__ __launch_bounds__(512)
void pkm_tail_fp8(const unsigned short* __restrict__ dots,
                  const unsigned char* __restrict__ vals8,
                  const float* __restrict__ x1,
                  float* __restrict__ outp) {
    __shared__ float sv[4][64];
    __shared__ int   sidx[4][64];
    __shared__ float w[128];
    __shared__ int   rows[128];
    __shared__ float red[3 * 768];
    int n = blockIdx.x, tid = threadIdx.x;
    int wv = tid >> 6, lane = tid & 63;
    int slot = wv >> 1, half = wv & 1;

    // ---- stage-1: top-32 of this (ph, half) ----
    {
        const unsigned short* d = dots + (long)n * 2048 + slot * 512 + half * 256;
        float v0 = bf2f(d[lane]), v1 = bf2f(d[lane + 64]);
        float v2 = bf2f(d[lane + 128]), v3 = bf2f(d[lane + 192]);
#pragma unroll 1
        for (int t = 0; t < 32; ++t) {
            float bm = v0; int ba = 0;
            if (v1 > bm) { bm = v1; ba = 1; }
            if (v2 > bm) { bm = v2; ba = 2; }
            if (v3 > bm) { bm = v3; ba = 3; }
            float wm = bm;
#pragma unroll
            for (int o = 32; o >= 1; o >>= 1) wm = fmaxf(wm, __shfl_xor(wm, o));
            unsigned long long msk = __ballot(bm == wm);
            int owner = (int)__builtin_ctzll(msk);
            if (lane == owner) {
                sv[slot][half * 32 + t] = wm;
                sidx[slot][half * 32 + t] = ba * 64 + lane;
                if (ba == 0) v0 = -1e30f;
                else if (ba == 1) v1 = -1e30f;
                else if (ba == 2) v2 = -1e30f;
                else v3 = -1e30f;
            }
        }
    }
    __syncthreads();

    // ---- combine (even waves): top-32 pair sums -> w/rows ----
    if (!half) {
        unsigned short t0 = ctab[lane], t1 = ctab[lane + 64];
        float c0 = -1e30f, c1 = -1e30f;
        int id0 = 0, id1 = 0;
        {
            int i = t0 >> 5, j = t0 & 31;
            c0 = sv[slot][i] + sv[slot][32 + j];
            id0 = sidx[slot][i] * NK_ + sidx[slot][32 + j];
        }
        if (t1 != 0xFFFF) {
            int i = t1 >> 5, j = t1 & 31;
            c1 = sv[slot][i] + sv[slot][32 + j];
            id1 = sidx[slot][i] * NK_ + sidx[slot][32 + j];
        }
#pragma unroll 1
        for (int t = 0; t < 32; ++t) {
            float bm = c0; int sel = 0;
            if (c1 > bm) { bm = c1; sel = 1; }
            float wm = bm;
#pragma unroll
            for (int o = 32; o >= 1; o >>= 1) wm = fmaxf(wm, __shfl_xor(wm, o));
            unsigned long long msk = __ballot(bm == wm);
            int owner = (int)__builtin_ctzll(msk);
            if (lane == owner) {
                w[slot * 32 + t] = wm;
                rows[slot * 32 + t] = sel ? id1 : id0;
                if (sel) c1 = -1e30f; else c0 = -1e30f;
            }
        }
    }
    __syncthreads();

    // ---- softmax over each ph's 32 scores (tid<128, 32-lane groups) ----
    if (tid < 128) {
        float e = w[tid];
        float m = e;
#pragma unroll
        for (int o = 16; o >= 1; o >>= 1) m = fmaxf(m, __shfl_xor(m, o));
        float ex = __expf(e - m);
        float s = ex;
#pragma unroll
        for (int o = 16; o >= 1; o >>= 1) s += __shfl_xor(s, o);
        w[tid] = ex / s;
    }
    __syncthreads();

    // ---- gather: 4 row-slots x 96 active chunks of 8 fp8 ----
    int gs = tid >> 7, chunk = tid & 127;
    float a0=0.f,a1=0.f,a2=0.f,a3=0.f,a4=0.f,a5=0.f,a6=0.f,a7=0.f;
    if (chunk < 96) {
#pragma unroll 4
        for (int e = 0; e < 32; ++e) {
            int er = e * 4 + gs;
            float wgt = w[er];
            long ro = (long)rows[er] * D_;
            uint2 v = *(const uint2*)(vals8 + ro + chunk * 8);
            f32x2 f0 = __builtin_amdgcn_cvt_pk_f32_fp8((int)v.x, false);
            f32x2 f1 = __builtin_amdgcn_cvt_pk_f32_fp8((int)v.x, true);
            f32x2 f2 = __builtin_amdgcn_cvt_pk_f32_fp8((int)v.y, false);
            f32x2 f3 = __builtin_amdgcn_cvt_pk_f32_fp8((int)v.y, true);
            a0 += wgt * f0[0]; a1 += wgt * f0[1]; a2 += wgt * f1[0]; a3 += wgt * f1[1];
            a4 += wgt * f2[0]; a5 += wgt * f2[1]; a6 += wgt * f3[0]; a7 += wgt * f3[1];
        }
        if (gs > 0) {
            float* rp = &red[(gs - 1) * 768 + chunk * 8];
            rp[0]=a0; rp[1]=a1; rp[2]=a2; rp[3]=a3; rp[4]=a4; rp[5]=a5; rp[6]=a6; rp[7]=a7;
        }
    }
    __syncthreads();
    if (gs == 0 && chunk < 96) {
        long o = (long)n * D_ + chunk * 8;
        const float* r0 = &red[chunk * 8];
        const float* r1 = &red[768 + chunk * 8];
        const float* r2 = &red[1536 + chunk * 8];
        f32x4 xa = *(const f32x4*)(x1 + o);
        f32x4 xb = *(const f32x4*)(x1 + o + 4);
        f32x4 o1 = { a0 + r0[0] + r1[0] + r2[0] + xa[0], a1 + r0[1] + r1[1] + r2[1] + xa[1],
                     a2 + r0[2] + r1[2] + r2[2] + xa[2], a3 + r0[3] + r1[3] + r2[3] + xa[3] };
        f32x4 o2 = { a4 + r0[4] + r1[4] + r2[4] + xb[0], a5 + r0[5] + r1[5] + r2[5] + xb[1],
                     a6 + r0[6] + r1[6] + r2[6] + xb[2], a7 + r0[7] + r1[7] + r2[7] + xb[3] };
        *(f32x4*)(outp + o) = o1;
        *(f32x4*)(outp + o + 4) = o2;
    }
}

// ---------------- fallback pair (f32 table): topk + gather ----------------
__global__ __launch_bounds__(256)
void topk_kernel(const unsigned short* __restrict__ dots, float* __restrict__ fs, int* __restrict__ vi) {
    __shared__ float sv[2][64];
    __shared__ int   sidx[2][64];
    int tid = threadIdx.x, wv = tid >> 6, lane = tid & 63;
    int slot = wv >> 1, half = wv & 1;
    long task = (long)blockIdx.x * 2 + slot;
    const unsigned short* d = dots + (task >> 2) * 2048 + (task & 3) * 512 + half * 256;

    float v0 = bf2f(d[lane]), v1 = bf2f(d[lane + 64]);
    float v2 = bf2f(d[lane + 128]), v3 = bf2f(d[lane + 192]);
#pragma unroll 1
    for (int t = 0; t < 32; ++t) {
        float bm = v0; int ba = 0;
        if (v1 > bm) { bm = v1; ba = 1; }
        if (v2 > bm) { bm = v2; ba = 2; }
        if (v3 > bm) { bm = v3; ba = 3; }
        float wm = bm;
#pragma unroll
        for (int o = 32; o >= 1; o >>= 1) wm = fmaxf(wm, __shfl_xor(wm, o));
        unsigned long long msk = __ballot(bm == wm);
        int owner = (int)__builtin_ctzll(msk);
        if (lane == owner) {
            sv[slot][half * 32 + t] = wm;
            sidx[slot][half * 32 + t] = ba * 64 + lane;
            if (ba == 0) v0 = -1e30f;
            else if (ba == 1) v1 = -1e30f;
            else if (ba == 2) v2 = -1e30f;
            else v3 = -1e30f;
        }
    }
    __syncthreads();
    if (half) return;

    unsigned short t0 = ctab[lane], t1 = ctab[lane + 64];
    float c0 = -1e30f, c1 = -1e30f;
    int id0 = 0, id1 = 0;
    {
        int i = t0 >> 5, j = t0 & 31;
        c0 = sv[slot][i] + sv[slot][32 + j];
        id0 = sidx[slot][i] * NK_ + sidx[slot][32 + j];
    }
    if (t1 != 0xFFFF) {
        int i = t1 >> 5, j = t1 & 31;
        c1 = sv[slot][i] + sv[slot][32 + j];
        id1 = sidx[slot][i] * NK_ + sidx[slot][32 + j];
    }

    float* fo = fs + task * 32;
    int*   vo = vi + task * 32;
#pragma unroll 1
    for (int t = 0; t < 32; ++t) {
        float bm = c0; int sel = 0;
        if (c1 > bm) { bm = c1; sel = 1; }
        float wm = bm;
#pragma unroll
        for (int o = 32; o >= 1; o >>= 1) wm = fmaxf(wm, __shfl_xor(wm, o));
        unsigned long long msk = __ballot(bm == wm);
        int owner = (int)__builtin_ctzll(msk);
        if (lane == owner) {
            fo[t] = wm;
            vo[t] = sel ? id1 : id0;
            if (sel) c1 = -1e30f; else c0 = -1e30f;
        }
    }
}

__global__ __launch_bounds__(384)
void pkm_out_f32(const float* __restrict__ fs, const int* __restrict__ vi,
                 const float* __restrict__ values, const float* __restrict__ x1,
                 float* __restrict__ outp) {
    int n = blockIdx.x, tid = threadIdx.x;
    __shared__ float w[128];
    __shared__ int   rows[128];
    __shared__ float red[768];
    if (tid < 128) {
        float e = fs[(long)n * 128 + tid];
        rows[tid] = vi[(long)n * 128 + tid];
        float m = e;
#pragma unroll
        for (int o = 16; o >= 1; o >>= 1) m = fmaxf(m, __shfl_xor(m, o));
        float ex = __expf(e - m);
        float s = ex;
#pragma unroll
        for (int o = 16; o >= 1; o >>= 1) s += __shfl_xor(s, o);
        w[tid] = ex / s;
    }
    __syncthreads();
    int slot = tid / 192, chunk = tid % 192;
    float a0 = 0.f, a1 = 0.f, a2 = 0.f, a3 = 0.f;
#pragma unroll 4
    for (int e = 0; e < 64; ++e) {
        int er = e * 2 + slot;
        float wgt = w[er];
        long ro = (long)rows[er] * D_;
        f32x4 v = *(const f32x4*)(values + ro + chunk * 4);
        a0 += wgt * v[0]; a1 += wgt * v[1]; a2 += wgt * v[2]; a3 += wgt * v[3];
    }
    if (slot == 1) {
        f32x4 t = {a0, a1, a2, a3};
        *(f32x4*)&red[chunk * 4] = t;
    }
    __syncthreads();
    if (slot == 0) {
        f32x4 o = *(const f32x4*)&red[chunk * 4];
        f32x4 xr = *(const f32x4*)(x1 + (long)n * D_ + chunk * 4);
        o[0] += a0 + xr[0]; o[1] += a1 + xr[1]; o[2] += a2 + xr[2]; o[3] += a3 + xr[3];
        *(f32x4*)(outp + (long)n * D_ + chunk * 4) = o;
    }
}

extern "C" void kernel_launch(void* const* d_in, const int* in_sizes, int n_in,
                              void* d_out, int out_size, void* d_ws, size_t ws_size,
                              hipStream_t stream) {
    const float* x    = (const float*)d_in[0];
    const float* wq   = (const float*)d_in[1];
    const float* bq   = (const float*)d_in[2];
    const float* wk   = (const float*)d_in[3];
    const float* bk   = (const float*)d_in[4];
    const float* wv   = (const float*)d_in[5];
    const float* bv   = (const float*)d_in[6];
    const float* wo   = (const float*)d_in[7];
    const float* bo   = (const float*)d_in[8];
    const float* ln1g = (const float*)d_in[9];
    const float* ln1b = (const float*)d_in[10];
    const float* ln2g = (const float*)d_in[11];
    const float* ln2b = (const float*)d_in[12];
    const float* pwq  = (const float*)d_in[13];
    const float* bng  = (const float*)d_in[14];
    const float* bnb  = (const float*)d_in[15];
    const float* keys = (const float*)d_in[16];
    const float* vals = (const float*)d_in[17];
    float* out = (float*)d_out;

    char* p = (char*)d_ws;
    auto alloc = [&](size_t bytes) -> char* {
        char* r = p; p += (bytes + 255) & ~(size_t)255; return r;
    };
    unsigned short* wqkvT = (unsigned short*)alloc((size_t)3 * D_ * D_ * 2);
    unsigned short* woT   = (unsigned short*)alloc((size_t)D_ * D_ * 2);
    unsigned short* pwqT  = (unsigned short*)alloc((size_t)D_ * DQ_ * 2);
    unsigned short* keyB  = (unsigned short*)alloc((size_t)NKEYS * 2);
    unsigned short* h1    = (unsigned short*)alloc((size_t)NT * D_ * 2);
    unsigned short* qkvB  = (unsigned short*)alloc((size_t)NT * QKVLD * 2);
    unsigned short* aout  = (unsigned short*)alloc((size_t)NT * D_ * 2);
    float* x1             = (float*)alloc((size_t)NT * D_ * 4);
    unsigned short* h2    = (unsigned short*)alloc((size_t)NT * D_ * 2);
    unsigned short* qfB   = (unsigned short*)alloc((size_t)NT * DQ_ * 2);
    float* pS             = (float*)alloc((size_t)64 * DQ_ * 4);
    float* pSS            = (float*)alloc((size_t)64 * DQ_ * 4);
    unsigned short* qnB   = (unsigned short*)alloc((size_t)NT * DQ_ * 2);
    unsigned short* dots  = (unsigned short*)alloc((size_t)NT * 2048 * 2);
    float* fsb            = (float*)alloc((size_t)NT * PH_ * 32 * 4);
    int*   vib            = (int*)alloc((size_t)NT * PH_ * 32 * 4);

    // fp8 values table if workspace allows (~50.4 MB more)
    size_t used = (size_t)(p - (char*)d_ws);
    size_t vbytes = (size_t)NK_ * NK_ * D_;
    bool useTab = (used + vbytes + 256) <= ws_size;
    unsigned char* vals8 = nullptr;
    if (useTab) vals8 = (unsigned char*)alloc(vbytes);

    // LN1 + hosted weight prep (transposes + keys convert)
    ln_kernel<<<NT + PREPBLKS, 256, 0, stream>>>(
        x, ln1g, ln1b, h1, NT, wq, wk, wv, wo, pwq, keys, wqkvT, woT, pwqT, keyB);
    // merged QKV GEMM -> qkvB; hosts first half of the values-table conversion
    gemm_kernel<<<dim3(32, useTab ? 52 : 36), 256, 0, stream>>>(
        h1, D_, wqkvT, D_, bq, bk, bv, nullptr, nullptr, qkvB, QKVLD, D_, 2,
        useTab ? vals : nullptr, vals8, 0L, 36);
    // attention (8-wave blocks, 128 q-rows, grid 192)
    attn_mfma_kernel<<<dim3(B_ * H_, T_ / 128), 512, 0, stream>>>(qkvB, aout);
    // output projection + residual
    gemm_kernel<<<dim3(32, 12), 256, 0, stream>>>(
        aout, D_, woT, D_, bo, nullptr, nullptr, x, x1, nullptr, D_, D_, 0,
        nullptr, nullptr, 0L, 0);
    // LN2
    ln_kernel<<<NT, 256, 0, stream>>>(
        x1, ln2g, ln2b, h2, NT, nullptr, nullptr, nullptr, nullptr, nullptr, nullptr,
        nullptr, nullptr, nullptr, nullptr);
    // PKM query GEMM (bf16 qf); hosts second half of the values-table conversion
    gemm_kernel<<<dim3(32, useTab ? 32 : 16), 256, 0, stream>>>(
        h2, D_, pwqT, D_, nullptr, nullptr, nullptr, nullptr, nullptr, qfB, DQ_, D_, 0,
        useTab ? vals : nullptr, vals8, CVHALF, 16);
    // BatchNorm partials + fused finalize/normalize
    bn_part<<<dim3(64, 4), 256, 0, stream>>>(qfB, pS, pSS);
    qnf_kernel<<<dim3(64, 4), 256, 0, stream>>>(qfB, pS, pSS, bng, bnb, qnB);
    // dots: single-stage K=128 GEMM -> bf16
    dots_kernel<<<dim3(32, 4, 8), 256, 0, stream>>>(qnB, keyB, dots);
    // fused tail: top-k + softmax + gather + residual
    if (useTab) {
        pkm_tail_fp8<<<NT, 512, 0, stream>>>(dots, vals8, x1, out);
    } else {
        topk_kernel<<<(NT * PH_) / 2, 256, 0, stream>>>(dots, fsb, vib);
        pkm_out_f32<<<NT, 384, 0, stream>>>(fsb, vib, vals, x1, out);
    }
}

// Round 16
// 240.846 us; speedup vs baseline: 1.3594x; 1.0126x over previous
//
#include <hip/hip_runtime.h>
#include <hip/hip_bf16.h>

#define B_  2
#define T_  1024
#define D_  768
#define H_  12
#define NT  2048        // B*T
#define DQ_ 1024
#define PH_ 4
#define NK_ 256
#define TK_ 32
#define DHK_ 128
#define QKVLD 2304      // merged QKV row stride
#define CVHALF 25165824L // half the values table, elements
#define NKEYS (PH_ * NK_ * 2 * DHK_)
#define PREPBLKS 3584   // 4*576 + 768 + 512

typedef __attribute__((ext_vector_type(8))) short bf16x8;
typedef __attribute__((ext_vector_type(4))) float f32x4;
typedef __attribute__((ext_vector_type(2))) float f32x2;

static __device__ __forceinline__ unsigned short f2bf(float f) {
    union { float f; unsigned u; } c; c.f = f;
    unsigned r = (c.u + 0x7fffu + ((c.u >> 16) & 1u)) >> 16;
    return (unsigned short)r;
}

static __device__ __forceinline__ float bf2f(unsigned short s) {
    union { unsigned u; float f; } c; c.u = ((unsigned)s) << 16;
    return c.f;
}

__device__ __constant__ unsigned short ctab[128] = {
    0,1,2,3,4,5,6,7,8,9,10,11,12,13,14,15,16,17,18,19,20,21,22,23,24,25,26,27,28,29,30,31,
    32,33,34,35,36,37,38,39,40,41,42,43,44,45,46,47,
    64,65,66,67,68,69,70,71,72,73,
    96,97,98,99,100,101,102,103,
    128,129,130,131,132,133,
    160,161,162,163,164,
    192,193,194,195,
    224,225,226,227,
    256,257,258,
    288,289,290,
    320,321, 352,353, 384,385, 416,417, 448,449, 480,481,
    512,544,576,608,640,672,704,736,768,800,832,864,896,928,960,992,
    0xFFFF,0xFFFF,0xFFFF,0xFFFF,0xFFFF,0xFFFF,0xFFFF,0xFFFF,0xFFFF
};

// ---------------- LayerNorm (rows < nrows) + hosted weight prep (rows >= nrows) ----------------
__global__ __launch_bounds__(256)
void ln_kernel(const float* __restrict__ x, const float* __restrict__ g,
               const float* __restrict__ b, unsigned short* __restrict__ out,
               int nrows,
               const float* __restrict__ wq, const float* __restrict__ wk,
               const float* __restrict__ wv, const float* __restrict__ wo,
               const float* __restrict__ pwq, const float* __restrict__ keys,
               unsigned short* __restrict__ wqkvT, unsigned short* __restrict__ woT,
               unsigned short* __restrict__ pwqT, unsigned short* __restrict__ keyB) {
    int tid = threadIdx.x;
    if ((int)blockIdx.x >= nrows) {
        int tb = blockIdx.x - nrows;
        if (tb >= 3072) {                         // keys convert: 512 blocks x 512 elems
            long i = ((long)(tb - 3072) * 256 + tid) * 2;
            if (i + 1 < NKEYS + 1) { keyB[i] = f2bf(keys[i]); keyB[i + 1] = f2bf(keys[i + 1]); }
            return;
        }
        __shared__ float t[32][33];
        const float* W; unsigned short* Wt; int N, kx, ny;
        if (tb < 2304) {
            int z = tb / 576, rem = tb % 576;
            kx = rem % 24; ny = rem / 24; N = 768;
            if (z == 0)      { W = wq; Wt = wqkvT; }
            else if (z == 1) { W = wk; Wt = wqkvT + 589824; }
            else if (z == 2) { W = wv; Wt = wqkvT + 2 * 589824; }
            else             { W = wo; Wt = woT; }
        } else {
            int rem = tb - 2304;
            kx = rem % 24; ny = rem / 24; N = 1024;
            W = pwq; Wt = pwqT;
        }
        int k0 = kx * 32, n0 = ny * 32;
        int tx = tid & 31, ty = tid >> 5;
#pragma unroll
        for (int i = 0; i < 4; ++i)
            t[ty + 8 * i][tx] = W[(long)(k0 + ty + 8 * i) * N + n0 + tx];
        __syncthreads();
#pragma unroll
        for (int i = 0; i < 4; ++i)
            Wt[(long)(n0 + ty + 8 * i) * 768 + k0 + tx] = f2bf(t[tx][ty + 8 * i]);
        return;
    }

    int row = blockIdx.x;
    const float* xr = x + (long)row * D_;
    float v0 = xr[tid], v1 = xr[tid + 256], v2 = xr[tid + 512];
    float s = v0 + v1 + v2, ss = v0 * v0 + v1 * v1 + v2 * v2;
#pragma unroll
    for (int o = 1; o < 64; o <<= 1) { s += __shfl_xor(s, o); ss += __shfl_xor(ss, o); }
    __shared__ float ps[4], pss[4];
    int wid = tid >> 6, lane = tid & 63;
    if (lane == 0) { ps[wid] = s; pss[wid] = ss; }
    __syncthreads();
    s = ps[0] + ps[1] + ps[2] + ps[3];
    ss = pss[0] + pss[1] + pss[2] + pss[3];
    float mean = s * (1.f / D_);
    float var = ss * (1.f / D_) - mean * mean;
    float rs = rsqrtf(var + 1e-5f);
    unsigned short* orow = out + (long)row * D_;
    orow[tid]       = f2bf((v0 - mean) * rs * g[tid]       + b[tid]);
    orow[tid + 256] = f2bf((v1 - mean) * rs * g[tid + 256] + b[tid + 256]);
    orow[tid + 512] = f2bf((v2 - mean) * rs * g[tid + 512] + b[tid + 512]);
}

// ---------------- MFMA GEMM (64x64 tile, 4 waves, BK=32) ----------------
__global__ __launch_bounds__(256)
void gemm_kernel(const unsigned short* __restrict__ A, int lda,
                 const unsigned short* __restrict__ Bt, int ldb,
                 const float* __restrict__ bias,
                 const float* __restrict__ bias2,
                 const float* __restrict__ bias3,
                 const float* __restrict__ res,
                 float* __restrict__ outF,
                 unsigned short* __restrict__ outB,
                 int ldc, int K, int zmode,
                 const float* __restrict__ cvin,
                 unsigned char* __restrict__ cvout,
                 long cvbase, int cvy0) {
    if (cvin && (int)blockIdx.y >= cvy0) {
        long stride = (long)(gridDim.y - cvy0) * gridDim.x * 256 * 8;
        long idx = cvbase +
            ((long)((blockIdx.y - cvy0) * gridDim.x + blockIdx.x) * 256 + threadIdx.x) * 8;
        long end = cvbase + CVHALF;
#pragma unroll 2
        for (; idx < end; idx += stride) {
            f32x4 a = *(const f32x4*)(cvin + idx);
            f32x4 b = *(const f32x4*)(cvin + idx + 4);
            int lo = __builtin_amdgcn_cvt_pk_fp8_f32(a[0], a[1], 0, false);
            lo = __builtin_amdgcn_cvt_pk_fp8_f32(a[2], a[3], lo, true);
            int hi = __builtin_amdgcn_cvt_pk_fp8_f32(b[0], b[1], 0, false);
            hi = __builtin_amdgcn_cvt_pk_fp8_f32(b[2], b[3], hi, true);
            *(uint2*)(cvout + idx) = make_uint2((unsigned)lo, (unsigned)hi);
        }
        return;
    }
    const int tid = threadIdx.x;
    const int w = tid >> 6, lane = tid & 63;
    const int ls = lane & 15, g = lane >> 4;
    const int m0 = blockIdx.x * 64, n0 = blockIdx.y * 64;

    __shared__ unsigned short As[64][40];
    __shared__ unsigned short Bs[64][40];

    f32x4 acc[4];
#pragma unroll
    for (int c = 0; c < 4; ++c) acc[c] = (f32x4){0.f, 0.f, 0.f, 0.f};

    const int lrow = tid >> 2, lseg = tid & 3;
    const unsigned short* gA = A + (long)(m0 + lrow) * lda + lseg * 8;
    const unsigned short* gB = Bt + (long)(n0 + lrow) * ldb + lseg * 8;

    for (int kt = 0; kt < K; kt += 32) {
        __syncthreads();
        *(int4*)&As[lrow][lseg * 8] = *(const int4*)(gA + kt);
        *(int4*)&Bs[lrow][lseg * 8] = *(const int4*)(gB + kt);
        __syncthreads();
        bf16x8 bfr = *(const bf16x8*)&Bs[w * 16 + ls][g * 8];
#pragma unroll
        for (int c = 0; c < 4; ++c) {
            bf16x8 afr = *(const bf16x8*)&As[c * 16 + ls][g * 8];
            acc[c] = __builtin_amdgcn_mfma_f32_16x16x32_bf16(afr, bfr, acc[c], 0, 0, 0);
        }
    }
#pragma unroll
    for (int c = 0; c < 4; ++c) {
#pragma unroll
        for (int r = 0; r < 4; ++r) {
            int row = m0 + c * 16 + g * 4 + r;
            int col = n0 + w * 16 + ls;
            float v = acc[c][r];
            if (bias) {
                const float* bp = bias; int cc = col;
                if (zmode == 2) {
                    int sel = col >= 1536 ? 2 : (col >= 768 ? 1 : 0);
                    bp = sel == 0 ? bias : (sel == 1 ? bias2 : bias3);
                    cc = col - sel * 768;
                }
                v += bp[cc];
            }
            long off = (long)row * ldc + col;
            if (res)  v += res[off];
            if (outF) outF[off] = v;
            if (outB) outB[off] = f2bf(v);
        }
    }
}

// ---------------- dots GEMM with fused BN finalize + normalize ----------------
// A = raw qf (bf16, un-normalized); each block reduces the 64 BN partials for its
// 128-column slice (deterministic redundant reduce) and normalizes A during staging.
// grid (32, 4, 8): z -> (ph, half). Output bf16 [2048][2048].
__global__ __launch_bounds__(256)
void dots_kernel(const unsigned short* __restrict__ qf,
                 const unsigned short* __restrict__ Bt,
                 const float* __restrict__ pS, const float* __restrict__ pSS,
                 const float* __restrict__ bng, const float* __restrict__ bnb,
                 unsigned short* __restrict__ outB) {
    int z = blockIdx.z, ph = z >> 1, half = z & 1;
    const int cbase = half * 512 + ph * 128;
    const unsigned short* A = qf + cbase;
    Bt   += ph * 65536 + half * 128;
    outB += ph * 512 + half * 256;
    const int tid = threadIdx.x;
    const int w = tid >> 6, lane = tid & 63;
    const int ls = lane & 15, g = lane >> 4;
    const int m0 = blockIdx.x * 64, n0 = blockIdx.y * 64;

    __shared__ unsigned short As[64][136];
    __shared__ unsigned short Bs[64][136];
    __shared__ float ggs[128], bbs[128];

    const int row = tid >> 2, cs = (tid & 3) * 32;
    const unsigned short* gA = A + (long)(m0 + row) * DQ_ + cs;
    const unsigned short* gB = Bt + (long)(n0 + row) * 256 + cs;

    // issue A loads to registers, stage B directly
    bf16x8 areg[4];
#pragma unroll
    for (int j = 0; j < 4; ++j) {
        areg[j] = *(const bf16x8*)(gA + 8 * j);
        *(int4*)&Bs[row][cs + 8 * j] = *(const int4*)(gB + 8 * j);
    }
    // BN finalize for this block's 128 columns
    if (tid < 128) {
        int c = cbase + tid;
        float s = 0.f, ss = 0.f;
#pragma unroll 8
        for (int i = 0; i < 64; ++i) { s += pS[(long)i * DQ_ + c]; ss += pSS[(long)i * DQ_ + c]; }
        float m = s * (1.f / NT);
        float rs = rsqrtf(ss * (1.f / NT) - m * m + 1e-5f);
        float gg = bng[c] * rs;
        ggs[tid] = gg;
        bbs[tid] = bnb[c] - m * gg;
    }
    __syncthreads();
    // normalize A in registers, write to LDS
#pragma unroll
    for (int j = 0; j < 4; ++j) {
        bf16x8 r;
#pragma unroll
        for (int k = 0; k < 8; ++k) {
            int lc = cs + 8 * j + k;
            r[k] = (short)f2bf(bf2f((unsigned short)areg[j][k]) * ggs[lc] + bbs[lc]);
        }
        *(bf16x8*)&As[row][cs + 8 * j] = r;
    }
    __syncthreads();

    f32x4 acc[4];
#pragma unroll
    for (int c = 0; c < 4; ++c) acc[c] = (f32x4){0.f, 0.f, 0.f, 0.f};
#pragma unroll
    for (int kk = 0; kk < 4; ++kk) {
        bf16x8 bfr = *(const bf16x8*)&Bs[w * 16 + ls][g * 8 + 32 * kk];
#pragma unroll
        for (int c = 0; c < 4; ++c) {
            bf16x8 afr = *(const bf16x8*)&As[c * 16 + ls][g * 8 + 32 * kk];
            acc[c] = __builtin_amdgcn_mfma_f32_16x16x32_bf16(afr, bfr, acc[c], 0, 0, 0);
        }
    }
#pragma unroll
    for (int c = 0; c < 4; ++c)
#pragma unroll
        for (int r = 0; r < 4; ++r)
            outB[(long)(m0 + c * 16 + g * 4 + r) * 2048 + n0 + w * 16 + ls] = f2bf(acc[c][r]);
}

// ---------------- MFMA flash attention: 8-wave blocks, 128 q-rows ----------------
__global__ __launch_bounds__(512)
void attn_mfma_kernel(const unsigned short* __restrict__ qkv,
                      unsigned short* __restrict__ outg) {
    int bh = blockIdx.x, bb = bh / H_, hh = bh % H_;
    int q0 = blockIdx.y * 128;
    int tid = threadIdx.x, wv = tid >> 6, lane = tid & 63;
    int ls = lane & 15, g = lane >> 4;

    __shared__ unsigned short Klds[128 * 64];
    __shared__ unsigned short Vlds[64 * 128];
    __shared__ unsigned short Plds[8][16 * 128];

    const unsigned short* qrow = qkv + (long)(bb * T_ + q0 + wv * 16 + ls) * QKVLD + hh * 64 + g * 8;
    bf16x8 qf0 = *(const bf16x8*)qrow;
    bf16x8 qf1 = *(const bf16x8*)(qrow + 32);

    f32x4 o_acc[4];
#pragma unroll
    for (int nf = 0; nf < 4; ++nf) o_acc[nf] = (f32x4){0.f, 0.f, 0.f, 0.f};
    float mrun[4] = {-1e30f, -1e30f, -1e30f, -1e30f};
    float lrun[4] = {0.f, 0.f, 0.f, 0.f};

    char* pbase = (char*)&Plds[wv][0];
    const bool doK = tid < 256;
    const int t2 = tid & 255;
    const int d0 = (t2 & 7) * 8, kvq = t2 >> 3;

    bf16x8 streg[4];
    auto loadKV = [&](int kvb) {
        if (doK) {
#pragma unroll
            for (int i = 0; i < 4; ++i) {
                int c = t2 + i * 256;
                streg[i] = *(const bf16x8*)(qkv + (long)(bb * T_ + kvb + (c >> 3)) * QKVLD + 768 + hh * 64 + (c & 7) * 8);
            }
        } else {
            const unsigned short* vb = qkv + (long)(bb * T_ + kvb + kvq * 4) * QKVLD + 1536 + hh * 64 + d0;
#pragma unroll
            for (int i = 0; i < 4; ++i) streg[i] = *(const bf16x8*)(vb + i * QKVLD);
        }
    };

    loadKV(0);
    for (int kt = 0; kt < T_ / 128; ++kt) {
        __syncthreads();
        if (doK) {
#pragma unroll
            for (int i = 0; i < 4; ++i) {
                int c = t2 + i * 256;
                int kv = c >> 3, dc = c & 7;
                *(bf16x8*)((char*)Klds + ((kv * 128 + dc * 16) ^ ((kv & 7) << 4))) = streg[i];
            }
        } else {
#pragma unroll
            for (int j = 0; j < 8; ++j) {
                unsigned lo = (unsigned)(unsigned short)streg[0][j] | ((unsigned)(unsigned short)streg[1][j] << 16);
                unsigned hi = (unsigned)(unsigned short)streg[2][j] | ((unsigned)(unsigned short)streg[3][j] << 16);
                int d = d0 + j;
                *(uint2*)((char*)Vlds + ((d * 256 + kvq * 8) ^ ((d & 7) << 4))) = make_uint2(lo, hi);
            }
        }
        __syncthreads();
        if (kt + 1 < T_ / 128) loadKV((kt + 1) * 128);

        f32x4 sa[8];
#pragma unroll
        for (int f = 0; f < 8; ++f) sa[f] = (f32x4){0.f, 0.f, 0.f, 0.f};
        __builtin_amdgcn_s_setprio(1);
#pragma unroll
        for (int f = 0; f < 8; ++f) {
            int kv = f * 16 + ls;
            bf16x8 b0 = *(const bf16x8*)((char*)Klds + ((kv * 128 + g * 16) ^ ((kv & 7) << 4)));
            bf16x8 b1 = *(const bf16x8*)((char*)Klds + ((kv * 128 + 64 + g * 16) ^ ((kv & 7) << 4)));
            sa[f] = __builtin_amdgcn_mfma_f32_16x16x32_bf16(qf0, b0, sa[f], 0, 0, 0);
            sa[f] = __builtin_amdgcn_mfma_f32_16x16x32_bf16(qf1, b1, sa[f], 0, 0, 0);
        }
        __builtin_amdgcn_s_setprio(0);

        float pw[8][4];
#pragma unroll
        for (int f = 0; f < 8; ++f)
#pragma unroll
            for (int r = 0; r < 4; ++r) pw[f][r] = sa[f][r] * 0.125f;
#pragma unroll
        for (int r = 0; r < 4; ++r) {
            float m = pw[0][r];
#pragma unroll
            for (int f = 1; f < 8; ++f) m = fmaxf(m, pw[f][r]);
            m = fmaxf(m, __shfl_xor(m, 1));
            m = fmaxf(m, __shfl_xor(m, 2));
            m = fmaxf(m, __shfl_xor(m, 4));
            m = fmaxf(m, __shfl_xor(m, 8));
            if (m > mrun[r] + 8.f) {
                float fac = __expf(mrun[r] - m);
                lrun[r] *= fac;
#pragma unroll
                for (int nf = 0; nf < 4; ++nf) o_acc[nf][r] *= fac;
                mrun[r] = m;
            }
            float s = 0.f;
#pragma unroll
            for (int f = 0; f < 8; ++f) { float e = __expf(pw[f][r] - mrun[r]); pw[f][r] = e; s += e; }
            s += __shfl_xor(s, 1); s += __shfl_xor(s, 2);
            s += __shfl_xor(s, 4); s += __shfl_xor(s, 8);
            lrun[r] += s;
        }

#pragma unroll
        for (int f = 0; f < 8; ++f)
#pragma unroll
            for (int r = 0; r < 4; ++r) {
                int qr = g * 4 + r, col = ls + 16 * f;
                *(unsigned short*)(pbase + ((qr * 256 + col * 2) ^ ((qr & 7) << 4))) = f2bf(pw[f][r]);
            }

        __builtin_amdgcn_s_setprio(1);
#pragma unroll
        for (int ks = 0; ks < 4; ++ks) {
            bf16x8 pa = *(const bf16x8*)(pbase + ((ls * 256 + ks * 64 + g * 16) ^ ((ls & 7) << 4)));
#pragma unroll
            for (int nf = 0; nf < 4; ++nf) {
                int d = nf * 16 + ls;
                bf16x8 bv = *(const bf16x8*)((char*)Vlds + ((d * 256 + ks * 64 + g * 16) ^ ((d & 7) << 4)));
                o_acc[nf] = __builtin_amdgcn_mfma_f32_16x16x32_bf16(pa, bv, o_acc[nf], 0, 0, 0);
            }
        }
        __builtin_amdgcn_s_setprio(0);
    }

    float inv[4];
#pragma unroll
    for (int r = 0; r < 4; ++r) inv[r] = 1.f / lrun[r];
#pragma unroll
    for (int nf = 0; nf < 4; ++nf)
#pragma unroll
        for (int r = 0; r < 4; ++r) {
            long row = bb * T_ + q0 + wv * 16 + g * 4 + r;
            outg[row * D_ + hh * 64 + nf * 16 + ls] = f2bf(o_acc[nf][r] * inv[r]);
        }
}

// ---------------- BatchNorm partials (bf16 qf input) ----------------
__global__ __launch_bounds__(256)
void bn_part(const unsigned short* __restrict__ qf, float* __restrict__ pS, float* __restrict__ pSS) {
    int c = blockIdx.y * 256 + threadIdx.x;
    int r0 = blockIdx.x * 32;
    float s = 0.f, ss = 0.f;
#pragma unroll 4
    for (int r = 0; r < 32; ++r) {
        float v = bf2f(qf[(long)(r0 + r) * DQ_ + c]);
        s += v; ss += v * v;
    }
    pS[(long)blockIdx.x * DQ_ + c] = s;
    pSS[(long)blockIdx.x * DQ_ + c] = ss;
}

// ---------------- FUSED tail: top-k (8 waves) + softmax + fp8 gather + residual ----------------
__global__ __launch_bounds__(512)
void pkm_tail_fp8(const unsigned short* __restrict__ dots,
                  const unsigned char* __restrict__ vals8,
                  const float* __restrict__ x1,
                  float* __restrict__ outp) {
    __shared__ float sv[4][64];
    __shared__ int   sidx[4][64];
    __shared__ float w[128];
    __shared__ int   rows[128];
    __shared__ float red[3 * 768];
    int n = blockIdx.x, tid = threadIdx.x;
    int wv = tid >> 6, lane = tid & 63;
    int slot = wv >> 1, half = wv & 1;

    {
        const unsigned short* d = dots + (long)n * 2048 + slot * 512 + half * 256;
        float v0 = bf2f(d[lane]), v1 = bf2f(d[lane + 64]);
        float v2 = bf2f(d[lane + 128]), v3 = bf2f(d[lane + 192]);
#pragma unroll 1
        for (int t = 0; t < 32; ++t) {
            float bm = v0; int ba = 0;
            if (v1 > bm) { bm = v1; ba = 1; }
            if (v2 > bm) { bm = v2; ba = 2; }
            if (v3 > bm) { bm = v3; ba = 3; }
            float wm = bm;
#pragma unroll
            for (int o = 32; o >= 1; o >>= 1) wm = fmaxf(wm, __shfl_xor(wm, o));
            unsigned long long msk = __ballot(bm == wm);
            int owner = (int)__builtin_ctzll(msk);
            if (lane == owner) {
                sv[slot][half * 32 + t] = wm;
                sidx[slot][half * 32 + t] = ba * 64 + lane;
                if (ba == 0) v0 = -1e30f;
                else if (ba == 1) v1 = -1e30f;
                else if (ba == 2) v2 = -1e30f;
                else v3 = -1e30f;
            }
        }
    }
    __syncthreads();

    if (!half) {
        unsigned short t0 = ctab[lane], t1 = ctab[lane + 64];
        float c0 = -1e30f, c1 = -1e30f;
        int id0 = 0, id1 = 0;
        {
            int i = t0 >> 5, j = t0 & 31;
            c0 = sv[slot][i] + sv[slot][32 + j];
            id0 = sidx[slot][i] * NK_ + sidx[slot][32 + j];
        }
        if (t1 != 0xFFFF) {
            int i = t1 >> 5, j = t1 & 31;
            c1 = sv[slot][i] + sv[slot][32 + j];
            id1 = sidx[slot][i] * NK_ + sidx[slot][32 + j];
        }
#pragma unroll 1
        for (int t = 0; t < 32; ++t) {
            float bm = c0; int sel = 0;
            if (c1 > bm) { bm = c1; sel = 1; }
            float wm = bm;
#pragma unroll
            for (int o = 32; o >= 1; o >>= 1) wm = fmaxf(wm, __shfl_xor(wm, o));
            unsigned long long msk = __ballot(bm == wm);
            int owner = (int)__builtin_ctzll(msk);
            if (lane == owner) {
                w[slot * 32 + t] = wm;
                rows[slot * 32 + t] = sel ? id1 : id0;
                if (sel) c1 = -1e30f; else c0 = -1e30f;
            }
        }
    }
    __syncthreads();

    if (tid < 128) {
        float e = w[tid];
        float m = e;
#pragma unroll
        for (int o = 16; o >= 1; o >>= 1) m = fmaxf(m, __shfl_xor(m, o));
        float ex = __expf(e - m);
        float s = ex;
#pragma unroll
        for (int o = 16; o >= 1; o >>= 1) s += __shfl_xor(s, o);
        w[tid] = ex / s;
    }
    __syncthreads();

    int gs = tid >> 7, chunk = tid & 127;
    float a0=0.f,a1=0.f,a2=0.f,a3=0.f,a4=0.f,a5=0.f,a6=0.f,a7=0.f;
    if (chunk < 96) {
#pragma unroll 4
        for (int e = 0; e < 32; ++e) {
            int er = e * 4 + gs;
            float wgt = w[er];
            long ro = (long)rows[er] * D_;
            uint2 v = *(const uint2*)(vals8 + ro + chunk * 8);
            f32x2 f0 = __builtin_amdgcn_cvt_pk_f32_fp8((int)v.x, false);
            f32x2 f1 = __builtin_amdgcn_cvt_pk_f32_fp8((int)v.x, true);
            f32x2 f2 = __builtin_amdgcn_cvt_pk_f32_fp8((int)v.y, false);
            f32x2 f3 = __builtin_amdgcn_cvt_pk_f32_fp8((int)v.y, true);
            a0 += wgt * f0[0]; a1 += wgt * f0[1]; a2 += wgt * f1[0]; a3 += wgt * f1[1];
            a4 += wgt * f2[0]; a5 += wgt * f2[1]; a6 += wgt * f3[0]; a7 += wgt * f3[1];
        }
        if (gs > 0) {
            float* rp = &red[(gs - 1) * 768 + chunk * 8];
            rp[0]=a0; rp[1]=a1; rp[2]=a2; rp[3]=a3; rp[4]=a4; rp[5]=a5; rp[6]=a6; rp[7]=a7;
        }
    }
    __syncthreads();
    if (gs == 0 && chunk < 96) {
        long o = (long)n * D_ + chunk * 8;
        const float* r0 = &red[chunk * 8];
        const float* r1 = &red[768 + chunk * 8];
        const float* r2 = &red[1536 + chunk * 8];
        f32x4 xa = *(const f32x4*)(x1 + o);
        f32x4 xb = *(const f32x4*)(x1 + o + 4);
        f32x4 o1 = { a0 + r0[0] + r1[0] + r2[0] + xa[0], a1 + r0[1] + r1[1] + r2[1] + xa[1],
                     a2 + r0[2] + r1[2] + r2[2] + xa[2], a3 + r0[3] + r1[3] + r2[3] + xa[3] };
        f32x4 o2 = { a4 + r0[4] + r1[4] + r2[4] + xb[0], a5 + r0[5] + r1[5] + r2[5] + xb[1],
                     a6 + r0[6] + r1[6] + r2[6] + xb[2], a7 + r0[7] + r1[7] + r2[7] + xb[3] };
        *(f32x4*)(outp + o) = o1;
        *(f32x4*)(outp + o + 4) = o2;
    }
}

// ---------------- fallback pair (f32 table): topk + gather ----------------
__global__ __launch_bounds__(256)
void topk_kernel(const unsigned short* __restrict__ dots, float* __restrict__ fs, int* __restrict__ vi) {
    __shared__ float sv[2][64];
    __shared__ int   sidx[2][64];
    int tid = threadIdx.x, wv = tid >> 6, lane = tid & 63;
    int slot = wv >> 1, half = wv & 1;
    long task = (long)blockIdx.x * 2 + slot;
    const unsigned short* d = dots + (task >> 2) * 2048 + (task & 3) * 512 + half * 256;

    float v0 = bf2f(d[lane]), v1 = bf2f(d[lane + 64]);
    float v2 = bf2f(d[lane + 128]), v3 = bf2f(d[lane + 192]);
#pragma unroll 1
    for (int t = 0; t < 32; ++t) {
        float bm = v0; int ba = 0;
        if (v1 > bm) { bm = v1; ba = 1; }
        if (v2 > bm) { bm = v2; ba = 2; }
        if (v3 > bm) { bm = v3; ba = 3; }
        float wm = bm;
#pragma unroll
        for (int o = 32; o >= 1; o >>= 1) wm = fmaxf(wm, __shfl_xor(wm, o));
        unsigned long long msk = __ballot(bm == wm);
        int owner = (int)__builtin_ctzll(msk);
        if (lane == owner) {
            sv[slot][half * 32 + t] = wm;
            sidx[slot][half * 32 + t] = ba * 64 + lane;
            if (ba == 0) v0 = -1e30f;
            else if (ba == 1) v1 = -1e30f;
            else if (ba == 2) v2 = -1e30f;
            else v3 = -1e30f;
        }
    }
    __syncthreads();
    if (half) return;

    unsigned short t0 = ctab[lane], t1 = ctab[lane + 64];
    float c0 = -1e30f, c1 = -1e30f;
    int id0 = 0, id1 = 0;
    {
        int i = t0 >> 5, j = t0 & 31;
        c0 = sv[slot][i] + sv[slot][32 + j];
        id0 = sidx[slot][i] * NK_ + sidx[slot][32 + j];
    }
    if (t1 != 0xFFFF) {
        int i = t1 >> 5, j = t1 & 31;
        c1 = sv[slot][i] + sv[slot][32 + j];
        id1 = sidx[slot][i] * NK_ + sidx[slot][32 + j];
    }

    float* fo = fs + task * 32;
    int*   vo = vi + task * 32;
#pragma unroll 1
    for (int t = 0; t < 32; ++t) {
        float bm = c0; int sel = 0;
        if (c1 > bm) { bm = c1; sel = 1; }
        float wm = bm;
#pragma unroll
        for (int o = 32; o >= 1; o >>= 1) wm = fmaxf(wm, __shfl_xor(wm, o));
        unsigned long long msk = __ballot(bm == wm);
        int owner = (int)__builtin_ctzll(msk);
        if (lane == owner) {
            fo[t] = wm;
            vo[t] = sel ? id1 : id0;
            if (sel) c1 = -1e30f; else c0 = -1e30f;
        }
    }
}

__global__ __launch_bounds__(384)
void pkm_out_f32(const float* __restrict__ fs, const int* __restrict__ vi,
                 const float* __restrict__ values, const float* __restrict__ x1,
                 float* __restrict__ outp) {
    int n = blockIdx.x, tid = threadIdx.x;
    __shared__ float w[128];
    __shared__ int   rows[128];
    __shared__ float red[768];
    if (tid < 128) {
        float e = fs[(long)n * 128 + tid];
        rows[tid] = vi[(long)n * 128 + tid];
        float m = e;
#pragma unroll
        for (int o = 16; o >= 1; o >>= 1) m = fmaxf(m, __shfl_xor(m, o));
        float ex = __expf(e - m);
        float s = ex;
#pragma unroll
        for (int o = 16; o >= 1; o >>= 1) s += __shfl_xor(s, o);
        w[tid] = ex / s;
    }
    __syncthreads();
    int slot = tid / 192, chunk = tid % 192;
    float a0 = 0.f, a1 = 0.f, a2 = 0.f, a3 = 0.f;
#pragma unroll 4
    for (int e = 0; e < 64; ++e) {
        int er = e * 2 + slot;
        float wgt = w[er];
        long ro = (long)rows[er] * D_;
        f32x4 v = *(const f32x4*)(values + ro + chunk * 4);
        a0 += wgt * v[0]; a1 += wgt * v[1]; a2 += wgt * v[2]; a3 += wgt * v[3];
    }
    if (slot == 1) {
        f32x4 t = {a0, a1, a2, a3};
        *(f32x4*)&red[chunk * 4] = t;
    }
    __syncthreads();
    if (slot == 0) {
        f32x4 o = *(const f32x4*)&red[chunk * 4];
        f32x4 xr = *(const f32x4*)(x1 + (long)n * D_ + chunk * 4);
        o[0] += a0 + xr[0]; o[1] += a1 + xr[1]; o[2] += a2 + xr[2]; o[3] += a3 + xr[3];
        *(f32x4*)(outp + (long)n * D_ + chunk * 4) = o;
    }
}

extern "C" void kernel_launch(void* const* d_in, const int* in_sizes, int n_in,
                              void* d_out, int out_size, void* d_ws, size_t ws_size,
                              hipStream_t stream) {
    const float* x    = (const float*)d_in[0];
    const float* wq   = (const float*)d_in[1];
    const float* bq   = (const float*)d_in[2];
    const float* wk   = (const float*)d_in[3];
    const float* bk   = (const float*)d_in[4];
    const float* wv   = (const float*)d_in[5];
    const float* bv   = (const float*)d_in[6];
    const float* wo   = (const float*)d_in[7];
    const float* bo   = (const float*)d_in[8];
    const float* ln1g = (const float*)d_in[9];
    const float* ln1b = (const float*)d_in[10];
    const float* ln2g = (const float*)d_in[11];
    const float* ln2b = (const float*)d_in[12];
    const float* pwq  = (const float*)d_in[13];
    const float* bng  = (const float*)d_in[14];
    const float* bnb  = (const float*)d_in[15];
    const float* keys = (const float*)d_in[16];
    const float* vals = (const float*)d_in[17];
    float* out = (float*)d_out;

    char* p = (char*)d_ws;
    auto alloc = [&](size_t bytes) -> char* {
        char* r = p; p += (bytes + 255) & ~(size_t)255; return r;
    };
    unsigned short* wqkvT = (unsigned short*)alloc((size_t)3 * D_ * D_ * 2);
    unsigned short* woT   = (unsigned short*)alloc((size_t)D_ * D_ * 2);
    unsigned short* pwqT  = (unsigned short*)alloc((size_t)D_ * DQ_ * 2);
    unsigned short* keyB  = (unsigned short*)alloc((size_t)NKEYS * 2);
    unsigned short* h1    = (unsigned short*)alloc((size_t)NT * D_ * 2);
    unsigned short* qkvB  = (unsigned short*)alloc((size_t)NT * QKVLD * 2);
    unsigned short* aout  = (unsigned short*)alloc((size_t)NT * D_ * 2);
    float* x1             = (float*)alloc((size_t)NT * D_ * 4);
    unsigned short* h2    = (unsigned short*)alloc((size_t)NT * D_ * 2);
    unsigned short* qfB   = (unsigned short*)alloc((size_t)NT * DQ_ * 2);
    float* pS             = (float*)alloc((size_t)64 * DQ_ * 4);
    float* pSS            = (float*)alloc((size_t)64 * DQ_ * 4);
    unsigned short* dots  = (unsigned short*)alloc((size_t)NT * 2048 * 2);
    float* fsb            = (float*)alloc((size_t)NT * PH_ * 32 * 4);
    int*   vib            = (int*)alloc((size_t)NT * PH_ * 32 * 4);

    // fp8 values table if workspace allows (~50.4 MB more)
    size_t used = (size_t)(p - (char*)d_ws);
    size_t vbytes = (size_t)NK_ * NK_ * D_;
    bool useTab = (used + vbytes + 256) <= ws_size;
    unsigned char* vals8 = nullptr;
    if (useTab) vals8 = (unsigned char*)alloc(vbytes);

    // LN1 + hosted weight prep (transposes + keys convert)
    ln_kernel<<<NT + PREPBLKS, 256, 0, stream>>>(
        x, ln1g, ln1b, h1, NT, wq, wk, wv, wo, pwq, keys, wqkvT, woT, pwqT, keyB);
    // merged QKV GEMM -> qkvB; hosts first half of the values-table conversion
    gemm_kernel<<<dim3(32, useTab ? 52 : 36), 256, 0, stream>>>(
        h1, D_, wqkvT, D_, bq, bk, bv, nullptr, nullptr, qkvB, QKVLD, D_, 2,
        useTab ? vals : nullptr, vals8, 0L, 36);
    // attention (8-wave blocks, 128 q-rows, grid 192)
    attn_mfma_kernel<<<dim3(B_ * H_, T_ / 128), 512, 0, stream>>>(qkvB, aout);
    // output projection + residual
    gemm_kernel<<<dim3(32, 12), 256, 0, stream>>>(
        aout, D_, woT, D_, bo, nullptr, nullptr, x, x1, nullptr, D_, D_, 0,
        nullptr, nullptr, 0L, 0);
    // LN2
    ln_kernel<<<NT, 256, 0, stream>>>(
        x1, ln2g, ln2b, h2, NT, nullptr, nullptr, nullptr, nullptr, nullptr, nullptr,
        nullptr, nullptr, nullptr, nullptr);
    // PKM query GEMM (bf16 qf, un-normalized); hosts second half of the table conversion
    gemm_kernel<<<dim3(32, useTab ? 32 : 16), 256, 0, stream>>>(
        h2, D_, pwqT, D_, nullptr, nullptr, nullptr, nullptr, nullptr, qfB, DQ_, D_, 0,
        useTab ? vals : nullptr, vals8, CVHALF, 16);
    // BatchNorm partials
    bn_part<<<dim3(64, 4), 256, 0, stream>>>(qfB, pS, pSS);
    // dots GEMM with fused BN finalize + normalize -> bf16
    dots_kernel<<<dim3(32, 4, 8), 256, 0, stream>>>(qfB, keyB, pS, pSS, bng, bnb, dots);
    // fused tail: top-k + softmax + gather + residual
    if (useTab) {
        pkm_tail_fp8<<<NT, 512, 0, stream>>>(dots, vals8, x1, out);
    } else {
        topk_kernel<<<(NT * PH_) / 2, 256, 0, stream>>>(dots, fsb, vib);
        pkm_out_f32<<<NT, 384, 0, stream>>>(fsb, vib, vals, x1, out);
    }
}

// Round 17
// 235.002 us; speedup vs baseline: 1.3932x; 1.0249x over previous
//
#include <hip/hip_runtime.h>
#include <hip/hip_bf16.h>

#define B_  2
#define T_  1024
#define D_  768
#define H_  12
#define NT  2048        // B*T
#define DQ_ 1024
#define PH_ 4
#define NK_ 256
#define TK_ 32
#define DHK_ 128
#define QKVLD 2304      // merged QKV row stride
#define CVHALF 25165824L // half the values table, elements
#define NKEYS (PH_ * NK_ * 2 * DHK_)
#define PREPBLKS 3584   // 4*576 + 768 + 512

typedef __attribute__((ext_vector_type(8))) short bf16x8;
typedef __attribute__((ext_vector_type(4))) float f32x4;
typedef __attribute__((ext_vector_type(2))) float f32x2;

static __device__ __forceinline__ unsigned short f2bf(float f) {
    union { float f; unsigned u; } c; c.f = f;
    unsigned r = (c.u + 0x7fffu + ((c.u >> 16) & 1u)) >> 16;
    return (unsigned short)r;
}

static __device__ __forceinline__ float bf2f(unsigned short s) {
    union { unsigned u; float f; } c; c.u = ((unsigned)s) << 16;
    return c.f;
}

__device__ __constant__ unsigned short ctab[128] = {
    0,1,2,3,4,5,6,7,8,9,10,11,12,13,14,15,16,17,18,19,20,21,22,23,24,25,26,27,28,29,30,31,
    32,33,34,35,36,37,38,39,40,41,42,43,44,45,46,47,
    64,65,66,67,68,69,70,71,72,73,
    96,97,98,99,100,101,102,103,
    128,129,130,131,132,133,
    160,161,162,163,164,
    192,193,194,195,
    224,225,226,227,
    256,257,258,
    288,289,290,
    320,321, 352,353, 384,385, 416,417, 448,449, 480,481,
    512,544,576,608,640,672,704,736,768,800,832,864,896,928,960,992,
    0xFFFF,0xFFFF,0xFFFF,0xFFFF,0xFFFF,0xFFFF,0xFFFF,0xFFFF,0xFFFF
};

// ---------------- LayerNorm (rows < nrows) + hosted weight prep (rows >= nrows) ----------------
__global__ __launch_bounds__(256)
void ln_kernel(const float* __restrict__ x, const float* __restrict__ g,
               const float* __restrict__ b, unsigned short* __restrict__ out,
               int nrows,
               const float* __restrict__ wq, const float* __restrict__ wk,
               const float* __restrict__ wv, const float* __restrict__ wo,
               const float* __restrict__ pwq, const float* __restrict__ keys,
               unsigned short* __restrict__ wqkvT, unsigned short* __restrict__ woT,
               unsigned short* __restrict__ pwqT, unsigned short* __restrict__ keyB) {
    int tid = threadIdx.x;
    if ((int)blockIdx.x >= nrows) {
        int tb = blockIdx.x - nrows;
        if (tb >= 3072) {                         // keys convert: 512 blocks x 512 elems
            long i = ((long)(tb - 3072) * 256 + tid) * 2;
            if (i + 1 < NKEYS + 1) { keyB[i] = f2bf(keys[i]); keyB[i + 1] = f2bf(keys[i + 1]); }
            return;
        }
        __shared__ float t[32][33];
        const float* W; unsigned short* Wt; int N, kx, ny;
        if (tb < 2304) {
            int z = tb / 576, rem = tb % 576;
            kx = rem % 24; ny = rem / 24; N = 768;
            if (z == 0)      { W = wq; Wt = wqkvT; }
            else if (z == 1) { W = wk; Wt = wqkvT + 589824; }
            else if (z == 2) { W = wv; Wt = wqkvT + 2 * 589824; }
            else             { W = wo; Wt = woT; }
        } else {
            int rem = tb - 2304;
            kx = rem % 24; ny = rem / 24; N = 1024;
            W = pwq; Wt = pwqT;
        }
        int k0 = kx * 32, n0 = ny * 32;
        int tx = tid & 31, ty = tid >> 5;
#pragma unroll
        for (int i = 0; i < 4; ++i)
            t[ty + 8 * i][tx] = W[(long)(k0 + ty + 8 * i) * N + n0 + tx];
        __syncthreads();
#pragma unroll
        for (int i = 0; i < 4; ++i)
            Wt[(long)(n0 + ty + 8 * i) * 768 + k0 + tx] = f2bf(t[tx][ty + 8 * i]);
        return;
    }

    int row = blockIdx.x;
    const float* xr = x + (long)row * D_;
    float v0 = xr[tid], v1 = xr[tid + 256], v2 = xr[tid + 512];
    float s = v0 + v1 + v2, ss = v0 * v0 + v1 * v1 + v2 * v2;
#pragma unroll
    for (int o = 1; o < 64; o <<= 1) { s += __shfl_xor(s, o); ss += __shfl_xor(ss, o); }
    __shared__ float ps[4], pss[4];
    int wid = tid >> 6, lane = tid & 63;
    if (lane == 0) { ps[wid] = s; pss[wid] = ss; }
    __syncthreads();
    s = ps[0] + ps[1] + ps[2] + ps[3];
    ss = pss[0] + pss[1] + pss[2] + pss[3];
    float mean = s * (1.f / D_);
    float var = ss * (1.f / D_) - mean * mean;
    float rs = rsqrtf(var + 1e-5f);
    unsigned short* orow = out + (long)row * D_;
    orow[tid]       = f2bf((v0 - mean) * rs * g[tid]       + b[tid]);
    orow[tid + 256] = f2bf((v1 - mean) * rs * g[tid + 256] + b[tid + 256]);
    orow[tid + 512] = f2bf((v2 - mean) * rs * g[tid + 512] + b[tid + 512]);
}

// ---------------- MFMA GEMM (64x64 tile, 4 waves, BK=32) ----------------
// Optional fused column-partials epilogue (pSo/pSSo != null): per-block sums of each
// output column (pre-bf16-rounding), written to pSo[blockIdx.x][col] (deterministic).
__global__ __launch_bounds__(256)
void gemm_kernel(const unsigned short* __restrict__ A, int lda,
                 const unsigned short* __restrict__ Bt, int ldb,
                 const float* __restrict__ bias,
                 const float* __restrict__ bias2,
                 const float* __restrict__ bias3,
                 const float* __restrict__ res,
                 float* __restrict__ outF,
                 unsigned short* __restrict__ outB,
                 int ldc, int K, int zmode,
                 const float* __restrict__ cvin,
                 unsigned char* __restrict__ cvout,
                 long cvbase, int cvy0,
                 float* __restrict__ pSo, float* __restrict__ pSSo) {
    if (cvin && (int)blockIdx.y >= cvy0) {
        long stride = (long)(gridDim.y - cvy0) * gridDim.x * 256 * 8;
        long idx = cvbase +
            ((long)((blockIdx.y - cvy0) * gridDim.x + blockIdx.x) * 256 + threadIdx.x) * 8;
        long end = cvbase + CVHALF;
#pragma unroll 2
        for (; idx < end; idx += stride) {
            f32x4 a = *(const f32x4*)(cvin + idx);
            f32x4 b = *(const f32x4*)(cvin + idx + 4);
            int lo = __builtin_amdgcn_cvt_pk_fp8_f32(a[0], a[1], 0, false);
            lo = __builtin_amdgcn_cvt_pk_fp8_f32(a[2], a[3], lo, true);
            int hi = __builtin_amdgcn_cvt_pk_fp8_f32(b[0], b[1], 0, false);
            hi = __builtin_amdgcn_cvt_pk_fp8_f32(b[2], b[3], hi, true);
            *(uint2*)(cvout + idx) = make_uint2((unsigned)lo, (unsigned)hi);
        }
        return;
    }
    const int tid = threadIdx.x;
    const int w = tid >> 6, lane = tid & 63;
    const int ls = lane & 15, g = lane >> 4;
    const int m0 = blockIdx.x * 64, n0 = blockIdx.y * 64;

    __shared__ unsigned short As[64][40];
    __shared__ unsigned short Bs[64][40];

    f32x4 acc[4];
#pragma unroll
    for (int c = 0; c < 4; ++c) acc[c] = (f32x4){0.f, 0.f, 0.f, 0.f};

    const int lrow = tid >> 2, lseg = tid & 3;
    const unsigned short* gA = A + (long)(m0 + lrow) * lda + lseg * 8;
    const unsigned short* gB = Bt + (long)(n0 + lrow) * ldb + lseg * 8;

    for (int kt = 0; kt < K; kt += 32) {
        __syncthreads();
        *(int4*)&As[lrow][lseg * 8] = *(const int4*)(gA + kt);
        *(int4*)&Bs[lrow][lseg * 8] = *(const int4*)(gB + kt);
        __syncthreads();
        bf16x8 bfr = *(const bf16x8*)&Bs[w * 16 + ls][g * 8];
#pragma unroll
        for (int c = 0; c < 4; ++c) {
            bf16x8 afr = *(const bf16x8*)&As[c * 16 + ls][g * 8];
            acc[c] = __builtin_amdgcn_mfma_f32_16x16x32_bf16(afr, bfr, acc[c], 0, 0, 0);
        }
    }
#pragma unroll
    for (int c = 0; c < 4; ++c) {
#pragma unroll
        for (int r = 0; r < 4; ++r) {
            int row = m0 + c * 16 + g * 4 + r;
            int col = n0 + w * 16 + ls;
            float v = acc[c][r];
            if (bias) {
                const float* bp = bias; int cc = col;
                if (zmode == 2) {
                    int sel = col >= 1536 ? 2 : (col >= 768 ? 1 : 0);
                    bp = sel == 0 ? bias : (sel == 1 ? bias2 : bias3);
                    cc = col - sel * 768;
                }
                v += bp[cc];
            }
            long off = (long)row * ldc + col;
            if (res)  v += res[off];
            if (outF) outF[off] = v;
            if (outB) outB[off] = f2bf(v);
        }
    }
    if (pSo) {
        float s = 0.f, ss = 0.f;
#pragma unroll
        for (int c = 0; c < 4; ++c)
#pragma unroll
            for (int r = 0; r < 4; ++r) { float v = acc[c][r]; s += v; ss += v * v; }
        s += __shfl_xor(s, 16); s += __shfl_xor(s, 32);
        ss += __shfl_xor(ss, 16); ss += __shfl_xor(ss, 32);
        if (g == 0) {
            int col = n0 + w * 16 + ls;
            pSo[(long)blockIdx.x * DQ_ + col] = s;
            pSSo[(long)blockIdx.x * DQ_ + col] = ss;
        }
    }
}

// ---------------- dots GEMM with fused BN finalize + normalize ----------------
// A = raw qf (bf16, un-normalized); each block reduces the 32 BN partials for its
// 128-column slice (deterministic redundant reduce) and normalizes A during staging.
// grid (32, 4, 8): z -> (ph, half). Output bf16 [2048][2048].
__global__ __launch_bounds__(256)
void dots_kernel(const unsigned short* __restrict__ qf,
                 const unsigned short* __restrict__ Bt,
                 const float* __restrict__ pS, const float* __restrict__ pSS,
                 const float* __restrict__ bng, const float* __restrict__ bnb,
                 unsigned short* __restrict__ outB) {
    int z = blockIdx.z, ph = z >> 1, half = z & 1;
    const int cbase = half * 512 + ph * 128;
    const unsigned short* A = qf + cbase;
    Bt   += ph * 65536 + half * 128;
    outB += ph * 512 + half * 256;
    const int tid = threadIdx.x;
    const int w = tid >> 6, lane = tid & 63;
    const int ls = lane & 15, g = lane >> 4;
    const int m0 = blockIdx.x * 64, n0 = blockIdx.y * 64;

    __shared__ unsigned short As[64][136];
    __shared__ unsigned short Bs[64][136];
    __shared__ float ggs[128], bbs[128];

    const int row = tid >> 2, cs = (tid & 3) * 32;
    const unsigned short* gA = A + (long)(m0 + row) * DQ_ + cs;
    const unsigned short* gB = Bt + (long)(n0 + row) * 256 + cs;

    // issue A loads to registers, stage B directly
    bf16x8 areg[4];
#pragma unroll
    for (int j = 0; j < 4; ++j) {
        areg[j] = *(const bf16x8*)(gA + 8 * j);
        *(int4*)&Bs[row][cs + 8 * j] = *(const int4*)(gB + 8 * j);
    }
    // BN finalize for this block's 128 columns (32 row-partials)
    if (tid < 128) {
        int c = cbase + tid;
        float s = 0.f, ss = 0.f;
#pragma unroll 8
        for (int i = 0; i < 32; ++i) { s += pS[(long)i * DQ_ + c]; ss += pSS[(long)i * DQ_ + c]; }
        float m = s * (1.f / NT);
        float rs = rsqrtf(ss * (1.f / NT) - m * m + 1e-5f);
        float gg = bng[c] * rs;
        ggs[tid] = gg;
        bbs[tid] = bnb[c] - m * gg;
    }
    __syncthreads();
    // normalize A in registers, write to LDS
#pragma unroll
    for (int j = 0; j < 4; ++j) {
        bf16x8 r;
#pragma unroll
        for (int k = 0; k < 8; ++k) {
            int lc = cs + 8 * j + k;
            r[k] = (short)f2bf(bf2f((unsigned short)areg[j][k]) * ggs[lc] + bbs[lc]);
        }
        *(bf16x8*)&As[row][cs + 8 * j] = r;
    }
    __syncthreads();

    f32x4 acc[4];
#pragma unroll
    for (int c = 0; c < 4; ++c) acc[c] = (f32x4){0.f, 0.f, 0.f, 0.f};
#pragma unroll
    for (int kk = 0; kk < 4; ++kk) {
        bf16x8 bfr = *(const bf16x8*)&Bs[w * 16 + ls][g * 8 + 32 * kk];
#pragma unroll
        for (int c = 0; c < 4; ++c) {
            bf16x8 afr = *(const bf16x8*)&As[c * 16 + ls][g * 8 + 32 * kk];
            acc[c] = __builtin_amdgcn_mfma_f32_16x16x32_bf16(afr, bfr, acc[c], 0, 0, 0);
        }
    }
#pragma unroll
    for (int c = 0; c < 4; ++c)
#pragma unroll
        for (int r = 0; r < 4; ++r)
            outB[(long)(m0 + c * 16 + g * 4 + r) * 2048 + n0 + w * 16 + ls] = f2bf(acc[c][r]);
}

// ---------------- MFMA flash attention: 8-wave blocks, 128 q-rows ----------------
__global__ __launch_bounds__(512)
void attn_mfma_kernel(const unsigned short* __restrict__ qkv,
                      unsigned short* __restrict__ outg) {
    int bh = blockIdx.x, bb = bh / H_, hh = bh % H_;
    int q0 = blockIdx.y * 128;
    int tid = threadIdx.x, wv = tid >> 6, lane = tid & 63;
    int ls = lane & 15, g = lane >> 4;

    __shared__ unsigned short Klds[128 * 64];
    __shared__ unsigned short Vlds[64 * 128];
    __shared__ unsigned short Plds[8][16 * 128];

    const unsigned short* qrow = qkv + (long)(bb * T_ + q0 + wv * 16 + ls) * QKVLD + hh * 64 + g * 8;
    bf16x8 qf0 = *(const bf16x8*)qrow;
    bf16x8 qf1 = *(const bf16x8*)(qrow + 32);

    f32x4 o_acc[4];
#pragma unroll
    for (int nf = 0; nf < 4; ++nf) o_acc[nf] = (f32x4){0.f, 0.f, 0.f, 0.f};
    float mrun[4] = {-1e30f, -1e30f, -1e30f, -1e30f};
    float lrun[4] = {0.f, 0.f, 0.f, 0.f};

    char* pbase = (char*)&Plds[wv][0];
    const bool doK = tid < 256;
    const int t2 = tid & 255;
    const int d0 = (t2 & 7) * 8, kvq = t2 >> 3;

    bf16x8 streg[4];
    auto loadKV = [&](int kvb) {
        if (doK) {
#pragma unroll
            for (int i = 0; i < 4; ++i) {
                int c = t2 + i * 256;
                streg[i] = *(const bf16x8*)(qkv + (long)(bb * T_ + kvb + (c >> 3)) * QKVLD + 768 + hh * 64 + (c & 7) * 8);
            }
        } else {
            const unsigned short* vb = qkv + (long)(bb * T_ + kvb + kvq * 4) * QKVLD + 1536 + hh * 64 + d0;
#pragma unroll
            for (int i = 0; i < 4; ++i) streg[i] = *(const bf16x8*)(vb + i * QKVLD);
        }
    };

    loadKV(0);
    for (int kt = 0; kt < T_ / 128; ++kt) {
        __syncthreads();
        if (doK) {
#pragma unroll
            for (int i = 0; i < 4; ++i) {
                int c = t2 + i * 256;
                int kv = c >> 3, dc = c & 7;
                *(bf16x8*)((char*)Klds + ((kv * 128 + dc * 16) ^ ((kv & 7) << 4))) = streg[i];
            }
        } else {
#pragma unroll
            for (int j = 0; j < 8; ++j) {
                unsigned lo = (unsigned)(unsigned short)streg[0][j] | ((unsigned)(unsigned short)streg[1][j] << 16);
                unsigned hi = (unsigned)(unsigned short)streg[2][j] | ((unsigned)(unsigned short)streg[3][j] << 16);
                int d = d0 + j;
                *(uint2*)((char*)Vlds + ((d * 256 + kvq * 8) ^ ((d & 7) << 4))) = make_uint2(lo, hi);
            }
        }
        __syncthreads();
        if (kt + 1 < T_ / 128) loadKV((kt + 1) * 128);

        f32x4 sa[8];
#pragma unroll
        for (int f = 0; f < 8; ++f) sa[f] = (f32x4){0.f, 0.f, 0.f, 0.f};
        __builtin_amdgcn_s_setprio(1);
#pragma unroll
        for (int f = 0; f < 8; ++f) {
            int kv = f * 16 + ls;
            bf16x8 b0 = *(const bf16x8*)((char*)Klds + ((kv * 128 + g * 16) ^ ((kv & 7) << 4)));
            bf16x8 b1 = *(const bf16x8*)((char*)Klds + ((kv * 128 + 64 + g * 16) ^ ((kv & 7) << 4)));
            sa[f] = __builtin_amdgcn_mfma_f32_16x16x32_bf16(qf0, b0, sa[f], 0, 0, 0);
            sa[f] = __builtin_amdgcn_mfma_f32_16x16x32_bf16(qf1, b1, sa[f], 0, 0, 0);
        }
        __builtin_amdgcn_s_setprio(0);

        float pw[8][4];
#pragma unroll
        for (int f = 0; f < 8; ++f)
#pragma unroll
            for (int r = 0; r < 4; ++r) pw[f][r] = sa[f][r] * 0.125f;
#pragma unroll
        for (int r = 0; r < 4; ++r) {
            float m = pw[0][r];
#pragma unroll
            for (int f = 1; f < 8; ++f) m = fmaxf(m, pw[f][r]);
            m = fmaxf(m, __shfl_xor(m, 1));
            m = fmaxf(m, __shfl_xor(m, 2));
            m = fmaxf(m, __shfl_xor(m, 4));
            m = fmaxf(m, __shfl_xor(m, 8));
            if (m > mrun[r] + 8.f) {
                float fac = __expf(mrun[r] - m);
                lrun[r] *= fac;
#pragma unroll
                for (int nf = 0; nf < 4; ++nf) o_acc[nf][r] *= fac;
                mrun[r] = m;
            }
            float s = 0.f;
#pragma unroll
            for (int f = 0; f < 8; ++f) { float e = __expf(pw[f][r] - mrun[r]); pw[f][r] = e; s += e; }
            s += __shfl_xor(s, 1); s += __shfl_xor(s, 2);
            s += __shfl_xor(s, 4); s += __shfl_xor(s, 8);
            lrun[r] += s;
        }

#pragma unroll
        for (int f = 0; f < 8; ++f)
#pragma unroll
            for (int r = 0; r < 4; ++r) {
                int qr = g * 4 + r, col = ls + 16 * f;
                *(unsigned short*)(pbase + ((qr * 256 + col * 2) ^ ((qr & 7) << 4))) = f2bf(pw[f][r]);
            }

        __builtin_amdgcn_s_setprio(1);
#pragma unroll
        for (int ks = 0; ks < 4; ++ks) {
            bf16x8 pa = *(const bf16x8*)(pbase + ((ls * 256 + ks * 64 + g * 16) ^ ((ls & 7) << 4)));
#pragma unroll
            for (int nf = 0; nf < 4; ++nf) {
                int d = nf * 16 + ls;
                bf16x8 bv = *(const bf16x8*)((char*)Vlds + ((d * 256 + ks * 64 + g * 16) ^ ((d & 7) << 4)));
                o_acc[nf] = __builtin_amdgcn_mfma_f32_16x16x32_bf16(pa, bv, o_acc[nf], 0, 0, 0);
            }
        }
        __builtin_amdgcn_s_setprio(0);
    }

    float inv[4];
#pragma unroll
    for (int r = 0; r < 4; ++r) inv[r] = 1.f / lrun[r];
#pragma unroll
    for (int nf = 0; nf < 4; ++nf)
#pragma unroll
        for (int r = 0; r < 4; ++r) {
            long row = bb * T_ + q0 + wv * 16 + g * 4 + r;
            outg[row * D_ + hh * 64 + nf * 16 + ls] = f2bf(o_acc[nf][r] * inv[r]);
        }
}

// ---------------- FUSED tail: top-k (8 waves) + softmax + fp8 gather + residual ----------------
__global__ __launch_bounds__(512)
void pkm_tail_fp8(const unsigned short* __restrict__ dots,
                  const unsigned char* __restrict__ vals8,
                  const float* __restrict__ x1,
                  float* __restrict__ outp) {
    __shared__ float sv[4][64];
    __shared__ int   sidx[4][64];
    __shared__ float w[128];
    __shared__ int   rows[128];
    __shared__ float red[3 * 768];
    int n = blockIdx.x, tid = threadIdx.x;
    int wv = tid >> 6, lane = tid & 63;
    int slot = wv >> 1, half = wv & 1;

    {
        const unsigned short* d = dots + (long)n * 2048 + slot * 512 + half * 256;
        float v0 = bf2f(d[lane]), v1 = bf2f(d[lane + 64]);
        float v2 = bf2f(d[lane + 128]), v3 = bf2f(d[lane + 192]);
#pragma unroll 1
        for (int t = 0; t < 32; ++t) {
            float bm = v0; int ba = 0;
            if (v1 > bm) { bm = v1; ba = 1; }
            if (v2 > bm) { bm = v2; ba = 2; }
            if (v3 > bm) { bm = v3; ba = 3; }
            float wm = bm;
#pragma unroll
            for (int o = 32; o >= 1; o >>= 1) wm = fmaxf(wm, __shfl_xor(wm, o));
            unsigned long long msk = __ballot(bm == wm);
            int owner = (int)__builtin_ctzll(msk);
            if (lane == owner) {
                sv[slot][half * 32 + t] = wm;
                sidx[slot][half * 32 + t] = ba * 64 + lane;
                if (ba == 0) v0 = -1e30f;
                else if (ba == 1) v1 = -1e30f;
                else if (ba == 2) v2 = -1e30f;
                else v3 = -1e30f;
            }
        }
    }
    __syncthreads();

    if (!half) {
        unsigned short t0 = ctab[lane], t1 = ctab[lane + 64];
        float c0 = -1e30f, c1 = -1e30f;
        int id0 = 0, id1 = 0;
        {
            int i = t0 >> 5, j = t0 & 31;
            c0 = sv[slot][i] + sv[slot][32 + j];
            id0 = sidx[slot][i] * NK_ + sidx[slot][32 + j];
        }
        if (t1 != 0xFFFF) {
            int i = t1 >> 5, j = t1 & 31;
            c1 = sv[slot][i] + sv[slot][32 + j];
            id1 = sidx[slot][i] * NK_ + sidx[slot][32 + j];
        }
#pragma unroll 1
        for (int t = 0; t < 32; ++t) {
            float bm = c0; int sel = 0;
            if (c1 > bm) { bm = c1; sel = 1; }
            float wm = bm;
#pragma unroll
            for (int o = 32; o >= 1; o >>= 1) wm = fmaxf(wm, __shfl_xor(wm, o));
            unsigned long long msk = __ballot(bm == wm);
            int owner = (int)__builtin_ctzll(msk);
            if (lane == owner) {
                w[slot * 32 + t] = wm;
                rows[slot * 32 + t] = sel ? id1 : id0;
                if (sel) c1 = -1e30f; else c0 = -1e30f;
            }
        }
    }
    __syncthreads();

    if (tid < 128) {
        float e = w[tid];
        float m = e;
#pragma unroll
        for (int o = 16; o >= 1; o >>= 1) m = fmaxf(m, __shfl_xor(m, o));
        float ex = __expf(e - m);
        float s = ex;
#pragma unroll
        for (int o = 16; o >= 1; o >>= 1) s += __shfl_xor(s, o);
        w[tid] = ex / s;
    }
    __syncthreads();

    int gs = tid >> 7, chunk = tid & 127;
    float a0=0.f,a1=0.f,a2=0.f,a3=0.f,a4=0.f,a5=0.f,a6=0.f,a7=0.f;
    if (chunk < 96) {
#pragma unroll 4
        for (int e = 0; e < 32; ++e) {
            int er = e * 4 + gs;
            float wgt = w[er];
            long ro = (long)rows[er] * D_;
            uint2 v = *(const uint2*)(vals8 + ro + chunk * 8);
            f32x2 f0 = __builtin_amdgcn_cvt_pk_f32_fp8((int)v.x, false);
            f32x2 f1 = __builtin_amdgcn_cvt_pk_f32_fp8((int)v.x, true);
            f32x2 f2 = __builtin_amdgcn_cvt_pk_f32_fp8((int)v.y, false);
            f32x2 f3 = __builtin_amdgcn_cvt_pk_f32_fp8((int)v.y, true);
            a0 += wgt * f0[0]; a1 += wgt * f0[1]; a2 += wgt * f1[0]; a3 += wgt * f1[1];
            a4 += wgt * f2[0]; a5 += wgt * f2[1]; a6 += wgt * f3[0]; a7 += wgt * f3[1];
        }
        if (gs > 0) {
            float* rp = &red[(gs - 1) * 768 + chunk * 8];
            rp[0]=a0; rp[1]=a1; rp[2]=a2; rp[3]=a3; rp[4]=a4; rp[5]=a5; rp[6]=a6; rp[7]=a7;
        }
    }
    __syncthreads();
    if (gs == 0 && chunk < 96) {
        long o = (long)n * D_ + chunk * 8;
        const float* r0 = &red[chunk * 8];
        const float* r1 = &red[768 + chunk * 8];
        const float* r2 = &red[1536 + chunk * 8];
        f32x4 xa = *(const f32x4*)(x1 + o);
        f32x4 xb = *(const f32x4*)(x1 + o + 4);
        f32x4 o1 = { a0 + r0[0] + r1[0] + r2[0] + xa[0], a1 + r0[1] + r1[1] + r2[1] + xa[1],
                     a2 + r0[2] + r1[2] + r2[2] + xa[2], a3 + r0[3] + r1[3] + r2[3] + xa[3] };
        f32x4 o2 = { a4 + r0[4] + r1[4] + r2[4] + xb[0], a5 + r0[5] + r1[5] + r2[5] + xb[1],
                     a6 + r0[6] + r1[6] + r2[6] + xb[2], a7 + r0[7] + r1[7] + r2[7] + xb[3] };
        *(f32x4*)(outp + o) = o1;
        *(f32x4*)(outp + o + 4) = o2;
    }
}

// ---------------- fallback pair (f32 table): topk + gather ----------------
__global__ __launch_bounds__(256)
void topk_kernel(const unsigned short* __restrict__ dots, float* __restrict__ fs, int* __restrict__ vi) {
    __shared__ float sv[2][64];
    __shared__ int   sidx[2][64];
    int tid = threadIdx.x, wv = tid >> 6, lane = tid & 63;
    int slot = wv >> 1, half = wv & 1;
    long task = (long)blockIdx.x * 2 + slot;
    const unsigned short* d = dots + (task >> 2) * 2048 + (task & 3) * 512 + half * 256;

    float v0 = bf2f(d[lane]), v1 = bf2f(d[lane + 64]);
    float v2 = bf2f(d[lane + 128]), v3 = bf2f(d[lane + 192]);
#pragma unroll 1
    for (int t = 0; t < 32; ++t) {
        float bm = v0; int ba = 0;
        if (v1 > bm) { bm = v1; ba = 1; }
        if (v2 > bm) { bm = v2; ba = 2; }
        if (v3 > bm) { bm = v3; ba = 3; }
        float wm = bm;
#pragma unroll
        for (int o = 32; o >= 1; o >>= 1) wm = fmaxf(wm, __shfl_xor(wm, o));
        unsigned long long msk = __ballot(bm == wm);
        int owner = (int)__builtin_ctzll(msk);
        if (lane == owner) {
            sv[slot][half * 32 + t] = wm;
            sidx[slot][half * 32 + t] = ba * 64 + lane;
            if (ba == 0) v0 = -1e30f;
            else if (ba == 1) v1 = -1e30f;
            else if (ba == 2) v2 = -1e30f;
            else v3 = -1e30f;
        }
    }
    __syncthreads();
    if (half) return;

    unsigned short t0 = ctab[lane], t1 = ctab[lane + 64];
    float c0 = -1e30f, c1 = -1e30f;
    int id0 = 0, id1 = 0;
    {
        int i = t0 >> 5, j = t0 & 31;
        c0 = sv[slot][i] + sv[slot][32 + j];
        id0 = sidx[slot][i] * NK_ + sidx[slot][32 + j];
    }
    if (t1 != 0xFFFF) {
        int i = t1 >> 5, j = t1 & 31;
        c1 = sv[slot][i] + sv[slot][32 + j];
        id1 = sidx[slot][i] * NK_ + sidx[slot][32 + j];
    }

    float* fo = fs + task * 32;
    int*   vo = vi + task * 32;
#pragma unroll 1
    for (int t = 0; t < 32; ++t) {
        float bm = c0; int sel = 0;
        if (c1 > bm) { bm = c1; sel = 1; }
        float wm = bm;
#pragma unroll
        for (int o = 32; o >= 1; o >>= 1) wm = fmaxf(wm, __shfl_xor(wm, o));
        unsigned long long msk = __ballot(bm == wm);
        int owner = (int)__builtin_ctzll(msk);
        if (lane == owner) {
            fo[t] = wm;
            vo[t] = sel ? id1 : id0;
            if (sel) c1 = -1e30f; else c0 = -1e30f;
        }
    }
}

__global__ __launch_bounds__(384)
void pkm_out_f32(const float* __restrict__ fs, const int* __restrict__ vi,
                 const float* __restrict__ values, const float* __restrict__ x1,
                 float* __restrict__ outp) {
    int n = blockIdx.x, tid = threadIdx.x;
    __shared__ float w[128];
    __shared__ int   rows[128];
    __shared__ float red[768];
    if (tid < 128) {
        float e = fs[(long)n * 128 + tid];
        rows[tid] = vi[(long)n * 128 + tid];
        float m = e;
#pragma unroll
        for (int o = 16; o >= 1; o >>= 1) m = fmaxf(m, __shfl_xor(m, o));
        float ex = __expf(e - m);
        float s = ex;
#pragma unroll
        for (int o = 16; o >= 1; o >>= 1) s += __shfl_xor(s, o);
        w[tid] = ex / s;
    }
    __syncthreads();
    int slot = tid / 192, chunk = tid % 192;
    float a0 = 0.f, a1 = 0.f, a2 = 0.f, a3 = 0.f;
#pragma unroll 4
    for (int e = 0; e < 64; ++e) {
        int er = e * 2 + slot;
        float wgt = w[er];
        long ro = (long)rows[er] * D_;
        f32x4 v = *(const f32x4*)(values + ro + chunk * 4);
        a0 += wgt * v[0]; a1 += wgt * v[1]; a2 += wgt * v[2]; a3 += wgt * v[3];
    }
    if (slot == 1) {
        f32x4 t = {a0, a1, a2, a3};
        *(f32x4*)&red[chunk * 4] = t;
    }
    __syncthreads();
    if (slot == 0) {
        f32x4 o = *(const f32x4*)&red[chunk * 4];
        f32x4 xr = *(const f32x4*)(x1 + (long)n * D_ + chunk * 4);
        o[0] += a0 + xr[0]; o[1] += a1 + xr[1]; o[2] += a2 + xr[2]; o[3] += a3 + xr[3];
        *(f32x4*)(outp + (long)n * D_ + chunk * 4) = o;
    }
}

extern "C" void kernel_launch(void* const* d_in, const int* in_sizes, int n_in,
                              void* d_out, int out_size, void* d_ws, size_t ws_size,
                              hipStream_t stream) {
    const float* x    = (const float*)d_in[0];
    const float* wq   = (const float*)d_in[1];
    const float* bq   = (const float*)d_in[2];
    const float* wk   = (const float*)d_in[3];
    const float* bk   = (const float*)d_in[4];
    const float* wv   = (const float*)d_in[5];
    const float* bv   = (const float*)d_in[6];
    const float* wo   = (const float*)d_in[7];
    const float* bo   = (const float*)d_in[8];
    const float* ln1g = (const float*)d_in[9];
    const float* ln1b = (const float*)d_in[10];
    const float* ln2g = (const float*)d_in[11];
    const float* ln2b = (const float*)d_in[12];
    const float* pwq  = (const float*)d_in[13];
    const float* bng  = (const float*)d_in[14];
    const float* bnb  = (const float*)d_in[15];
    const float* keys = (const float*)d_in[16];
    const float* vals = (const float*)d_in[17];
    float* out = (float*)d_out;

    char* p = (char*)d_ws;
    auto alloc = [&](size_t bytes) -> char* {
        char* r = p; p += (bytes + 255) & ~(size_t)255; return r;
    };
    unsigned short* wqkvT = (unsigned short*)alloc((size_t)3 * D_ * D_ * 2);
    unsigned short* woT   = (unsigned short*)alloc((size_t)D_ * D_ * 2);
    unsigned short* pwqT  = (unsigned short*)alloc((size_t)D_ * DQ_ * 2);
    unsigned short* keyB  = (unsigned short*)alloc((size_t)NKEYS * 2);
    unsigned short* h1    = (unsigned short*)alloc((size_t)NT * D_ * 2);
    unsigned short* qkvB  = (unsigned short*)alloc((size_t)NT * QKVLD * 2);
    unsigned short* aout  = (unsigned short*)alloc((size_t)NT * D_ * 2);
    float* x1             = (float*)alloc((size_t)NT * D_ * 4);
    unsigned short* h2    = (unsigned short*)alloc((size_t)NT * D_ * 2);
    unsigned short* qfB   = (unsigned short*)alloc((size_t)NT * DQ_ * 2);
    float* pS             = (float*)alloc((size_t)32 * DQ_ * 4);
    float* pSS            = (float*)alloc((size_t)32 * DQ_ * 4);
    unsigned short* dots  = (unsigned short*)alloc((size_t)NT * 2048 * 2);
    float* fsb            = (float*)alloc((size_t)NT * PH_ * 32 * 4);
    int*   vib            = (int*)alloc((size_t)NT * PH_ * 32 * 4);

    // fp8 values table if workspace allows (~50.4 MB more)
    size_t used = (size_t)(p - (char*)d_ws);
    size_t vbytes = (size_t)NK_ * NK_ * D_;
    bool useTab = (used + vbytes + 256) <= ws_size;
    unsigned char* vals8 = nullptr;
    if (useTab) vals8 = (unsigned char*)alloc(vbytes);

    // LN1 + hosted weight prep (transposes + keys convert)
    ln_kernel<<<NT + PREPBLKS, 256, 0, stream>>>(
        x, ln1g, ln1b, h1, NT, wq, wk, wv, wo, pwq, keys, wqkvT, woT, pwqT, keyB);
    // merged QKV GEMM -> qkvB; hosts first half of the values-table conversion
    gemm_kernel<<<dim3(32, useTab ? 52 : 36), 256, 0, stream>>>(
        h1, D_, wqkvT, D_, bq, bk, bv, nullptr, nullptr, qkvB, QKVLD, D_, 2,
        useTab ? vals : nullptr, vals8, 0L, 36, nullptr, nullptr);
    // attention (8-wave blocks, 128 q-rows, grid 192)
    attn_mfma_kernel<<<dim3(B_ * H_, T_ / 128), 512, 0, stream>>>(qkvB, aout);
    // output projection + residual
    gemm_kernel<<<dim3(32, 12), 256, 0, stream>>>(
        aout, D_, woT, D_, bo, nullptr, nullptr, x, x1, nullptr, D_, D_, 0,
        nullptr, nullptr, 0L, 0, nullptr, nullptr);
    // LN2
    ln_kernel<<<NT, 256, 0, stream>>>(
        x1, ln2g, ln2b, h2, NT, nullptr, nullptr, nullptr, nullptr, nullptr, nullptr,
        nullptr, nullptr, nullptr, nullptr);
    // PKM query GEMM (bf16 qf, un-normalized) + fused BN column partials;
    // hosts second half of the values-table conversion
    gemm_kernel<<<dim3(32, useTab ? 32 : 16), 256, 0, stream>>>(
        h2, D_, pwqT, D_, nullptr, nullptr, nullptr, nullptr, nullptr, qfB, DQ_, D_, 0,
        useTab ? vals : nullptr, vals8, CVHALF, 16, pS, pSS);
    // dots GEMM with fused BN finalize + normalize -> bf16
    dots_kernel<<<dim3(32, 4, 8), 256, 0, stream>>>(qfB, keyB, pS, pSS, bng, bnb, dots);
    // fused tail: top-k + softmax + gather + residual
    if (useTab) {
        pkm_tail_fp8<<<NT, 512, 0, stream>>>(dots, vals8, x1, out);
    } else {
        topk_kernel<<<(NT * PH_) / 2, 256, 0, stream>>>(dots, fsb, vib);
        pkm_out_f32<<<NT, 384, 0, stream>>>(fsb, vib, vals, x1, out);
    }
}